// Round 8
// baseline (1147.006 us; speedup 1.0000x reference)
//
#include <hip/hip_runtime.h>
#include <hip/hip_bf16.h>

#define N_NODES 8000
#define N_EDGES 64000
#define NBATCH  64
#define NGRID   12
#define HIDC    128
#define MNPB    4
#define EB      64
#define SE      8
#define NBLK    (N_EDGES / EB)

typedef __bf16 bf16x8 __attribute__((ext_vector_type(8)));
typedef __bf16 bf16x4 __attribute__((ext_vector_type(4)));
typedef float  f32x4  __attribute__((ext_vector_type(4)));
typedef int    i32x4  __attribute__((ext_vector_type(4)));

// gelu = x * sigmoid(2u); fast v_rcp (err ~1e-6)
__device__ __forceinline__ float gelu_f(float x) {
    float u = 0.7978845608f * x * (1.0f + 0.044715f * x * x);
    float e = __expf(2.0f * u);
    float r = __builtin_amdgcn_rcpf(e + 1.0f);
    return x * (1.0f - r);
}

// ---------------- grid0 + per-batch rotated grids ----------------
__global__ void k_grid(const float* __restrict__ Q, float* __restrict__ grid0,
                       float* __restrict__ grid) {
    int t = threadIdx.x;
    __shared__ float g0[12][3];
    if (t < 12) {
        float fi = (float)t;
        float theta = 6.28318530717958647692f * fi / 1.61803398874989484820f;
        float z = 1.0f - (2.0f * fi + 1.0f) / 12.0f;
        float r = sqrtf(fmaxf(1.0f - z * z, 0.0f));
        g0[t][0] = r * cosf(theta);
        g0[t][1] = r * sinf(theta);
        g0[t][2] = z;
        grid0[t * 3 + 0] = g0[t][0];
        grid0[t * 3 + 1] = g0[t][1];
        grid0[t * 3 + 2] = g0[t][2];
    }
    __syncthreads();
    for (int idx = t; idx < NBATCH * 12 * 3; idx += blockDim.x) {
        int b = idx / 36, rmd = idx % 36, n = rmd / 3, i = rmd % 3;
        float acc = 0.f;
        #pragma unroll
        for (int j = 0; j < 3; ++j) acc += Q[b * 9 + i * 3 + j] * g0[n][j];
        grid[idx] = acc;
    }
}

// ---------------- kb_sh -> fk  (fk layout: [l][p][c][o]) ----------------
__global__ __launch_bounds__(128) void k_kbsh(
    const float* __restrict__ grid0,
    const float* __restrict__ Wsh1, const float* __restrict__ bsh1,
    const float* __restrict__ Wsh2, const float* __restrict__ bsh2,
    const float* __restrict__ Wfk, float* __restrict__ fk) {
    int row = blockIdx.x;
    int p = row / 12, o = row % 12, t = threadIdx.x;
    float tt = grid0[p*3]*grid0[o*3] + grid0[p*3+1]*grid0[o*3+1] + grid0[p*3+2]*grid0[o*3+2];
    float p1 = tt, p2 = tt * tt, p3 = p2 * tt;
    float h1 = gelu_f(p1 * Wsh1[t] + p2 * Wsh1[128 + t] + p3 * Wsh1[256 + t] + bsh1[t]);
    __shared__ float h1S[128];
    __shared__ float h2S[128];
    h1S[t] = h1;
    __syncthreads();
    float acc = bsh2[t];
    #pragma unroll 8
    for (int k = 0; k < 128; ++k) acc += h1S[k] * Wsh2[k * 128 + t];
    h2S[t] = gelu_f(acc);
    __syncthreads();
    for (int l = 0; l < 3; ++l) {
        float a = 0.f;
        #pragma unroll 8
        for (int k = 0; k < 128; ++k) a += h2S[k] * Wfk[l * 16384 + k * 128 + t];
        fk[l * 18432 + (p * 128 + t) * 12 + o] = a;
    }
}

// ---------------- embed ----------------
__global__ __launch_bounds__(128) void k_embed(
    const float* __restrict__ x, const float* __restrict__ vec,
    const int* __restrict__ batch, const float* __restrict__ grid,
    const float* __restrict__ Wemb, float* __restrict__ node_grid,
    __bf16* __restrict__ h_bf) {
    __shared__ float WembS[18 * 128];
    __shared__ float ngS[36];
    __shared__ float xS[16];
    __shared__ float vS[6];
    int n = blockIdx.x, t = threadIdx.x;
    for (int i = t; i < 18 * 128; i += 128) WembS[i] = Wemb[i];
    int b = batch[n];
    if (t < 36) { float g = grid[b * 36 + t]; ngS[t] = g; node_grid[n * 36 + t] = g; }
    if (t < 16) xS[t] = x[n * 16 + t];
    if (t >= 16 && t < 22) vS[t - 16] = vec[n * 6 + (t - 16)];
    __syncthreads();
    for (int g = 0; g < NGRID; ++g) {
        float g0 = ngS[g*3], g1 = ngS[g*3+1], g2 = ngS[g*3+2];
        float xv0 = vS[0]*g0 + vS[1]*g1 + vS[2]*g2;
        float xv1 = vS[3]*g0 + vS[4]*g1 + vS[5]*g2;
        float acc = xv0 * WembS[16*128 + t] + xv1 * WembS[17*128 + t];
        #pragma unroll
        for (int j = 0; j < 16; ++j) acc += xS[j] * WembS[j*128 + t];
        h_bf[((size_t)n * NGRID + g) * HIDC + t] = (__bf16)acc;
    }
}

// ---------------- CSR build ----------------
__global__ __launch_bounds__(256) void k_deg(const int* __restrict__ recv,
                                             int* __restrict__ deg) {
    int e = blockIdx.x * 256 + threadIdx.x;
    if (e < N_EDGES) atomicAdd(&deg[recv[e]], 1);
}

__global__ __launch_bounds__(1024) void k_scan(const int* __restrict__ deg,
                                               int* __restrict__ rowptr,
                                               int* __restrict__ cursor) {
    __shared__ int part[1024];
    int t = threadIdx.x;
    int base = t * 8;
    int local[8];
    int s = 0;
    #pragma unroll
    for (int j = 0; j < 8; ++j) {
        int idx = base + j;
        int v = (idx < N_NODES) ? deg[idx] : 0;
        local[j] = s;
        s += v;
    }
    part[t] = s;
    __syncthreads();
    for (int off = 1; off < 1024; off <<= 1) {
        int v = (t >= off) ? part[t - off] : 0;
        __syncthreads();
        part[t] += v;
        __syncthreads();
    }
    int excl = (t == 0) ? 0 : part[t - 1];
    #pragma unroll
    for (int j = 0; j < 8; ++j) {
        int idx = base + j;
        if (idx < N_NODES) {
            int v = excl + local[j];
            rowptr[idx] = v;
            cursor[idx] = v;
        }
    }
    if (t == 1023) rowptr[N_NODES] = part[1023];
}

__global__ __launch_bounds__(256) void k_fill(const int* __restrict__ recv,
                                              int* __restrict__ cursor,
                                              int* __restrict__ perm) {
    int e = blockIdx.x * 256 + threadIdx.x;
    if (e < N_EDGES) {
        int r = recv[e];
        int p = atomicAdd(&cursor[r], 1);
        perm[p] = e;
    }
}

// ---------------- attrs (recv-sorted) ----------------
__global__ __launch_bounds__(256) void k_attr_sorted(
    const float* __restrict__ pos, const float* __restrict__ ng,
    const int* __restrict__ send, const int* __restrict__ recv,
    const int* __restrict__ perm,
    float* __restrict__ attr_s, int* __restrict__ send_s,
    int* __restrict__ recv_s) {
    int idx = blockIdx.x * 256 + threadIdx.x;
    if (idx >= (N_EDGES + 16) * 12) return;
    int i = idx / 12, g = idx % 12;
    if (i < N_EDGES) {
        int e = perm[i];
        int s = send[e], r = recv[e];
        float rx = pos[s*3+0] - pos[r*3+0];
        float ry = pos[s*3+1] - pos[r*3+1];
        float rz = pos[s*3+2] - pos[r*3+2];
        const float* gr = ng + ((size_t)r * 12 + g) * 3;
        float g0 = gr[0], g1 = gr[1], g2 = gr[2];
        float iv1 = rx*g0 + ry*g1 + rz*g2;
        float wx = rx - iv1*g0, wy = ry - iv1*g1, wz = rz - iv1*g2;
        attr_s[(size_t)idx * 2 + 0] = iv1;
        attr_s[(size_t)idx * 2 + 1] = sqrtf(wx*wx + wy*wy + wz*wz);
        if (g == 0) { send_s[i] = s; recv_s[i] = r; }
    } else {
        attr_s[(size_t)idx * 2 + 0] = 0.f;
        attr_s[(size_t)idx * 2 + 1] = 0.f;
        if (g == 0) { send_s[i] = 0; recv_s[i] = 0; }
    }
}

// ---- transposed bf16 weights [Wsp2T | WkT | W1T | W2T] ----
__global__ __launch_bounds__(256) void k_prepw2(
    const float* __restrict__ Wsp2, const float* __restrict__ Wk,
    const float* __restrict__ W1, const float* __restrict__ W2,
    __bf16* __restrict__ WT) {
    int i = blockIdx.x * 256 + threadIdx.x;
    if (i >= 7 * 65536) return;
    float v;
    if (i < 65536) {
        int buf = i >> 14, r = i & 16383;
        int n = r >> 7, k = r & 127;
        v = (buf == 0) ? Wsp2[k * 128 + n] : Wk[(buf - 1) * 16384 + k * 128 + n];
    } else {
        int i2 = i - 65536;
        int l = i2 >> 16, r = i2 & 65535;
        if (l < 3) {
            int n = r >> 7, k = r & 127;
            v = W1[l * 65536 + k * 512 + n];
        } else {
            int l2 = l - 3;
            int n = r >> 9, k = r & 511;
            v = W2[l2 * 65536 + k * 128 + n];
        }
    }
    WT[i] = (__bf16)v;
}

// ---- int8 Wk (transposed, per-column scales) ----
__global__ __launch_bounds__(128) void k_prepw_i8(
    const float* __restrict__ Wk, signed char* __restrict__ Wk8,
    float* __restrict__ s_c) {
    int i = blockIdx.x * 128 + threadIdx.x;
    if (i >= 384) return;
    int l = i / 128, col = i % 128;
    float mx = 0.f;
    for (int k = 0; k < 128; ++k)
        mx = fmaxf(mx, fabsf(Wk[l * 16384 + k * 128 + col]));
    float s = fmaxf(mx * (1.0f / 127.0f), 1e-20f);
    s_c[i] = s;
    float inv = 127.0f / fmaxf(mx, 1e-20f);
    for (int k = 0; k < 128; ++k) {
        int q = __float2int_rn(Wk[l * 16384 + k * 128 + col] * inv);
        q = q > 127 ? 127 : (q < -127 ? -127 : q);
        Wk8[(size_t)l * 16384 + col * 128 + k] = (signed char)q;
    }
}

// ---- combined poly weights WP1T [128 cols x 32 k] bf16 (bias at k=9) ----
__global__ __launch_bounds__(128) void k_prepw_p(
    const float* __restrict__ Wsp1, const float* __restrict__ bsp1,
    __bf16* __restrict__ WP1T) {
    int col = threadIdx.x;
    float w1[14];
    #pragma unroll
    for (int j = 0; j < 14; ++j) w1[j] = Wsp1[j * 128 + col];
    float vals[10];
    vals[0] = w1[0];                       // a
    vals[1] = w1[1];                       // b
    vals[2] = w1[2];                       // aa
    vals[3] = w1[3] + w1[4];               // ab
    vals[4] = w1[5];                       // bb
    vals[5] = w1[6];                       // aaa
    vals[6] = w1[7] + w1[8] + w1[10];      // aab
    vals[7] = w1[9] + w1[11] + w1[12];     // abb
    vals[8] = w1[13];                      // bbb
    vals[9] = bsp1[col];                   // bias (monomial 1)
    for (int k = 0; k < 32; ++k)
        WP1T[col * 32 + k] = (k < 10) ? (__bf16)vals[k] : (__bf16)0.f;
}

// ---- Wro packed per-layer into MFMA B-fragment per-lane layout ----
// WroF[l][lane][ks*8+j] = bf16( col<9 ? Wro[l][k*9+col] : 0 ),
//   col = lane&15, k = ks*32 + (lane>>4)*8 + j.  (verified round 6)
__global__ __launch_bounds__(192) void k_prepw_ro(
    const float* __restrict__ Wro, __bf16* __restrict__ WroF) {
    int t = threadIdx.x;
    int l = t / 64, lane = t % 64;
    int l15 = lane & 15, quad = lane >> 4;
    #pragma unroll
    for (int ks = 0; ks < 4; ++ks)
        #pragma unroll
        for (int j = 0; j < 8; ++j) {
            int k = ks * 32 + quad * 8 + j;
            float v = (l15 < 9) ? Wro[l * 1152 + k * 9 + l15] : 0.f;
            WroF[(size_t)(l * 64 + lane) * 32 + ks * 8 + j] = (__bf16)v;
        }
}

// ---------------- kb precompute (once): MFMA poly -> GEMM1 -> gelu -> kb int8 ----------------
__global__ __launch_bounds__(256, 4) void k_kb_i8(
    const float* __restrict__ attr_s,
    const __bf16* __restrict__ W2T, const __bf16* __restrict__ WP1T,
    const float* __restrict__ bsp2,
    signed char* __restrict__ kb8, float* __restrict__ s_r) {
    __shared__ __align__(16) __bf16 H1[64 * 136];
    __shared__ __align__(16) signed char K8[64 * 144];
    __shared__ float rowmaxS[64];
    int t = threadIdx.x;
    int lane = t & 63, w = t >> 6, l15 = lane & 15, quad = lane >> 4;
    size_t grow0 = (size_t)blockIdx.x * 64;
    // ---- poly via MFMA: wave w owns rows w*16 + l15 ----
    {
        float2 ab = ((const float2*)attr_s)[grow0 + w * 16 + l15];
        float a = ab.x, b = ab.y;
        float aa = a * a, abm = a * b, bb = b * b;
        float m0 = quad == 0 ? a        : (quad == 1 ? bb * b : 0.f);
        float m1 = quad == 0 ? b        : (quad == 1 ? 1.f    : 0.f);
        float m2 = quad == 0 ? aa       : 0.f;
        float m3 = quad == 0 ? abm      : 0.f;
        float m4 = quad == 0 ? bb       : 0.f;
        float m5 = quad == 0 ? aa * a   : 0.f;
        float m6 = quad == 0 ? aa * b   : 0.f;
        float m7 = quad == 0 ? abm * b  : 0.f;
        bf16x8 afrag = { (__bf16)m0, (__bf16)m1, (__bf16)m2, (__bf16)m3,
                         (__bf16)m4, (__bf16)m5, (__bf16)m6, (__bf16)m7 };
        #pragma unroll
        for (int n = 0; n < 8; ++n) {
            bf16x8 bp = *(const bf16x8*)(WP1T + (n * 16 + l15) * 32 + quad * 8);
            f32x4 cacc = {0.f, 0.f, 0.f, 0.f};
            cacc = __builtin_amdgcn_mfma_f32_16x16x32_bf16(afrag, bp, cacc, 0, 0, 0);
            #pragma unroll
            for (int rg = 0; rg < 4; ++rg) {
                int row = w * 16 + quad * 4 + rg;
                H1[row * 136 + n * 16 + l15] = (__bf16)gelu_f(cacc[rg]);
            }
        }
    }
    __syncthreads();
    bf16x8 Bf[2][4];
    #pragma unroll
    for (int j = 0; j < 2; ++j)
        #pragma unroll
        for (int ks = 0; ks < 4; ++ks)
            Bf[j][ks] = *(const bf16x8*)(W2T + (size_t)(w * 32 + j * 16 + l15) * 128 + ks * 32 + quad * 8);
    float b2v[2] = { bsp2[w * 32 + l15], bsp2[w * 32 + 16 + l15] };
    f32x4 acc[4][2];
    #pragma unroll
    for (int mt = 0; mt < 4; ++mt) {
        acc[mt][0] = (f32x4){0.f,0.f,0.f,0.f};
        acc[mt][1] = (f32x4){0.f,0.f,0.f,0.f};
        #pragma unroll
        for (int ks = 0; ks < 4; ++ks) {
            bf16x8 af = *(const bf16x8*)(H1 + (mt * 16 + l15) * 136 + ks * 32 + quad * 8);
            acc[mt][0] = __builtin_amdgcn_mfma_f32_16x16x32_bf16(af, Bf[0][ks], acc[mt][0], 0, 0, 0);
            acc[mt][1] = __builtin_amdgcn_mfma_f32_16x16x32_bf16(af, Bf[1][ks], acc[mt][1], 0, 0, 0);
        }
    }
    float g[4][2][4];
    #pragma unroll
    for (int mt = 0; mt < 4; ++mt)
        #pragma unroll
        for (int j = 0; j < 2; ++j)
            #pragma unroll
            for (int rg = 0; rg < 4; ++rg)
                g[mt][j][rg] = gelu_f(acc[mt][j][rg] + b2v[j]);
    __syncthreads();
    #pragma unroll
    for (int mt = 0; mt < 4; ++mt)
        #pragma unroll
        for (int j = 0; j < 2; ++j)
            #pragma unroll
            for (int rg = 0; rg < 4; ++rg) {
                int row = mt * 16 + quad * 4 + rg;
                H1[row * 136 + w * 32 + j * 16 + l15] = (__bf16)g[mt][j][rg];
            }
    __syncthreads();
    if (t < 64) {
        float mx = 0.f;
        #pragma unroll
        for (int ks = 0; ks < 16; ++ks) {
            bf16x8 xv = *(const bf16x8*)(H1 + t * 136 + ks * 8);
            #pragma unroll
            for (int m = 0; m < 8; ++m) mx = fmaxf(mx, fabsf((float)xv[m]));
        }
        float s = fmaxf(mx * (1.0f / 127.0f), 1e-20f);
        rowmaxS[t] = s;
        s_r[grow0 + t] = s;
    }
    __syncthreads();
    #pragma unroll
    for (int mt = 0; mt < 4; ++mt)
        #pragma unroll
        for (int j = 0; j < 2; ++j)
            #pragma unroll
            for (int rg = 0; rg < 4; ++rg) {
                int row = mt * 16 + quad * 4 + rg;
                float inv = __builtin_amdgcn_rcpf(rowmaxS[row]);
                int q = __float2int_rn(g[mt][j][rg] * inv);
                q = q > 127 ? 127 : (q < -127 ? -127 : q);
                K8[row * 144 + w * 32 + j * 16 + l15] = (signed char)q;
            }
    __syncthreads();
    #pragma unroll
    for (int it = 0; it < 2; ++it) {
        int idx = it * 256 + t;
        int row = idx >> 3, cv = idx & 7;
        *(uint4*)(kb8 + (grow0 + row) * 128 + cv * 16) =
            *(const uint4*)(K8 + row * 144 + cv * 16);
    }
}

// -------- fused per-layer GEMM2 + scatter (node-aligned, NO atomics) --------
__global__ __launch_bounds__(256, 4) void k_gscat2(
    const signed char* __restrict__ kb8, const float* __restrict__ s_r,
    const signed char* __restrict__ Wk8, const float* __restrict__ s_cL,
    const int* __restrict__ send_s, const int* __restrict__ recv_s,
    const int* __restrict__ rowptr, const __bf16* __restrict__ h_bf,
    __bf16* __restrict__ aggb) {
    __shared__ __align__(16) signed char T8[96 * 144];
    __shared__ __align__(16) __bf16 P[96 * 136];
    __shared__ float srS[96];
    int t = threadIdx.x;
    int lane = t & 63, w = t >> 6, l15 = lane & 15, quad = lane >> 4;
    int bid = blockIdx.x;
    int n0, n1;
    {
        if (bid == 0) n0 = 0;
        else {
            int tgt = bid * EB, lo = 0, hi = N_NODES;
            while (lo < hi) { int m = (lo + hi) >> 1; if (rowptr[m] < tgt) lo = m + 1; else hi = m; }
            n0 = lo;
        }
        if (bid == NBLK - 1) n1 = N_NODES;
        else {
            int tgt = (bid + 1) * EB, lo = 0, hi = N_NODES;
            while (lo < hi) { int m = (lo + hi) >> 1; if (rowptr[m] < tgt) lo = m + 1; else hi = m; }
            n1 = lo;
        }
    }
    if (n0 >= n1) return;                    // uniform: no barriers crossed
    int e0 = rowptr[n0], e1 = rowptr[n1];
    long long Bf[2][4];
    #pragma unroll
    for (int j = 0; j < 2; ++j)
        #pragma unroll
        for (int ks = 0; ks < 4; ++ks)
            Bf[j][ks] = *(const long long*)(Wk8 + (size_t)(w * 32 + j * 16 + l15) * 128 + ks * 32 + quad * 8);
    float sc0 = s_cL[w * 32 + l15], sc1 = s_cL[w * 32 + 16 + l15];
    int c = t & 127, half = t >> 7;
    float acc[6] = {0.f, 0.f, 0.f, 0.f, 0.f, 0.f};
    int cur = (e0 < e1) ? recv_s[e0] : -1;
    for (int et0 = e0; et0 < e1; et0 += SE) {
        int cnt = e1 - et0; if (cnt > SE) cnt = SE;
        int nrows = cnt * 12;
        __syncthreads();                     // previous scatter done reading P
        #pragma unroll
        for (int it = 0; it < 3; ++it) {
            int idx = it * 256 + t;
            if (idx < nrows * 8) {
                int row = idx >> 3, cv = idx & 7;
                *(uint4*)(T8 + row * 144 + cv * 16) =
                    *(const uint4*)(kb8 + ((size_t)et0 * 12 + row) * 128 + cv * 16);
            }
        }
        if (t < nrows) srS[t] = s_r[(size_t)et0 * 12 + t];
        __syncthreads();
        int nrt = (nrows + 15) >> 4;
        for (int rt = 0; rt < nrt; ++rt) {
            i32x4 a0 = (i32x4){0, 0, 0, 0};
            i32x4 a1 = (i32x4){0, 0, 0, 0};
            #pragma unroll
            for (int ks = 0; ks < 4; ++ks) {
                long long a = *(const long long*)(T8 + (rt * 16 + l15) * 144 + ks * 32 + quad * 8);
                a0 = __builtin_amdgcn_mfma_i32_16x16x32_i8(a, Bf[0][ks], a0, 0, 0, 0);
                a1 = __builtin_amdgcn_mfma_i32_16x16x32_i8(a, Bf[1][ks], a1, 0, 0, 0);
            }
            #pragma unroll
            for (int rg = 0; rg < 4; ++rg) {
                int row = rt * 16 + quad * 4 + rg;
                float sr = srS[row];
                P[row * 136 + w * 32 + l15]      = (__bf16)((float)a0[rg] * sr * sc0);
                P[row * 136 + w * 32 + 16 + l15] = (__bf16)((float)a1[rg] * sr * sc1);
            }
        }
        __syncthreads();
        for (int el = 0; el < cnt; ++el) {
            int e = et0 + el;
            int r = recv_s[e];
            if (r != cur) {
                __bf16* op = aggb + ((size_t)cur * 128 + c) * 12 + half * 6;
                #pragma unroll
                for (int j = 0; j < 6; ++j) { op[j] = (__bf16)acc[j]; acc[j] = 0.f; }
                cur = r;
            }
            int s = send_s[e];
            const __bf16* hp = h_bf + (size_t)s * 1536 + half * 6 * 128 + c;
            const __bf16* pp = P + (el * 12 + half * 6) * 136 + c;
            #pragma unroll
            for (int j = 0; j < 6; ++j)
                acc[j] += (float)hp[j * 128] * (float)pp[j * 136];
        }
    }
    if (e0 < e1) {
        __bf16* op = aggb + ((size_t)cur * 128 + c) * 12 + half * 6;
        #pragma unroll
        for (int j = 0; j < 6; ++j) op[j] = (__bf16)acc[j];
    }
    for (int n = n0; n < n1; ++n) {
        if (rowptr[n] == rowptr[n + 1]) {
            __bf16* op = aggb + ((size_t)n * 128 + c) * 12 + half * 6;
            #pragma unroll
            for (int j = 0; j < 6; ++j) op[j] = (__bf16)0.f;
        }
    }
}

// ---------------- node kernel: conv + LN + MFMA MLP + MFMA readout ----------------
// Round-21: coalesced-store tail. Round-6's (256,6) regressed because the
// scattered partial-line h_bf/readout RMW lost L2 write-merging at >4
// blocks/CU (FETCH 27->81MB, WRITE 27->106MB). Now: MLP out staged in X
// (LDS), residual done as contiguous bf16x8 pass over the block's h slice
// ((n0*12+row)*128 — contiguous 12KB); readout staged in LDS (aliasing dead
// H4) then contiguous 432-float RMW. WroT via WroF per-lane pre-pack (r6,
// verified) -> LDS 26.5KB -> (256,6).
__global__ __launch_bounds__(256, 6) void k_mlp(
    const __bf16* __restrict__ aggb, const float* __restrict__ fkl,
    const float* __restrict__ bconv, const float* __restrict__ ln_g,
    const float* __restrict__ ln_b,
    const __bf16* __restrict__ W1T, const float* __restrict__ b1,
    const __bf16* __restrict__ W2T2, const float* __restrict__ b2,
    const __bf16* __restrict__ WroFl, const float* __restrict__ bro,
    __bf16* __restrict__ h_bf, float* __restrict__ readout) {
    __shared__ __align__(16) __bf16 X[48 * 136];
    __shared__ __align__(16) __bf16 H4[48 * 136];
    __shared__ float redS[48][2];
    int t = threadIdx.x;
    int lane = t & 63, w = t >> 6, l15 = lane & 15, quad = lane >> 4;
    int c = t & 127, nh = t >> 7;
    int n0 = blockIdx.x * MNPB;
    float bcv = bconv[c];
    // ---- conv: thread owns channel c, nodes {nh, nh+2} ----
    {
        float a2[2][12];
        #pragma unroll
        for (int u = 0; u < 2; ++u) {
            const __bf16* ap = aggb + ((size_t)(n0 + nh + u * 2) * 128 + c) * 12;
            #pragma unroll
            for (int v = 0; v < 3; ++v) {
                bf16x4 pk = *(const bf16x4*)(ap + v * 4);
                #pragma unroll
                for (int j = 0; j < 4; ++j) a2[u][v * 4 + j] = (float)pk[j];
            }
        }
        #pragma unroll 4
        for (int p = 0; p < 12; ++p) {
            const float* fp = fkl + ((size_t)p * 128 + c) * 12;
            float fr[12];
            #pragma unroll
            for (int v = 0; v < 3; ++v) {
                float4 fv = *(const float4*)(fp + v * 4);
                fr[v*4+0] = fv.x; fr[v*4+1] = fv.y; fr[v*4+2] = fv.z; fr[v*4+3] = fv.w;
            }
            float s0 = 0.f, s1 = 0.f;
            #pragma unroll
            for (int o = 0; o < 12; ++o) {
                s0 += a2[0][o] * fr[o];
                s1 += a2[1][o] * fr[o];
            }
            X[(nh * 12 + p) * 136 + c]       = (__bf16)(s0 * (1.0f / 12.0f) + bcv);
            X[((nh + 2) * 12 + p) * 136 + c] = (__bf16)(s1 * (1.0f / 12.0f) + bcv);
        }
    }
    __syncthreads();
    // ---- LN stats ----
    for (int r = w * 12; r < w * 12 + 12; ++r) {
        float v0 = (float)X[r * 136 + lane];
        float v1 = (float)X[r * 136 + 64 + lane];
        float s = v0 + v1, s2 = v0 * v0 + v1 * v1;
        for (int off = 32; off > 0; off >>= 1) {
            s += __shfl_down(s, off);
            s2 += __shfl_down(s2, off);
        }
        if (lane == 0) {
            float mu = s * (1.0f / 128.0f);
            float var = s2 * (1.0f / 128.0f) - mu * mu;
            redS[r][0] = mu;
            redS[r][1] = rsqrtf(var + 1e-5f);
        }
    }
    __syncthreads();
    float gv = ln_g[c], bv = ln_b[c];
    #pragma unroll
    for (int nn = nh; nn < 4; nn += 2)
        #pragma unroll
        for (int p = 0; p < 12; ++p) {
            int r = nn * 12 + p;
            float v = (float)X[r * 136 + c];
            X[r * 136 + c] = (__bf16)((v - redS[r][0]) * redS[r][1] * gv + bv);
        }
    __syncthreads();
    // ---- MLP: 4 phases of 128 hidden cols ----
    f32x4 acc2[3][2];
    #pragma unroll
    for (int mt = 0; mt < 3; ++mt)
        #pragma unroll
        for (int j = 0; j < 2; ++j) acc2[mt][j] = (f32x4){0.f, 0.f, 0.f, 0.f};
    for (int ph = 0; ph < 4; ++ph) {
        if (ph) __syncthreads();
        #pragma unroll
        for (int mt = 0; mt < 3; ++mt) {
            bf16x8 af[4];
            #pragma unroll
            for (int ks = 0; ks < 4; ++ks)
                af[ks] = *(const bf16x8*)(X + (mt * 16 + l15) * 136 + ks * 32 + quad * 8);
            #pragma unroll
            for (int nt = 0; nt < 2; ++nt) {
                int colf = ph * 128 + w * 32 + nt * 16 + l15;
                f32x4 a = {0.f, 0.f, 0.f, 0.f};
                #pragma unroll
                for (int ks = 0; ks < 4; ++ks) {
                    bf16x8 bf = *(const bf16x8*)(W1T + (size_t)colf * 128 + ks * 32 + quad * 8);
                    a = __builtin_amdgcn_mfma_f32_16x16x32_bf16(af[ks], bf, a, 0, 0, 0);
                }
                float bj = b1[colf];
                #pragma unroll
                for (int rg = 0; rg < 4; ++rg) {
                    int row = mt * 16 + quad * 4 + rg;
                    H4[row * 136 + w * 32 + nt * 16 + l15] = (__bf16)gelu_f(a[rg] + bj);
                }
            }
        }
        __syncthreads();
        #pragma unroll
        for (int mt = 0; mt < 3; ++mt)
            #pragma unroll
            for (int ks = 0; ks < 4; ++ks) {
                bf16x8 af = *(const bf16x8*)(H4 + (mt * 16 + l15) * 136 + ks * 32 + quad * 8);
                #pragma unroll
                for (int j = 0; j < 2; ++j) {
                    int col = w * 32 + j * 16 + l15;
                    bf16x8 bf = *(const bf16x8*)(W2T2 + (size_t)col * 512 + ph * 128 + ks * 32 + quad * 8);
                    acc2[mt][j] = __builtin_amdgcn_mfma_f32_16x16x32_bf16(af, bf, acc2[mt][j], 0, 0, 0);
                }
            }
    }
    // ---- stage MLP out (+bias) into X (LDS scatter; no global traffic) ----
    #pragma unroll
    for (int mt = 0; mt < 3; ++mt) {
        float bj0 = b2[w * 32 + l15], bj1 = b2[w * 32 + 16 + l15];
        #pragma unroll
        for (int rg = 0; rg < 4; ++rg) {
            int row = mt * 16 + quad * 4 + rg;
            X[row * 136 + w * 32 + l15]      = (__bf16)(acc2[mt][0][rg] + bj0);
            X[row * 136 + w * 32 + 16 + l15] = (__bf16)(acc2[mt][1][rg] + bj1);
        }
    }
    __syncthreads();
    // ---- coalesced residual: h_new = h_old + X over contiguous block slice ----
    for (int i = t; i < 768; i += 256) {     // 48 rows x 16 bf16x8 chunks
        int row = i >> 4, cv = i & 15;
        __bf16* hp = h_bf + ((size_t)n0 * 12 + row) * 128 + cv * 8;
        bf16x8 xm = *(const bf16x8*)(X + row * 136 + cv * 8);
        bf16x8 ho = *(const bf16x8*)hp;
        bf16x8 hn;
        #pragma unroll
        for (int j = 0; j < 8; ++j) hn[j] = (__bf16)((float)xm[j] + (float)ho[j]);
        *(bf16x8*)hp = hn;
        *(bf16x8*)(X + row * 136 + cv * 8) = hn;
    }
    __syncthreads();
    // ---- readout via MFMA -> LDS stage (aliasing dead H4) ----
    float* roS = (float*)H4;
    if (w < 3) {
        int mt = w;
        const __bf16* wp = WroFl + (size_t)lane * 32;
        f32x4 a = {0.f, 0.f, 0.f, 0.f};
        #pragma unroll
        for (int ks = 0; ks < 4; ++ks) {
            bf16x8 af = *(const bf16x8*)(X + (mt * 16 + l15) * 136 + ks * 32 + quad * 8);
            bf16x8 bf = *(const bf16x8*)(wp + ks * 8);
            a = __builtin_amdgcn_mfma_f32_16x16x32_bf16(af, bf, a, 0, 0, 0);
        }
        if (l15 < 9) {
            float bj = bro[l15];
            #pragma unroll
            for (int rg = 0; rg < 4; ++rg) {
                int row = mt * 16 + quad * 4 + rg;
                roS[row * 9 + l15] = a[rg] + bj;
            }
        }
    }
    __syncthreads();
    // ---- coalesced readout RMW: contiguous 432 floats per block ----
    for (int i = t; i < 432; i += 256)
        readout[(size_t)n0 * 108 + i] += roS[i] * (1.0f / 3.0f);
}

// ---------------- final pooling ----------------
__global__ __launch_bounds__(128) void k_out(
    const float* __restrict__ readout, const float* __restrict__ node_grid,
    const int* __restrict__ batch, float* __restrict__ out) {
    int n = blockIdx.x * 128 + threadIdx.x;
    if (n >= N_NODES) return;
    int b = batch[n];
    const float* ro = readout + (size_t)n * 108;
    float ss[8] = {0, 0, 0, 0, 0, 0, 0, 0};
    float v0 = 0.f, v1 = 0.f, v2 = 0.f;
    for (int p = 0; p < 12; ++p) {
        #pragma unroll
        for (int j = 0; j < 8; ++j) ss[j] += ro[p * 9 + j];
        float rv = ro[p * 9 + 8];
        v0 += rv * node_grid[n * 36 + p * 3 + 0];
        v1 += rv * node_grid[n * 36 + p * 3 + 1];
        v2 += rv * node_grid[n * 36 + p * 3 + 2];
    }
    #pragma unroll
    for (int j = 0; j < 8; ++j) atomicAdd(&out[b * 8 + j], ss[j] * (1.0f / 12.0f));
    atomicAdd(&out[512 + b * 3 + 0], v0 * (1.0f / 12.0f));
    atomicAdd(&out[512 + b * 3 + 1], v1 * (1.0f / 12.0f));
    atomicAdd(&out[512 + b * 3 + 2], v2 * (1.0f / 12.0f));
}

extern "C" void kernel_launch(void* const* d_in, const int* in_sizes, int n_in,
                              void* d_out, int out_size, void* d_ws, size_t ws_size,
                              hipStream_t stream) {
    const float* x    = (const float*)d_in[0];
    const float* vec  = (const float*)d_in[1];
    const float* pos  = (const float*)d_in[2];
    const float* Q    = (const float*)d_in[3];
    const float* Wsp1 = (const float*)d_in[4];
    const float* bsp1 = (const float*)d_in[5];
    const float* Wsp2 = (const float*)d_in[6];
    const float* bsp2 = (const float*)d_in[7];
    const float* Wsh1 = (const float*)d_in[8];
    const float* bsh1 = (const float*)d_in[9];
    const float* Wsh2 = (const float*)d_in[10];
    const float* bsh2 = (const float*)d_in[11];
    const float* Wemb = (const float*)d_in[12];
    const float* Wk   = (const float*)d_in[13];
    const float* Wfk  = (const float*)d_in[14];
    const float* bconv= (const float*)d_in[15];
    const float* ln_g = (const float*)d_in[16];
    const float* ln_b = (const float*)d_in[17];
    const float* W1   = (const float*)d_in[18];
    const float* b1   = (const float*)d_in[19];
    const float* W2   = (const float*)d_in[20];
    const float* b2   = (const float*)d_in[21];
    const float* Wro  = (const float*)d_in[22];
    const float* bro  = (const float*)d_in[23];
    const int* ei     = (const int*)d_in[24];
    const int* batch  = (const int*)d_in[25];
    const int* send = ei;
    const int* recv = ei + N_EDGES;

    float* ws = (float*)d_ws;
    float* grid0  = ws;
    float* grid   = ws + 64;
    float* fk     = ws + 2368;
    float* ng     = ws + 57664;
    float* ro     = ws + 345664;
    float* attr_s = ws + 1209664;
    const size_t P_WT  = 2746048;            // bf16 WT: 458752 bf16
    const size_t P_WK8 = P_WT + 229376;      // int8 Wk: 49152 B
    const size_t P_SC  = P_WK8 + 12288;      // col scales
    const size_t P_WP  = P_SC + 384;         // WP1T: 4096 bf16
    const size_t P_WROF= P_WP + 2048;        // WroF: 6144 bf16 = 3072 f
    const size_t P_H   = P_WROF + 3072;      // h bf16
    const size_t P_AGG = P_H + 6144000;      // aggb
    const size_t P_KB8 = P_AGG + 6144000;    // kb int8 (98.3 MB)
    const size_t P_SR  = P_KB8 + 24576000;   // row scales
    const size_t T_INT = P_SR + 768000;
    const size_t NEED  = (T_INT + 216096) * 4ull;   // ~163 MB

    if (ws_size < NEED) return;

    __bf16* WT   = (__bf16*)(ws + P_WT);
    signed char* Wk8 = (signed char*)(ws + P_WK8);
    float* s_c   = ws + P_SC;
    __bf16* WP1T = (__bf16*)(ws + P_WP);
    __bf16* WroF = (__bf16*)(ws + P_WROF);
    __bf16* hA   = (__bf16*)(ws + P_H);
    __bf16* aggb = (__bf16*)(ws + P_AGG);
    signed char* kb8 = (signed char*)(ws + P_KB8);
    float* s_r   = ws + P_SR;
    int*   ibase = (int*)(ws + T_INT);
    int* deg    = ibase;
    int* cursor = ibase + 8000;
    int* rowptr = ibase + 16000;
    int* perm   = ibase + 24064;
    int* send_s = ibase + 88064;
    int* recv_s = ibase + 152080;

    const __bf16* Wsp2T = WT;
    const __bf16* W1T   = WT + 65536;
    const __bf16* W2T   = WT + 65536 + 3 * 65536;

    hipMemsetAsync(d_out, 0, sizeof(float) * (size_t)out_size, stream);
    hipMemsetAsync(ro, 0, sizeof(float) * 864000, stream);
    hipMemsetAsync(deg, 0, sizeof(int) * 8000, stream);

    k_grid<<<1, 256, 0, stream>>>(Q, grid0, grid);
    k_kbsh<<<144, 128, 0, stream>>>(grid0, Wsh1, bsh1, Wsh2, bsh2, Wfk, fk);
    k_embed<<<N_NODES, 128, 0, stream>>>(x, vec, batch, grid, Wemb, ng, hA);
    k_deg<<<250, 256, 0, stream>>>(recv, deg);
    k_scan<<<1, 1024, 0, stream>>>(deg, rowptr, cursor);
    k_fill<<<250, 256, 0, stream>>>(recv, cursor, perm);
    k_attr_sorted<<<((N_EDGES + 16) * 12 + 255) / 256, 256, 0, stream>>>(
        pos, ng, send, recv, perm, attr_s, send_s, recv_s);
    k_prepw2<<<(7 * 65536 + 255) / 256, 256, 0, stream>>>(Wsp2, Wk, W1, W2, WT);
    k_prepw_i8<<<3, 128, 0, stream>>>(Wk, Wk8, s_c);
    k_prepw_p<<<1, 128, 0, stream>>>(Wsp1, bsp1, WP1T);
    k_prepw_ro<<<1, 192, 0, stream>>>(Wro, WroF);

    k_kb_i8<<<N_EDGES * 12 / 64, 256, 0, stream>>>(attr_s, Wsp2T, WP1T, bsp2, kb8, s_r);

    for (int l = 0; l < 3; ++l) {
        k_gscat2<<<NBLK, 256, 0, stream>>>(kb8, s_r,
            Wk8 + (size_t)l * 16384, s_c + l * 128,
            send_s, recv_s, rowptr, hA, aggb);
        k_mlp<<<N_NODES / MNPB, 256, 0, stream>>>(aggb, fk + l * 18432,
            bconv + l * 128, ln_g + l * 128, ln_b + l * 128,
            W1T + l * 65536, b1 + l * 512, W2T + l * 65536, b2 + l * 128,
            WroF + l * 2048, bro + l * 9, hA, ro);
    }
    k_out<<<(N_NODES + 127) / 128, 128, 0, stream>>>(ro, ng, batch, (float*)d_out);
}

// Round 9
// 1060.172 us; speedup vs baseline: 1.0819x; 1.0819x over previous
//
#include <hip/hip_runtime.h>
#include <hip/hip_bf16.h>

#define N_NODES 8000
#define N_EDGES 64000
#define NBATCH  64
#define NGRID   12
#define HIDC    128
#define MNPB    4
#define ENPB    8
#define EB      32
#define SE      8
#define NBLK    (N_EDGES / EB)

typedef __bf16 bf16x8 __attribute__((ext_vector_type(8)));
typedef __bf16 bf16x4 __attribute__((ext_vector_type(4)));
typedef float  f32x4  __attribute__((ext_vector_type(4)));
typedef int    i32x4  __attribute__((ext_vector_type(4)));

// gelu = x * sigmoid(2u); fast v_rcp (err ~1e-6)
__device__ __forceinline__ float gelu_f(float x) {
    float u = 0.7978845608f * x * (1.0f + 0.044715f * x * x);
    float e = __expf(2.0f * u);
    float r = __builtin_amdgcn_rcpf(e + 1.0f);
    return x * (1.0f - r);
}

// ---------------- grid0 + per-batch rotated grids ----------------
__global__ void k_grid(const float* __restrict__ Q, float* __restrict__ grid0,
                       float* __restrict__ grid) {
    int t = threadIdx.x;
    __shared__ float g0[12][3];
    if (t < 12) {
        float fi = (float)t;
        float theta = 6.28318530717958647692f * fi / 1.61803398874989484820f;
        float z = 1.0f - (2.0f * fi + 1.0f) / 12.0f;
        float r = sqrtf(fmaxf(1.0f - z * z, 0.0f));
        g0[t][0] = r * cosf(theta);
        g0[t][1] = r * sinf(theta);
        g0[t][2] = z;
        grid0[t * 3 + 0] = g0[t][0];
        grid0[t * 3 + 1] = g0[t][1];
        grid0[t * 3 + 2] = g0[t][2];
    }
    __syncthreads();
    for (int idx = t; idx < NBATCH * 12 * 3; idx += blockDim.x) {
        int b = idx / 36, rmd = idx % 36, n = rmd / 3, i = rmd % 3;
        float acc = 0.f;
        #pragma unroll
        for (int j = 0; j < 3; ++j) acc += Q[b * 9 + i * 3 + j] * g0[n][j];
        grid[idx] = acc;
    }
}

// ---------------- kb_sh -> fk  (fk layout: [l][p][c][o]) ----------------
__global__ __launch_bounds__(128) void k_kbsh(
    const float* __restrict__ grid0,
    const float* __restrict__ Wsh1, const float* __restrict__ bsh1,
    const float* __restrict__ Wsh2, const float* __restrict__ bsh2,
    const float* __restrict__ Wfk, float* __restrict__ fk) {
    int row = blockIdx.x;
    int p = row / 12, o = row % 12, t = threadIdx.x;
    float tt = grid0[p*3]*grid0[o*3] + grid0[p*3+1]*grid0[o*3+1] + grid0[p*3+2]*grid0[o*3+2];
    float p1 = tt, p2 = tt * tt, p3 = p2 * tt;
    float h1 = gelu_f(p1 * Wsh1[t] + p2 * Wsh1[128 + t] + p3 * Wsh1[256 + t] + bsh1[t]);
    __shared__ float h1S[128];
    __shared__ float h2S[128];
    h1S[t] = h1;
    __syncthreads();
    float acc = bsh2[t];
    #pragma unroll 8
    for (int k = 0; k < 128; ++k) acc += h1S[k] * Wsh2[k * 128 + t];
    h2S[t] = gelu_f(acc);
    __syncthreads();
    for (int l = 0; l < 3; ++l) {
        float a = 0.f;
        #pragma unroll 8
        for (int k = 0; k < 128; ++k) a += h2S[k] * Wfk[l * 16384 + k * 128 + t];
        fk[l * 18432 + (p * 128 + t) * 12 + o] = a;
    }
}

// ---------------- embed (round-22: ENPB=8 nodes/block, Wemb amortized) ----------------
// Was 8000 blocks x 9KB Wemb stage each (72 MB redundant L2 reads). Now 1000
// blocks stage Wemb once per 8 nodes; per-node scalars staged cooperatively.
__global__ __launch_bounds__(128) void k_embed(
    const float* __restrict__ x, const float* __restrict__ vec,
    const int* __restrict__ batch, const float* __restrict__ grid,
    const float* __restrict__ Wemb, float* __restrict__ node_grid,
    __bf16* __restrict__ h_bf) {
    __shared__ float WembS[18 * 128];
    __shared__ float ngS[ENPB][36];
    __shared__ float xS[ENPB][16];
    __shared__ float vS[ENPB][6];
    int n0 = blockIdx.x * ENPB, t = threadIdx.x;
    for (int i = t; i < 18 * 128; i += 128) WembS[i] = Wemb[i];
    for (int i = t; i < ENPB * 36; i += 128) {
        int u = i / 36, j = i % 36;
        float g = grid[batch[n0 + u] * 36 + j];
        ngS[u][j] = g;
        node_grid[(size_t)(n0 + u) * 36 + j] = g;
    }
    for (int i = t; i < ENPB * 16; i += 128) {
        int u = i >> 4, j = i & 15;
        xS[u][j] = x[(n0 + u) * 16 + j];
    }
    for (int i = t; i < ENPB * 6; i += 128) {
        int u = i / 6, j = i % 6;
        vS[u][j] = vec[(n0 + u) * 6 + j];
    }
    __syncthreads();
    for (int u = 0; u < ENPB; ++u) {
        for (int g = 0; g < NGRID; ++g) {
            float g0 = ngS[u][g*3], g1 = ngS[u][g*3+1], g2 = ngS[u][g*3+2];
            float xv0 = vS[u][0]*g0 + vS[u][1]*g1 + vS[u][2]*g2;
            float xv1 = vS[u][3]*g0 + vS[u][4]*g1 + vS[u][5]*g2;
            float acc = xv0 * WembS[16*128 + t] + xv1 * WembS[17*128 + t];
            #pragma unroll
            for (int j = 0; j < 16; ++j) acc += xS[u][j] * WembS[j*128 + t];
            h_bf[((size_t)(n0 + u) * NGRID + g) * HIDC + t] = (__bf16)acc;
        }
    }
}

// ---------------- CSR build ----------------
__global__ __launch_bounds__(256) void k_deg(const int* __restrict__ recv,
                                             int* __restrict__ deg) {
    int e = blockIdx.x * 256 + threadIdx.x;
    if (e < N_EDGES) atomicAdd(&deg[recv[e]], 1);
}

__global__ __launch_bounds__(1024) void k_scan(const int* __restrict__ deg,
                                               int* __restrict__ rowptr,
                                               int* __restrict__ cursor) {
    __shared__ int part[1024];
    int t = threadIdx.x;
    int base = t * 8;
    int local[8];
    int s = 0;
    #pragma unroll
    for (int j = 0; j < 8; ++j) {
        int idx = base + j;
        int v = (idx < N_NODES) ? deg[idx] : 0;
        local[j] = s;
        s += v;
    }
    part[t] = s;
    __syncthreads();
    for (int off = 1; off < 1024; off <<= 1) {
        int v = (t >= off) ? part[t - off] : 0;
        __syncthreads();
        part[t] += v;
        __syncthreads();
    }
    int excl = (t == 0) ? 0 : part[t - 1];
    #pragma unroll
    for (int j = 0; j < 8; ++j) {
        int idx = base + j;
        if (idx < N_NODES) {
            int v = excl + local[j];
            rowptr[idx] = v;
            cursor[idx] = v;
        }
    }
    if (t == 1023) rowptr[N_NODES] = part[1023];
}

__global__ __launch_bounds__(256) void k_fill(const int* __restrict__ recv,
                                              int* __restrict__ cursor,
                                              int* __restrict__ perm) {
    int e = blockIdx.x * 256 + threadIdx.x;
    if (e < N_EDGES) {
        int r = recv[e];
        int p = atomicAdd(&cursor[r], 1);
        perm[p] = e;
    }
}

// ---------------- attrs (recv-sorted) ----------------
__global__ __launch_bounds__(256) void k_attr_sorted(
    const float* __restrict__ pos, const float* __restrict__ ng,
    const int* __restrict__ send, const int* __restrict__ recv,
    const int* __restrict__ perm,
    float* __restrict__ attr_s, int* __restrict__ send_s,
    int* __restrict__ recv_s) {
    int idx = blockIdx.x * 256 + threadIdx.x;
    if (idx >= (N_EDGES + 16) * 12) return;
    int i = idx / 12, g = idx % 12;
    if (i < N_EDGES) {
        int e = perm[i];
        int s = send[e], r = recv[e];
        float rx = pos[s*3+0] - pos[r*3+0];
        float ry = pos[s*3+1] - pos[r*3+1];
        float rz = pos[s*3+2] - pos[r*3+2];
        const float* gr = ng + ((size_t)r * 12 + g) * 3;
        float g0 = gr[0], g1 = gr[1], g2 = gr[2];
        float iv1 = rx*g0 + ry*g1 + rz*g2;
        float wx = rx - iv1*g0, wy = ry - iv1*g1, wz = rz - iv1*g2;
        attr_s[(size_t)idx * 2 + 0] = iv1;
        attr_s[(size_t)idx * 2 + 1] = sqrtf(wx*wx + wy*wy + wz*wz);
        if (g == 0) { send_s[i] = s; recv_s[i] = r; }
    } else {
        attr_s[(size_t)idx * 2 + 0] = 0.f;
        attr_s[(size_t)idx * 2 + 1] = 0.f;
        if (g == 0) { send_s[i] = 0; recv_s[i] = 0; }
    }
}

// ---- transposed bf16 weights [Wsp2T | WkT | W1T | W2T] ----
__global__ __launch_bounds__(256) void k_prepw2(
    const float* __restrict__ Wsp2, const float* __restrict__ Wk,
    const float* __restrict__ W1, const float* __restrict__ W2,
    __bf16* __restrict__ WT) {
    int i = blockIdx.x * 256 + threadIdx.x;
    if (i >= 7 * 65536) return;
    float v;
    if (i < 65536) {
        int buf = i >> 14, r = i & 16383;
        int n = r >> 7, k = r & 127;
        v = (buf == 0) ? Wsp2[k * 128 + n] : Wk[(buf - 1) * 16384 + k * 128 + n];
    } else {
        int i2 = i - 65536;
        int l = i2 >> 16, r = i2 & 65535;
        if (l < 3) {
            int n = r >> 7, k = r & 127;
            v = W1[l * 65536 + k * 512 + n];
        } else {
            int l2 = l - 3;
            int n = r >> 9, k = r & 511;
            v = W2[l2 * 65536 + k * 128 + n];
        }
    }
    WT[i] = (__bf16)v;
}

// ---- int8 Wk (transposed, per-column scales) ----
__global__ __launch_bounds__(128) void k_prepw_i8(
    const float* __restrict__ Wk, signed char* __restrict__ Wk8,
    float* __restrict__ s_c) {
    int i = blockIdx.x * 128 + threadIdx.x;
    if (i >= 384) return;
    int l = i / 128, col = i % 128;
    float mx = 0.f;
    for (int k = 0; k < 128; ++k)
        mx = fmaxf(mx, fabsf(Wk[l * 16384 + k * 128 + col]));
    float s = fmaxf(mx * (1.0f / 127.0f), 1e-20f);
    s_c[i] = s;
    float inv = 127.0f / fmaxf(mx, 1e-20f);
    for (int k = 0; k < 128; ++k) {
        int q = __float2int_rn(Wk[l * 16384 + k * 128 + col] * inv);
        q = q > 127 ? 127 : (q < -127 ? -127 : q);
        Wk8[(size_t)l * 16384 + col * 128 + k] = (signed char)q;
    }
}

// ---- combined poly weights WP1T [128 cols x 32 k] bf16 (bias at k=9) ----
__global__ __launch_bounds__(128) void k_prepw_p(
    const float* __restrict__ Wsp1, const float* __restrict__ bsp1,
    __bf16* __restrict__ WP1T) {
    int col = threadIdx.x;
    float w1[14];
    #pragma unroll
    for (int j = 0; j < 14; ++j) w1[j] = Wsp1[j * 128 + col];
    float vals[10];
    vals[0] = w1[0];                       // a
    vals[1] = w1[1];                       // b
    vals[2] = w1[2];                       // aa
    vals[3] = w1[3] + w1[4];               // ab
    vals[4] = w1[5];                       // bb
    vals[5] = w1[6];                       // aaa
    vals[6] = w1[7] + w1[8] + w1[10];      // aab
    vals[7] = w1[9] + w1[11] + w1[12];     // abb
    vals[8] = w1[13];                      // bbb
    vals[9] = bsp1[col];                   // bias (monomial 1)
    for (int k = 0; k < 32; ++k)
        WP1T[col * 32 + k] = (k < 10) ? (__bf16)vals[k] : (__bf16)0.f;
}

// ---------------- kb precompute (once): MFMA poly -> GEMM1 -> gelu -> kb int8 ----------------
__global__ __launch_bounds__(256, 4) void k_kb_i8(
    const float* __restrict__ attr_s,
    const __bf16* __restrict__ W2T, const __bf16* __restrict__ WP1T,
    const float* __restrict__ bsp2,
    signed char* __restrict__ kb8, float* __restrict__ s_r) {
    __shared__ __align__(16) __bf16 H1[64 * 136];
    __shared__ __align__(16) signed char K8[64 * 144];
    __shared__ float rowmaxS[64];
    int t = threadIdx.x;
    int lane = t & 63, w = t >> 6, l15 = lane & 15, quad = lane >> 4;
    size_t grow0 = (size_t)blockIdx.x * 64;
    // ---- poly via MFMA: wave w owns rows w*16 + l15 ----
    {
        float2 ab = ((const float2*)attr_s)[grow0 + w * 16 + l15];
        float a = ab.x, b = ab.y;
        float aa = a * a, abm = a * b, bb = b * b;
        float m0 = quad == 0 ? a        : (quad == 1 ? bb * b : 0.f);
        float m1 = quad == 0 ? b        : (quad == 1 ? 1.f    : 0.f);
        float m2 = quad == 0 ? aa       : 0.f;
        float m3 = quad == 0 ? abm      : 0.f;
        float m4 = quad == 0 ? bb       : 0.f;
        float m5 = quad == 0 ? aa * a   : 0.f;
        float m6 = quad == 0 ? aa * b   : 0.f;
        float m7 = quad == 0 ? abm * b  : 0.f;
        bf16x8 afrag = { (__bf16)m0, (__bf16)m1, (__bf16)m2, (__bf16)m3,
                         (__bf16)m4, (__bf16)m5, (__bf16)m6, (__bf16)m7 };
        #pragma unroll
        for (int n = 0; n < 8; ++n) {
            bf16x8 bp = *(const bf16x8*)(WP1T + (n * 16 + l15) * 32 + quad * 8);
            f32x4 cacc = {0.f, 0.f, 0.f, 0.f};
            cacc = __builtin_amdgcn_mfma_f32_16x16x32_bf16(afrag, bp, cacc, 0, 0, 0);
            #pragma unroll
            for (int rg = 0; rg < 4; ++rg) {
                int row = w * 16 + quad * 4 + rg;
                H1[row * 136 + n * 16 + l15] = (__bf16)gelu_f(cacc[rg]);
            }
        }
    }
    __syncthreads();
    bf16x8 Bf[2][4];
    #pragma unroll
    for (int j = 0; j < 2; ++j)
        #pragma unroll
        for (int ks = 0; ks < 4; ++ks)
            Bf[j][ks] = *(const bf16x8*)(W2T + (size_t)(w * 32 + j * 16 + l15) * 128 + ks * 32 + quad * 8);
    float b2v[2] = { bsp2[w * 32 + l15], bsp2[w * 32 + 16 + l15] };
    f32x4 acc[4][2];
    #pragma unroll
    for (int mt = 0; mt < 4; ++mt) {
        acc[mt][0] = (f32x4){0.f,0.f,0.f,0.f};
        acc[mt][1] = (f32x4){0.f,0.f,0.f,0.f};
        #pragma unroll
        for (int ks = 0; ks < 4; ++ks) {
            bf16x8 af = *(const bf16x8*)(H1 + (mt * 16 + l15) * 136 + ks * 32 + quad * 8);
            acc[mt][0] = __builtin_amdgcn_mfma_f32_16x16x32_bf16(af, Bf[0][ks], acc[mt][0], 0, 0, 0);
            acc[mt][1] = __builtin_amdgcn_mfma_f32_16x16x32_bf16(af, Bf[1][ks], acc[mt][1], 0, 0, 0);
        }
    }
    float g[4][2][4];
    #pragma unroll
    for (int mt = 0; mt < 4; ++mt)
        #pragma unroll
        for (int j = 0; j < 2; ++j)
            #pragma unroll
            for (int rg = 0; rg < 4; ++rg)
                g[mt][j][rg] = gelu_f(acc[mt][j][rg] + b2v[j]);
    __syncthreads();
    #pragma unroll
    for (int mt = 0; mt < 4; ++mt)
        #pragma unroll
        for (int j = 0; j < 2; ++j)
            #pragma unroll
            for (int rg = 0; rg < 4; ++rg) {
                int row = mt * 16 + quad * 4 + rg;
                H1[row * 136 + w * 32 + j * 16 + l15] = (__bf16)g[mt][j][rg];
            }
    __syncthreads();
    if (t < 64) {
        float mx = 0.f;
        #pragma unroll
        for (int ks = 0; ks < 16; ++ks) {
            bf16x8 xv = *(const bf16x8*)(H1 + t * 136 + ks * 8);
            #pragma unroll
            for (int m = 0; m < 8; ++m) mx = fmaxf(mx, fabsf((float)xv[m]));
        }
        float s = fmaxf(mx * (1.0f / 127.0f), 1e-20f);
        rowmaxS[t] = s;
        s_r[grow0 + t] = s;
    }
    __syncthreads();
    #pragma unroll
    for (int mt = 0; mt < 4; ++mt)
        #pragma unroll
        for (int j = 0; j < 2; ++j)
            #pragma unroll
            for (int rg = 0; rg < 4; ++rg) {
                int row = mt * 16 + quad * 4 + rg;
                float inv = __builtin_amdgcn_rcpf(rowmaxS[row]);
                int q = __float2int_rn(g[mt][j][rg] * inv);
                q = q > 127 ? 127 : (q < -127 ? -127 : q);
                K8[row * 144 + w * 32 + j * 16 + l15] = (signed char)q;
            }
    __syncthreads();
    #pragma unroll
    for (int it = 0; it < 2; ++it) {
        int idx = it * 256 + t;
        int row = idx >> 3, cv = idx & 7;
        *(uint4*)(kb8 + (grow0 + row) * 128 + cv * 16) =
            *(const uint4*)(K8 + row * 144 + cv * 16);
    }
}

// -------- fused per-layer GEMM2 + scatter (node-aligned, NO atomics) --------
// Round-22: EB 64 -> 32 (NBLK 1000 -> 2000), continuing the verified
// grid-occupancy mechanism from round 7 (EB 128->64 was -35 µs/dispatch).
__global__ __launch_bounds__(256, 4) void k_gscat2(
    const signed char* __restrict__ kb8, const float* __restrict__ s_r,
    const signed char* __restrict__ Wk8, const float* __restrict__ s_cL,
    const int* __restrict__ send_s, const int* __restrict__ recv_s,
    const int* __restrict__ rowptr, const __bf16* __restrict__ h_bf,
    __bf16* __restrict__ aggb) {
    __shared__ __align__(16) signed char T8[96 * 144];
    __shared__ __align__(16) __bf16 P[96 * 136];
    __shared__ float srS[96];
    int t = threadIdx.x;
    int lane = t & 63, w = t >> 6, l15 = lane & 15, quad = lane >> 4;
    int bid = blockIdx.x;
    int n0, n1;
    {
        if (bid == 0) n0 = 0;
        else {
            int tgt = bid * EB, lo = 0, hi = N_NODES;
            while (lo < hi) { int m = (lo + hi) >> 1; if (rowptr[m] < tgt) lo = m + 1; else hi = m; }
            n0 = lo;
        }
        if (bid == NBLK - 1) n1 = N_NODES;
        else {
            int tgt = (bid + 1) * EB, lo = 0, hi = N_NODES;
            while (lo < hi) { int m = (lo + hi) >> 1; if (rowptr[m] < tgt) lo = m + 1; else hi = m; }
            n1 = lo;
        }
    }
    if (n0 >= n1) return;                    // uniform: no barriers crossed
    int e0 = rowptr[n0], e1 = rowptr[n1];
    long long Bf[2][4];
    #pragma unroll
    for (int j = 0; j < 2; ++j)
        #pragma unroll
        for (int ks = 0; ks < 4; ++ks)
            Bf[j][ks] = *(const long long*)(Wk8 + (size_t)(w * 32 + j * 16 + l15) * 128 + ks * 32 + quad * 8);
    float sc0 = s_cL[w * 32 + l15], sc1 = s_cL[w * 32 + 16 + l15];
    int c = t & 127, half = t >> 7;
    float acc[6] = {0.f, 0.f, 0.f, 0.f, 0.f, 0.f};
    int cur = (e0 < e1) ? recv_s[e0] : -1;
    for (int et0 = e0; et0 < e1; et0 += SE) {
        int cnt = e1 - et0; if (cnt > SE) cnt = SE;
        int nrows = cnt * 12;
        __syncthreads();                     // previous scatter done reading P
        #pragma unroll
        for (int it = 0; it < 3; ++it) {
            int idx = it * 256 + t;
            if (idx < nrows * 8) {
                int row = idx >> 3, cv = idx & 7;
                *(uint4*)(T8 + row * 144 + cv * 16) =
                    *(const uint4*)(kb8 + ((size_t)et0 * 12 + row) * 128 + cv * 16);
            }
        }
        if (t < nrows) srS[t] = s_r[(size_t)et0 * 12 + t];
        __syncthreads();
        int nrt = (nrows + 15) >> 4;
        for (int rt = 0; rt < nrt; ++rt) {
            i32x4 a0 = (i32x4){0, 0, 0, 0};
            i32x4 a1 = (i32x4){0, 0, 0, 0};
            #pragma unroll
            for (int ks = 0; ks < 4; ++ks) {
                long long a = *(const long long*)(T8 + (rt * 16 + l15) * 144 + ks * 32 + quad * 8);
                a0 = __builtin_amdgcn_mfma_i32_16x16x32_i8(a, Bf[0][ks], a0, 0, 0, 0);
                a1 = __builtin_amdgcn_mfma_i32_16x16x32_i8(a, Bf[1][ks], a1, 0, 0, 0);
            }
            #pragma unroll
            for (int rg = 0; rg < 4; ++rg) {
                int row = rt * 16 + quad * 4 + rg;
                float sr = srS[row];
                P[row * 136 + w * 32 + l15]      = (__bf16)((float)a0[rg] * sr * sc0);
                P[row * 136 + w * 32 + 16 + l15] = (__bf16)((float)a1[rg] * sr * sc1);
            }
        }
        __syncthreads();
        for (int el = 0; el < cnt; ++el) {
            int e = et0 + el;
            int r = recv_s[e];
            if (r != cur) {
                __bf16* op = aggb + ((size_t)cur * 128 + c) * 12 + half * 6;
                #pragma unroll
                for (int j = 0; j < 6; ++j) { op[j] = (__bf16)acc[j]; acc[j] = 0.f; }
                cur = r;
            }
            int s = send_s[e];
            const __bf16* hp = h_bf + (size_t)s * 1536 + half * 6 * 128 + c;
            const __bf16* pp = P + (el * 12 + half * 6) * 136 + c;
            #pragma unroll
            for (int j = 0; j < 6; ++j)
                acc[j] += (float)hp[j * 128] * (float)pp[j * 136];
        }
    }
    if (e0 < e1) {
        __bf16* op = aggb + ((size_t)cur * 128 + c) * 12 + half * 6;
        #pragma unroll
        for (int j = 0; j < 6; ++j) op[j] = (__bf16)acc[j];
    }
    for (int n = n0; n < n1; ++n) {
        if (rowptr[n] == rowptr[n + 1]) {
            __bf16* op = aggb + ((size_t)n * 128 + c) * 12 + half * 6;
            #pragma unroll
            for (int j = 0; j < 6; ++j) op[j] = (__bf16)0.f;
        }
    }
}

// ---------------- node kernel: conv + LN + MFMA MLP + MFMA readout ----------------
// Round-22: round-7 verified version, UNTOUCHED (158 µs). (256,6) attempts
// regressed twice: HBM traffic triples at 6 blocks/CU regardless of store
// pattern (L2 residency effect, rounds 6+8). Keep 4 blocks/CU.
__global__ __launch_bounds__(256, 4) void k_mlp(
    const __bf16* __restrict__ aggb, const float* __restrict__ fkl,
    const float* __restrict__ bconv, const float* __restrict__ ln_g,
    const float* __restrict__ ln_b,
    const __bf16* __restrict__ W1T, const float* __restrict__ b1,
    const __bf16* __restrict__ W2T2, const float* __restrict__ b2,
    const float* __restrict__ Wro, const float* __restrict__ bro,
    __bf16* __restrict__ h_bf, float* __restrict__ readout) {
    __shared__ __align__(16) __bf16 X[48 * 136];
    __shared__ __align__(16) __bf16 H4[48 * 136];
    __shared__ __align__(16) __bf16 WroT[16 * 136];
    __shared__ float redS[48][2];
    int t = threadIdx.x;
    int lane = t & 63, w = t >> 6, l15 = lane & 15, quad = lane >> 4;
    int c = t & 127, nh = t >> 7;
    int n0 = blockIdx.x * MNPB;
    // stage Wro as MFMA B-fragment layout [col][k], cols 9..15 zero
    for (int i = t; i < 2048; i += 256) {
        int col = i >> 7, k = i & 127;
        WroT[col * 136 + k] = (col < 9) ? (__bf16)Wro[k * 9 + col] : (__bf16)0.f;
    }
    float bcv = bconv[c];
    // ---- conv: thread owns channel c, nodes {nh, nh+2} ----
    {
        float a2[2][12];
        #pragma unroll
        for (int u = 0; u < 2; ++u) {
            const __bf16* ap = aggb + ((size_t)(n0 + nh + u * 2) * 128 + c) * 12;
            #pragma unroll
            for (int v = 0; v < 3; ++v) {
                bf16x4 pk = *(const bf16x4*)(ap + v * 4);
                #pragma unroll
                for (int j = 0; j < 4; ++j) a2[u][v * 4 + j] = (float)pk[j];
            }
        }
        #pragma unroll 4
        for (int p = 0; p < 12; ++p) {
            const float* fp = fkl + ((size_t)p * 128 + c) * 12;
            float fr[12];
            #pragma unroll
            for (int v = 0; v < 3; ++v) {
                float4 fv = *(const float4*)(fp + v * 4);
                fr[v*4+0] = fv.x; fr[v*4+1] = fv.y; fr[v*4+2] = fv.z; fr[v*4+3] = fv.w;
            }
            float s0 = 0.f, s1 = 0.f;
            #pragma unroll
            for (int o = 0; o < 12; ++o) {
                s0 += a2[0][o] * fr[o];
                s1 += a2[1][o] * fr[o];
            }
            X[(nh * 12 + p) * 136 + c]       = (__bf16)(s0 * (1.0f / 12.0f) + bcv);
            X[((nh + 2) * 12 + p) * 136 + c] = (__bf16)(s1 * (1.0f / 12.0f) + bcv);
        }
    }
    __syncthreads();
    // ---- LN stats ----
    for (int r = w * 12; r < w * 12 + 12; ++r) {
        float v0 = (float)X[r * 136 + lane];
        float v1 = (float)X[r * 136 + 64 + lane];
        float s = v0 + v1, s2 = v0 * v0 + v1 * v1;
        for (int off = 32; off > 0; off >>= 1) {
            s += __shfl_down(s, off);
            s2 += __shfl_down(s2, off);
        }
        if (lane == 0) {
            float mu = s * (1.0f / 128.0f);
            float var = s2 * (1.0f / 128.0f) - mu * mu;
            redS[r][0] = mu;
            redS[r][1] = rsqrtf(var + 1e-5f);
        }
    }
    __syncthreads();
    float gv = ln_g[c], bv = ln_b[c];
    #pragma unroll
    for (int nn = nh; nn < 4; nn += 2)
        #pragma unroll
        for (int p = 0; p < 12; ++p) {
            int r = nn * 12 + p;
            float v = (float)X[r * 136 + c];
            X[r * 136 + c] = (__bf16)((v - redS[r][0]) * redS[r][1] * gv + bv);
        }
    __syncthreads();
    // ---- MLP: 4 phases of 128 hidden cols ----
    f32x4 acc2[3][2];
    #pragma unroll
    for (int mt = 0; mt < 3; ++mt)
        #pragma unroll
        for (int j = 0; j < 2; ++j) acc2[mt][j] = (f32x4){0.f, 0.f, 0.f, 0.f};
    for (int ph = 0; ph < 4; ++ph) {
        if (ph) __syncthreads();
        #pragma unroll
        for (int mt = 0; mt < 3; ++mt) {
            bf16x8 af[4];
            #pragma unroll
            for (int ks = 0; ks < 4; ++ks)
                af[ks] = *(const bf16x8*)(X + (mt * 16 + l15) * 136 + ks * 32 + quad * 8);
            #pragma unroll
            for (int nt = 0; nt < 2; ++nt) {
                int colf = ph * 128 + w * 32 + nt * 16 + l15;
                f32x4 a = {0.f, 0.f, 0.f, 0.f};
                #pragma unroll
                for (int ks = 0; ks < 4; ++ks) {
                    bf16x8 bf = *(const bf16x8*)(W1T + (size_t)colf * 128 + ks * 32 + quad * 8);
                    a = __builtin_amdgcn_mfma_f32_16x16x32_bf16(af[ks], bf, a, 0, 0, 0);
                }
                float bj = b1[colf];
                #pragma unroll
                for (int rg = 0; rg < 4; ++rg) {
                    int row = mt * 16 + quad * 4 + rg;
                    H4[row * 136 + w * 32 + nt * 16 + l15] = (__bf16)gelu_f(a[rg] + bj);
                }
            }
        }
        __syncthreads();
        #pragma unroll
        for (int mt = 0; mt < 3; ++mt)
            #pragma unroll
            for (int ks = 0; ks < 4; ++ks) {
                bf16x8 af = *(const bf16x8*)(H4 + (mt * 16 + l15) * 136 + ks * 32 + quad * 8);
                #pragma unroll
                for (int j = 0; j < 2; ++j) {
                    int col = w * 32 + j * 16 + l15;
                    bf16x8 bf = *(const bf16x8*)(W2T2 + (size_t)col * 512 + ph * 128 + ks * 32 + quad * 8);
                    acc2[mt][j] = __builtin_amdgcn_mfma_f32_16x16x32_bf16(af, bf, acc2[mt][j], 0, 0, 0);
                }
            }
    }
    // ---- residual h update (writes h_bf + X) ----
    #pragma unroll
    for (int mt = 0; mt < 3; ++mt) {
        float bj0 = b2[w * 32 + l15], bj1 = b2[w * 32 + 16 + l15];
        #pragma unroll
        for (int rg = 0; rg < 4; ++rg) {
            int row = mt * 16 + quad * 4 + rg;
            int node = n0 + row / 12, pp = row % 12;
            size_t hi = ((size_t)node * 12 + pp) * 128;
            {
                int col = w * 32 + l15;
                float hv = (float)h_bf[hi + col] + acc2[mt][0][rg] + bj0;
                h_bf[hi + col] = (__bf16)hv;
                X[row * 136 + col] = (__bf16)hv;
            }
            {
                int col = w * 32 + 16 + l15;
                float hv = (float)h_bf[hi + col] + acc2[mt][1][rg] + bj1;
                h_bf[hi + col] = (__bf16)hv;
                X[row * 136 + col] = (__bf16)hv;
            }
        }
    }
    __syncthreads();
    // ---- readout via MFMA: waves 0..2 each do 16 rows x 16 cols (9 real) ----
    if (w < 3) {
        int mt = w;
        f32x4 a = {0.f, 0.f, 0.f, 0.f};
        #pragma unroll
        for (int ks = 0; ks < 4; ++ks) {
            bf16x8 af = *(const bf16x8*)(X + (mt * 16 + l15) * 136 + ks * 32 + quad * 8);
            bf16x8 bf = *(const bf16x8*)(WroT + l15 * 136 + ks * 32 + quad * 8);
            a = __builtin_amdgcn_mfma_f32_16x16x32_bf16(af, bf, a, 0, 0, 0);
        }
        if (l15 < 9) {
            float bj = bro[l15];
            #pragma unroll
            for (int rg = 0; rg < 4; ++rg) {
                int row = mt * 16 + quad * 4 + rg;
                int node = n0 + row / 12, pp = row % 12;
                size_t ri = ((size_t)node * 12 + pp) * 9 + l15;
                readout[ri] += (a[rg] + bj) * (1.0f / 3.0f);
            }
        }
    }
}

// ---------------- final pooling ----------------
__global__ __launch_bounds__(128) void k_out(
    const float* __restrict__ readout, const float* __restrict__ node_grid,
    const int* __restrict__ batch, float* __restrict__ out) {
    int n = blockIdx.x * 128 + threadIdx.x;
    if (n >= N_NODES) return;
    int b = batch[n];
    const float* ro = readout + (size_t)n * 108;
    float ss[8] = {0, 0, 0, 0, 0, 0, 0, 0};
    float v0 = 0.f, v1 = 0.f, v2 = 0.f;
    for (int p = 0; p < 12; ++p) {
        #pragma unroll
        for (int j = 0; j < 8; ++j) ss[j] += ro[p * 9 + j];
        float rv = ro[p * 9 + 8];
        v0 += rv * node_grid[n * 36 + p * 3 + 0];
        v1 += rv * node_grid[n * 36 + p * 3 + 1];
        v2 += rv * node_grid[n * 36 + p * 3 + 2];
    }
    #pragma unroll
    for (int j = 0; j < 8; ++j) atomicAdd(&out[b * 8 + j], ss[j] * (1.0f / 12.0f));
    atomicAdd(&out[512 + b * 3 + 0], v0 * (1.0f / 12.0f));
    atomicAdd(&out[512 + b * 3 + 1], v1 * (1.0f / 12.0f));
    atomicAdd(&out[512 + b * 3 + 2], v2 * (1.0f / 12.0f));
}

extern "C" void kernel_launch(void* const* d_in, const int* in_sizes, int n_in,
                              void* d_out, int out_size, void* d_ws, size_t ws_size,
                              hipStream_t stream) {
    const float* x    = (const float*)d_in[0];
    const float* vec  = (const float*)d_in[1];
    const float* pos  = (const float*)d_in[2];
    const float* Q    = (const float*)d_in[3];
    const float* Wsp1 = (const float*)d_in[4];
    const float* bsp1 = (const float*)d_in[5];
    const float* Wsp2 = (const float*)d_in[6];
    const float* bsp2 = (const float*)d_in[7];
    const float* Wsh1 = (const float*)d_in[8];
    const float* bsh1 = (const float*)d_in[9];
    const float* Wsh2 = (const float*)d_in[10];
    const float* bsh2 = (const float*)d_in[11];
    const float* Wemb = (const float*)d_in[12];
    const float* Wk   = (const float*)d_in[13];
    const float* Wfk  = (const float*)d_in[14];
    const float* bconv= (const float*)d_in[15];
    const float* ln_g = (const float*)d_in[16];
    const float* ln_b = (const float*)d_in[17];
    const float* W1   = (const float*)d_in[18];
    const float* b1   = (const float*)d_in[19];
    const float* W2   = (const float*)d_in[20];
    const float* b2   = (const float*)d_in[21];
    const float* Wro  = (const float*)d_in[22];
    const float* bro  = (const float*)d_in[23];
    const int* ei     = (const int*)d_in[24];
    const int* batch  = (const int*)d_in[25];
    const int* send = ei;
    const int* recv = ei + N_EDGES;

    float* ws = (float*)d_ws;
    float* grid0  = ws;
    float* grid   = ws + 64;
    float* fk     = ws + 2368;
    float* ng     = ws + 57664;
    float* ro     = ws + 345664;
    float* attr_s = ws + 1209664;
    const size_t P_WT  = 2746048;            // bf16 WT: 458752 bf16
    const size_t P_WK8 = P_WT + 229376;      // int8 Wk: 49152 B
    const size_t P_SC  = P_WK8 + 12288;      // col scales
    const size_t P_WP  = P_SC + 384;         // WP1T: 4096 bf16
    const size_t P_H   = P_WP + 2048;        // h bf16
    const size_t P_AGG = P_H + 6144000;      // aggb
    const size_t P_KB8 = P_AGG + 6144000;    // kb int8 (98.3 MB)
    const size_t P_SR  = P_KB8 + 24576000;   // row scales
    const size_t T_INT = P_SR + 768000;
    const size_t NEED  = (T_INT + 216096) * 4ull;   // ~163 MB

    if (ws_size < NEED) return;

    __bf16* WT   = (__bf16*)(ws + P_WT);
    signed char* Wk8 = (signed char*)(ws + P_WK8);
    float* s_c   = ws + P_SC;
    __bf16* WP1T = (__bf16*)(ws + P_WP);
    __bf16* hA   = (__bf16*)(ws + P_H);
    __bf16* aggb = (__bf16*)(ws + P_AGG);
    signed char* kb8 = (signed char*)(ws + P_KB8);
    float* s_r   = ws + P_SR;
    int*   ibase = (int*)(ws + T_INT);
    int* deg    = ibase;
    int* cursor = ibase + 8000;
    int* rowptr = ibase + 16000;
    int* perm   = ibase + 24064;
    int* send_s = ibase + 88064;
    int* recv_s = ibase + 152080;

    const __bf16* Wsp2T = WT;
    const __bf16* W1T   = WT + 65536;
    const __bf16* W2T   = WT + 65536 + 3 * 65536;

    hipMemsetAsync(d_out, 0, sizeof(float) * (size_t)out_size, stream);
    hipMemsetAsync(ro, 0, sizeof(float) * 864000, stream);
    hipMemsetAsync(deg, 0, sizeof(int) * 8000, stream);

    k_grid<<<1, 256, 0, stream>>>(Q, grid0, grid);
    k_kbsh<<<144, 128, 0, stream>>>(grid0, Wsh1, bsh1, Wsh2, bsh2, Wfk, fk);
    k_embed<<<N_NODES / ENPB, 128, 0, stream>>>(x, vec, batch, grid, Wemb, ng, hA);
    k_deg<<<250, 256, 0, stream>>>(recv, deg);
    k_scan<<<1, 1024, 0, stream>>>(deg, rowptr, cursor);
    k_fill<<<250, 256, 0, stream>>>(recv, cursor, perm);
    k_attr_sorted<<<((N_EDGES + 16) * 12 + 255) / 256, 256, 0, stream>>>(
        pos, ng, send, recv, perm, attr_s, send_s, recv_s);
    k_prepw2<<<(7 * 65536 + 255) / 256, 256, 0, stream>>>(Wsp2, Wk, W1, W2, WT);
    k_prepw_i8<<<3, 128, 0, stream>>>(Wk, Wk8, s_c);
    k_prepw_p<<<1, 128, 0, stream>>>(Wsp1, bsp1, WP1T);

    k_kb_i8<<<N_EDGES * 12 / 64, 256, 0, stream>>>(attr_s, Wsp2T, WP1T, bsp2, kb8, s_r);

    for (int l = 0; l < 3; ++l) {
        k_gscat2<<<NBLK, 256, 0, stream>>>(kb8, s_r,
            Wk8 + (size_t)l * 16384, s_c + l * 128,
            send_s, recv_s, rowptr, hA, aggb);
        k_mlp<<<N_NODES / MNPB, 256, 0, stream>>>(aggb, fk + l * 18432,
            bconv + l * 128, ln_g + l * 128, ln_b + l * 128,
            W1T + l * 65536, b1 + l * 512, W2T + l * 65536, b2 + l * 128,
            Wro + l * 1152, bro + l * 9, hA, ro);
    }
    k_out<<<(N_NODES + 127) / 128, 128, 0, stream>>>(ro, ng, batch, (float*)d_out);
}

// Round 10
// 1041.742 us; speedup vs baseline: 1.1010x; 1.0177x over previous
//
#include <hip/hip_runtime.h>
#include <hip/hip_bf16.h>

#define N_NODES 8000
#define N_EDGES 64000
#define NBATCH  64
#define NGRID   12
#define HIDC    128
#define MNPB    8
#define EB      64
#define SE      8
#define NBLK    (N_EDGES / EB)

typedef __bf16 bf16x8 __attribute__((ext_vector_type(8)));
typedef __bf16 bf16x4 __attribute__((ext_vector_type(4)));
typedef float  f32x4  __attribute__((ext_vector_type(4)));
typedef int    i32x4  __attribute__((ext_vector_type(4)));

// gelu = x * sigmoid(2u); fast v_rcp (err ~1e-6)
__device__ __forceinline__ float gelu_f(float x) {
    float u = 0.7978845608f * x * (1.0f + 0.044715f * x * x);
    float e = __expf(2.0f * u);
    float r = __builtin_amdgcn_rcpf(e + 1.0f);
    return x * (1.0f - r);
}

// ---------------- grid0 + per-batch rotated grids ----------------
__global__ void k_grid(const float* __restrict__ Q, float* __restrict__ grid0,
                       float* __restrict__ grid) {
    int t = threadIdx.x;
    __shared__ float g0[12][3];
    if (t < 12) {
        float fi = (float)t;
        float theta = 6.28318530717958647692f * fi / 1.61803398874989484820f;
        float z = 1.0f - (2.0f * fi + 1.0f) / 12.0f;
        float r = sqrtf(fmaxf(1.0f - z * z, 0.0f));
        g0[t][0] = r * cosf(theta);
        g0[t][1] = r * sinf(theta);
        g0[t][2] = z;
        grid0[t * 3 + 0] = g0[t][0];
        grid0[t * 3 + 1] = g0[t][1];
        grid0[t * 3 + 2] = g0[t][2];
    }
    __syncthreads();
    for (int idx = t; idx < NBATCH * 12 * 3; idx += blockDim.x) {
        int b = idx / 36, rmd = idx % 36, n = rmd / 3, i = rmd % 3;
        float acc = 0.f;
        #pragma unroll
        for (int j = 0; j < 3; ++j) acc += Q[b * 9 + i * 3 + j] * g0[n][j];
        grid[idx] = acc;
    }
}

// ---------------- kb_sh -> fk  (fk layout: [l][p][c][o]) ----------------
__global__ __launch_bounds__(128) void k_kbsh(
    const float* __restrict__ grid0,
    const float* __restrict__ Wsh1, const float* __restrict__ bsh1,
    const float* __restrict__ Wsh2, const float* __restrict__ bsh2,
    const float* __restrict__ Wfk, float* __restrict__ fk) {
    int row = blockIdx.x;
    int p = row / 12, o = row % 12, t = threadIdx.x;
    float tt = grid0[p*3]*grid0[o*3] + grid0[p*3+1]*grid0[o*3+1] + grid0[p*3+2]*grid0[o*3+2];
    float p1 = tt, p2 = tt * tt, p3 = p2 * tt;
    float h1 = gelu_f(p1 * Wsh1[t] + p2 * Wsh1[128 + t] + p3 * Wsh1[256 + t] + bsh1[t]);
    __shared__ float h1S[128];
    __shared__ float h2S[128];
    h1S[t] = h1;
    __syncthreads();
    float acc = bsh2[t];
    #pragma unroll 8
    for (int k = 0; k < 128; ++k) acc += h1S[k] * Wsh2[k * 128 + t];
    h2S[t] = gelu_f(acc);
    __syncthreads();
    for (int l = 0; l < 3; ++l) {
        float a = 0.f;
        #pragma unroll 8
        for (int k = 0; k < 128; ++k) a += h2S[k] * Wfk[l * 16384 + k * 128 + t];
        fk[l * 18432 + (p * 128 + t) * 12 + o] = a;
    }
}

// ---------------- embed (round-7 verified version) ----------------
__global__ __launch_bounds__(128) void k_embed(
    const float* __restrict__ x, const float* __restrict__ vec,
    const int* __restrict__ batch, const float* __restrict__ grid,
    const float* __restrict__ Wemb, float* __restrict__ node_grid,
    __bf16* __restrict__ h_bf) {
    __shared__ float WembS[18 * 128];
    __shared__ float ngS[36];
    __shared__ float xS[16];
    __shared__ float vS[6];
    int n = blockIdx.x, t = threadIdx.x;
    for (int i = t; i < 18 * 128; i += 128) WembS[i] = Wemb[i];
    int b = batch[n];
    if (t < 36) { float g = grid[b * 36 + t]; ngS[t] = g; node_grid[n * 36 + t] = g; }
    if (t < 16) xS[t] = x[n * 16 + t];
    if (t >= 16 && t < 22) vS[t - 16] = vec[n * 6 + (t - 16)];
    __syncthreads();
    for (int g = 0; g < NGRID; ++g) {
        float g0 = ngS[g*3], g1 = ngS[g*3+1], g2 = ngS[g*3+2];
        float xv0 = vS[0]*g0 + vS[1]*g1 + vS[2]*g2;
        float xv1 = vS[3]*g0 + vS[4]*g1 + vS[5]*g2;
        float acc = xv0 * WembS[16*128 + t] + xv1 * WembS[17*128 + t];
        #pragma unroll
        for (int j = 0; j < 16; ++j) acc += xS[j] * WembS[j*128 + t];
        h_bf[((size_t)n * NGRID + g) * HIDC + t] = (__bf16)acc;
    }
}

// ---------------- CSR build ----------------
__global__ __launch_bounds__(256) void k_deg(const int* __restrict__ recv,
                                             int* __restrict__ deg) {
    int e = blockIdx.x * 256 + threadIdx.x;
    if (e < N_EDGES) atomicAdd(&deg[recv[e]], 1);
}

__global__ __launch_bounds__(1024) void k_scan(const int* __restrict__ deg,
                                               int* __restrict__ rowptr,
                                               int* __restrict__ cursor) {
    __shared__ int part[1024];
    int t = threadIdx.x;
    int base = t * 8;
    int local[8];
    int s = 0;
    #pragma unroll
    for (int j = 0; j < 8; ++j) {
        int idx = base + j;
        int v = (idx < N_NODES) ? deg[idx] : 0;
        local[j] = s;
        s += v;
    }
    part[t] = s;
    __syncthreads();
    for (int off = 1; off < 1024; off <<= 1) {
        int v = (t >= off) ? part[t - off] : 0;
        __syncthreads();
        part[t] += v;
        __syncthreads();
    }
    int excl = (t == 0) ? 0 : part[t - 1];
    #pragma unroll
    for (int j = 0; j < 8; ++j) {
        int idx = base + j;
        if (idx < N_NODES) {
            int v = excl + local[j];
            rowptr[idx] = v;
            cursor[idx] = v;
        }
    }
    if (t == 1023) rowptr[N_NODES] = part[1023];
}

__global__ __launch_bounds__(256) void k_fill(const int* __restrict__ recv,
                                              int* __restrict__ cursor,
                                              int* __restrict__ perm) {
    int e = blockIdx.x * 256 + threadIdx.x;
    if (e < N_EDGES) {
        int r = recv[e];
        int p = atomicAdd(&cursor[r], 1);
        perm[p] = e;
    }
}

// ---------------- attrs (recv-sorted) ----------------
__global__ __launch_bounds__(256) void k_attr_sorted(
    const float* __restrict__ pos, const float* __restrict__ ng,
    const int* __restrict__ send, const int* __restrict__ recv,
    const int* __restrict__ perm,
    float* __restrict__ attr_s, int* __restrict__ send_s,
    int* __restrict__ recv_s) {
    int idx = blockIdx.x * 256 + threadIdx.x;
    if (idx >= (N_EDGES + 16) * 12) return;
    int i = idx / 12, g = idx % 12;
    if (i < N_EDGES) {
        int e = perm[i];
        int s = send[e], r = recv[e];
        float rx = pos[s*3+0] - pos[r*3+0];
        float ry = pos[s*3+1] - pos[r*3+1];
        float rz = pos[s*3+2] - pos[r*3+2];
        const float* gr = ng + ((size_t)r * 12 + g) * 3;
        float g0 = gr[0], g1 = gr[1], g2 = gr[2];
        float iv1 = rx*g0 + ry*g1 + rz*g2;
        float wx = rx - iv1*g0, wy = ry - iv1*g1, wz = rz - iv1*g2;
        attr_s[(size_t)idx * 2 + 0] = iv1;
        attr_s[(size_t)idx * 2 + 1] = sqrtf(wx*wx + wy*wy + wz*wz);
        if (g == 0) { send_s[i] = s; recv_s[i] = r; }
    } else {
        attr_s[(size_t)idx * 2 + 0] = 0.f;
        attr_s[(size_t)idx * 2 + 1] = 0.f;
        if (g == 0) { send_s[i] = 0; recv_s[i] = 0; }
    }
}

// ---- transposed bf16 weights [Wsp2T | WkT | W1T | W2T] ----
__global__ __launch_bounds__(256) void k_prepw2(
    const float* __restrict__ Wsp2, const float* __restrict__ Wk,
    const float* __restrict__ W1, const float* __restrict__ W2,
    __bf16* __restrict__ WT) {
    int i = blockIdx.x * 256 + threadIdx.x;
    if (i >= 7 * 65536) return;
    float v;
    if (i < 65536) {
        int buf = i >> 14, r = i & 16383;
        int n = r >> 7, k = r & 127;
        v = (buf == 0) ? Wsp2[k * 128 + n] : Wk[(buf - 1) * 16384 + k * 128 + n];
    } else {
        int i2 = i - 65536;
        int l = i2 >> 16, r = i2 & 65535;
        if (l < 3) {
            int n = r >> 7, k = r & 127;
            v = W1[l * 65536 + k * 512 + n];
        } else {
            int l2 = l - 3;
            int n = r >> 9, k = r & 511;
            v = W2[l2 * 65536 + k * 128 + n];
        }
    }
    WT[i] = (__bf16)v;
}

// ---- int8 Wk (transposed, per-column scales) ----
__global__ __launch_bounds__(128) void k_prepw_i8(
    const float* __restrict__ Wk, signed char* __restrict__ Wk8,
    float* __restrict__ s_c) {
    int i = blockIdx.x * 128 + threadIdx.x;
    if (i >= 384) return;
    int l = i / 128, col = i % 128;
    float mx = 0.f;
    for (int k = 0; k < 128; ++k)
        mx = fmaxf(mx, fabsf(Wk[l * 16384 + k * 128 + col]));
    float s = fmaxf(mx * (1.0f / 127.0f), 1e-20f);
    s_c[i] = s;
    float inv = 127.0f / fmaxf(mx, 1e-20f);
    for (int k = 0; k < 128; ++k) {
        int q = __float2int_rn(Wk[l * 16384 + k * 128 + col] * inv);
        q = q > 127 ? 127 : (q < -127 ? -127 : q);
        Wk8[(size_t)l * 16384 + col * 128 + k] = (signed char)q;
    }
}

// ---- combined poly weights WP1T [128 cols x 32 k] bf16 (bias at k=9) ----
__global__ __launch_bounds__(128) void k_prepw_p(
    const float* __restrict__ Wsp1, const float* __restrict__ bsp1,
    __bf16* __restrict__ WP1T) {
    int col = threadIdx.x;
    float w1[14];
    #pragma unroll
    for (int j = 0; j < 14; ++j) w1[j] = Wsp1[j * 128 + col];
    float vals[10];
    vals[0] = w1[0];                       // a
    vals[1] = w1[1];                       // b
    vals[2] = w1[2];                       // aa
    vals[3] = w1[3] + w1[4];               // ab
    vals[4] = w1[5];                       // bb
    vals[5] = w1[6];                       // aaa
    vals[6] = w1[7] + w1[8] + w1[10];      // aab
    vals[7] = w1[9] + w1[11] + w1[12];     // abb
    vals[8] = w1[13];                      // bbb
    vals[9] = bsp1[col];                   // bias (monomial 1)
    for (int k = 0; k < 32; ++k)
        WP1T[col * 32 + k] = (k < 10) ? (__bf16)vals[k] : (__bf16)0.f;
}

// ---- Wro packed per-layer into MFMA B-fragment per-lane layout ----
// WroF[l][lane][ks*8+j] = bf16( col<9 ? Wro[l][k*9+col] : 0 ),
//   col = lane&15, k = ks*32 + (lane>>4)*8 + j.  (verified rounds 6+8)
__global__ __launch_bounds__(192) void k_prepw_ro(
    const float* __restrict__ Wro, __bf16* __restrict__ WroF) {
    int t = threadIdx.x;
    int l = t / 64, lane = t % 64;
    int l15 = lane & 15, quad = lane >> 4;
    #pragma unroll
    for (int ks = 0; ks < 4; ++ks)
        #pragma unroll
        for (int j = 0; j < 8; ++j) {
            int k = ks * 32 + quad * 8 + j;
            float v = (l15 < 9) ? Wro[l * 1152 + k * 9 + l15] : 0.f;
            WroF[(size_t)(l * 64 + lane) * 32 + ks * 8 + j] = (__bf16)v;
        }
}

// ---------------- kb precompute (once): MFMA poly -> GEMM1 -> gelu -> kb int8 ----------------
__global__ __launch_bounds__(256, 4) void k_kb_i8(
    const float* __restrict__ attr_s,
    const __bf16* __restrict__ W2T, const __bf16* __restrict__ WP1T,
    const float* __restrict__ bsp2,
    signed char* __restrict__ kb8, float* __restrict__ s_r) {
    __shared__ __align__(16) __bf16 H1[64 * 136];
    __shared__ __align__(16) signed char K8[64 * 144];
    __shared__ float rowmaxS[64];
    int t = threadIdx.x;
    int lane = t & 63, w = t >> 6, l15 = lane & 15, quad = lane >> 4;
    size_t grow0 = (size_t)blockIdx.x * 64;
    // ---- poly via MFMA: wave w owns rows w*16 + l15 ----
    {
        float2 ab = ((const float2*)attr_s)[grow0 + w * 16 + l15];
        float a = ab.x, b = ab.y;
        float aa = a * a, abm = a * b, bb = b * b;
        float m0 = quad == 0 ? a        : (quad == 1 ? bb * b : 0.f);
        float m1 = quad == 0 ? b        : (quad == 1 ? 1.f    : 0.f);
        float m2 = quad == 0 ? aa       : 0.f;
        float m3 = quad == 0 ? abm      : 0.f;
        float m4 = quad == 0 ? bb       : 0.f;
        float m5 = quad == 0 ? aa * a   : 0.f;
        float m6 = quad == 0 ? aa * b   : 0.f;
        float m7 = quad == 0 ? abm * b  : 0.f;
        bf16x8 afrag = { (__bf16)m0, (__bf16)m1, (__bf16)m2, (__bf16)m3,
                         (__bf16)m4, (__bf16)m5, (__bf16)m6, (__bf16)m7 };
        #pragma unroll
        for (int n = 0; n < 8; ++n) {
            bf16x8 bp = *(const bf16x8*)(WP1T + (n * 16 + l15) * 32 + quad * 8);
            f32x4 cacc = {0.f, 0.f, 0.f, 0.f};
            cacc = __builtin_amdgcn_mfma_f32_16x16x32_bf16(afrag, bp, cacc, 0, 0, 0);
            #pragma unroll
            for (int rg = 0; rg < 4; ++rg) {
                int row = w * 16 + quad * 4 + rg;
                H1[row * 136 + n * 16 + l15] = (__bf16)gelu_f(cacc[rg]);
            }
        }
    }
    __syncthreads();
    bf16x8 Bf[2][4];
    #pragma unroll
    for (int j = 0; j < 2; ++j)
        #pragma unroll
        for (int ks = 0; ks < 4; ++ks)
            Bf[j][ks] = *(const bf16x8*)(W2T + (size_t)(w * 32 + j * 16 + l15) * 128 + ks * 32 + quad * 8);
    float b2v[2] = { bsp2[w * 32 + l15], bsp2[w * 32 + 16 + l15] };
    f32x4 acc[4][2];
    #pragma unroll
    for (int mt = 0; mt < 4; ++mt) {
        acc[mt][0] = (f32x4){0.f,0.f,0.f,0.f};
        acc[mt][1] = (f32x4){0.f,0.f,0.f,0.f};
        #pragma unroll
        for (int ks = 0; ks < 4; ++ks) {
            bf16x8 af = *(const bf16x8*)(H1 + (mt * 16 + l15) * 136 + ks * 32 + quad * 8);
            acc[mt][0] = __builtin_amdgcn_mfma_f32_16x16x32_bf16(af, Bf[0][ks], acc[mt][0], 0, 0, 0);
            acc[mt][1] = __builtin_amdgcn_mfma_f32_16x16x32_bf16(af, Bf[1][ks], acc[mt][1], 0, 0, 0);
        }
    }
    float g[4][2][4];
    #pragma unroll
    for (int mt = 0; mt < 4; ++mt)
        #pragma unroll
        for (int j = 0; j < 2; ++j)
            #pragma unroll
            for (int rg = 0; rg < 4; ++rg)
                g[mt][j][rg] = gelu_f(acc[mt][j][rg] + b2v[j]);
    __syncthreads();
    #pragma unroll
    for (int mt = 0; mt < 4; ++mt)
        #pragma unroll
        for (int j = 0; j < 2; ++j)
            #pragma unroll
            for (int rg = 0; rg < 4; ++rg) {
                int row = mt * 16 + quad * 4 + rg;
                H1[row * 136 + w * 32 + j * 16 + l15] = (__bf16)g[mt][j][rg];
            }
    __syncthreads();
    if (t < 64) {
        float mx = 0.f;
        #pragma unroll
        for (int ks = 0; ks < 16; ++ks) {
            bf16x8 xv = *(const bf16x8*)(H1 + t * 136 + ks * 8);
            #pragma unroll
            for (int m = 0; m < 8; ++m) mx = fmaxf(mx, fabsf((float)xv[m]));
        }
        float s = fmaxf(mx * (1.0f / 127.0f), 1e-20f);
        rowmaxS[t] = s;
        s_r[grow0 + t] = s;
    }
    __syncthreads();
    #pragma unroll
    for (int mt = 0; mt < 4; ++mt)
        #pragma unroll
        for (int j = 0; j < 2; ++j)
            #pragma unroll
            for (int rg = 0; rg < 4; ++rg) {
                int row = mt * 16 + quad * 4 + rg;
                float inv = __builtin_amdgcn_rcpf(rowmaxS[row]);
                int q = __float2int_rn(g[mt][j][rg] * inv);
                q = q > 127 ? 127 : (q < -127 ? -127 : q);
                K8[row * 144 + w * 32 + j * 16 + l15] = (signed char)q;
            }
    __syncthreads();
    #pragma unroll
    for (int it = 0; it < 2; ++it) {
        int idx = it * 256 + t;
        int row = idx >> 3, cv = idx & 7;
        *(uint4*)(kb8 + (grow0 + row) * 128 + cv * 16) =
            *(const uint4*)(K8 + row * 144 + cv * 16);
    }
}

// -------- fused per-layer GEMM2 + scatter (node-aligned, NO atomics) --------
// EB=64 (round-7 verified optimum; EB=32 was +16 µs total — reverted).
__global__ __launch_bounds__(256, 4) void k_gscat2(
    const signed char* __restrict__ kb8, const float* __restrict__ s_r,
    const signed char* __restrict__ Wk8, const float* __restrict__ s_cL,
    const int* __restrict__ send_s, const int* __restrict__ recv_s,
    const int* __restrict__ rowptr, const __bf16* __restrict__ h_bf,
    __bf16* __restrict__ aggb) {
    __shared__ __align__(16) signed char T8[96 * 144];
    __shared__ __align__(16) __bf16 P[96 * 136];
    __shared__ float srS[96];
    int t = threadIdx.x;
    int lane = t & 63, w = t >> 6, l15 = lane & 15, quad = lane >> 4;
    int bid = blockIdx.x;
    int n0, n1;
    {
        if (bid == 0) n0 = 0;
        else {
            int tgt = bid * EB, lo = 0, hi = N_NODES;
            while (lo < hi) { int m = (lo + hi) >> 1; if (rowptr[m] < tgt) lo = m + 1; else hi = m; }
            n0 = lo;
        }
        if (bid == NBLK - 1) n1 = N_NODES;
        else {
            int tgt = (bid + 1) * EB, lo = 0, hi = N_NODES;
            while (lo < hi) { int m = (lo + hi) >> 1; if (rowptr[m] < tgt) lo = m + 1; else hi = m; }
            n1 = lo;
        }
    }
    if (n0 >= n1) return;                    // uniform: no barriers crossed
    int e0 = rowptr[n0], e1 = rowptr[n1];
    long long Bf[2][4];
    #pragma unroll
    for (int j = 0; j < 2; ++j)
        #pragma unroll
        for (int ks = 0; ks < 4; ++ks)
            Bf[j][ks] = *(const long long*)(Wk8 + (size_t)(w * 32 + j * 16 + l15) * 128 + ks * 32 + quad * 8);
    float sc0 = s_cL[w * 32 + l15], sc1 = s_cL[w * 32 + 16 + l15];
    int c = t & 127, half = t >> 7;
    float acc[6] = {0.f, 0.f, 0.f, 0.f, 0.f, 0.f};
    int cur = (e0 < e1) ? recv_s[e0] : -1;
    for (int et0 = e0; et0 < e1; et0 += SE) {
        int cnt = e1 - et0; if (cnt > SE) cnt = SE;
        int nrows = cnt * 12;
        __syncthreads();                     // previous scatter done reading P
        #pragma unroll
        for (int it = 0; it < 3; ++it) {
            int idx = it * 256 + t;
            if (idx < nrows * 8) {
                int row = idx >> 3, cv = idx & 7;
                *(uint4*)(T8 + row * 144 + cv * 16) =
                    *(const uint4*)(kb8 + ((size_t)et0 * 12 + row) * 128 + cv * 16);
            }
        }
        if (t < nrows) srS[t] = s_r[(size_t)et0 * 12 + t];
        __syncthreads();
        int nrt = (nrows + 15) >> 4;
        for (int rt = 0; rt < nrt; ++rt) {
            i32x4 a0 = (i32x4){0, 0, 0, 0};
            i32x4 a1 = (i32x4){0, 0, 0, 0};
            #pragma unroll
            for (int ks = 0; ks < 4; ++ks) {
                long long a = *(const long long*)(T8 + (rt * 16 + l15) * 144 + ks * 32 + quad * 8);
                a0 = __builtin_amdgcn_mfma_i32_16x16x32_i8(a, Bf[0][ks], a0, 0, 0, 0);
                a1 = __builtin_amdgcn_mfma_i32_16x16x32_i8(a, Bf[1][ks], a1, 0, 0, 0);
            }
            #pragma unroll
            for (int rg = 0; rg < 4; ++rg) {
                int row = rt * 16 + quad * 4 + rg;
                float sr = srS[row];
                P[row * 136 + w * 32 + l15]      = (__bf16)((float)a0[rg] * sr * sc0);
                P[row * 136 + w * 32 + 16 + l15] = (__bf16)((float)a1[rg] * sr * sc1);
            }
        }
        __syncthreads();
        for (int el = 0; el < cnt; ++el) {
            int e = et0 + el;
            int r = recv_s[e];
            if (r != cur) {
                __bf16* op = aggb + ((size_t)cur * 128 + c) * 12 + half * 6;
                #pragma unroll
                for (int j = 0; j < 6; ++j) { op[j] = (__bf16)acc[j]; acc[j] = 0.f; }
                cur = r;
            }
            int s = send_s[e];
            const __bf16* hp = h_bf + (size_t)s * 1536 + half * 6 * 128 + c;
            const __bf16* pp = P + (el * 12 + half * 6) * 136 + c;
            #pragma unroll
            for (int j = 0; j < 6; ++j)
                acc[j] += (float)hp[j * 128] * (float)pp[j * 136];
        }
    }
    if (e0 < e1) {
        __bf16* op = aggb + ((size_t)cur * 128 + c) * 12 + half * 6;
        #pragma unroll
        for (int j = 0; j < 6; ++j) op[j] = (__bf16)acc[j];
    }
    for (int n = n0; n < n1; ++n) {
        if (rowptr[n] == rowptr[n + 1]) {
            __bf16* op = aggb + ((size_t)n * 128 + c) * 12 + half * 6;
            #pragma unroll
            for (int j = 0; j < 6; ++j) op[j] = (__bf16)0.f;
        }
    }
}

// ---------------- node kernel: conv + LN + MFMA MLP + MFMA readout ----------------
// Round-23: MNPB 4 -> 8 (1000 blocks). Theory: k_mlp's 158 µs was invariant
// to occupancy/phase structure but each block streams 262 KB of W1T/W2T
// through L1 with zero reuse (2000 blocks = 524 MB of L2-latency loads behind
// 13 barriers). Doubling per-block work halves that stream and amortizes
// barriers. LDS: X+H4 at 96x136 + redS = 52.9 KB -> 3 blocks/CU (WroT LDS
// staging replaced by WroF register fragments, verified rounds 6/8).
__global__ __launch_bounds__(256, 3) void k_mlp(
    const __bf16* __restrict__ aggb, const float* __restrict__ fkl,
    const float* __restrict__ bconv, const float* __restrict__ ln_g,
    const float* __restrict__ ln_b,
    const __bf16* __restrict__ W1T, const float* __restrict__ b1,
    const __bf16* __restrict__ W2T2, const float* __restrict__ b2,
    const __bf16* __restrict__ WroFl, const float* __restrict__ bro,
    __bf16* __restrict__ h_bf, float* __restrict__ readout) {
    __shared__ __align__(16) __bf16 X[96 * 136];
    __shared__ __align__(16) __bf16 H4[96 * 136];
    __shared__ float redS[96][2];
    int t = threadIdx.x;
    int lane = t & 63, w = t >> 6, l15 = lane & 15, quad = lane >> 4;
    int c = t & 127, nh = t >> 7;
    int n0 = blockIdx.x * MNPB;
    float bcv = bconv[c];
    // ---- conv: thread owns channel c, nodes {nh, nh+2, nh+4, nh+6} ----
    {
        float a2[4][12];
        #pragma unroll
        for (int u = 0; u < 4; ++u) {
            const __bf16* ap = aggb + ((size_t)(n0 + nh + u * 2) * 128 + c) * 12;
            #pragma unroll
            for (int v = 0; v < 3; ++v) {
                bf16x4 pk = *(const bf16x4*)(ap + v * 4);
                #pragma unroll
                for (int j = 0; j < 4; ++j) a2[u][v * 4 + j] = (float)pk[j];
            }
        }
        #pragma unroll 4
        for (int p = 0; p < 12; ++p) {
            const float* fp = fkl + ((size_t)p * 128 + c) * 12;
            float fr[12];
            #pragma unroll
            for (int v = 0; v < 3; ++v) {
                float4 fv = *(const float4*)(fp + v * 4);
                fr[v*4+0] = fv.x; fr[v*4+1] = fv.y; fr[v*4+2] = fv.z; fr[v*4+3] = fv.w;
            }
            #pragma unroll
            for (int u = 0; u < 4; ++u) {
                float s = 0.f;
                #pragma unroll
                for (int o = 0; o < 12; ++o) s += a2[u][o] * fr[o];
                X[((nh + u * 2) * 12 + p) * 136 + c] = (__bf16)(s * (1.0f / 12.0f) + bcv);
            }
        }
    }
    __syncthreads();
    // ---- LN stats: wave w owns rows w*24 .. w*24+24 ----
    for (int r = w * 24; r < w * 24 + 24; ++r) {
        float v0 = (float)X[r * 136 + lane];
        float v1 = (float)X[r * 136 + 64 + lane];
        float s = v0 + v1, s2 = v0 * v0 + v1 * v1;
        for (int off = 32; off > 0; off >>= 1) {
            s += __shfl_down(s, off);
            s2 += __shfl_down(s2, off);
        }
        if (lane == 0) {
            float mu = s * (1.0f / 128.0f);
            float var = s2 * (1.0f / 128.0f) - mu * mu;
            redS[r][0] = mu;
            redS[r][1] = rsqrtf(var + 1e-5f);
        }
    }
    __syncthreads();
    float gv = ln_g[c], bv = ln_b[c];
    #pragma unroll
    for (int nn = nh; nn < 8; nn += 2)
        #pragma unroll
        for (int p = 0; p < 12; ++p) {
            int r = nn * 12 + p;
            float v = (float)X[r * 136 + c];
            X[r * 136 + c] = (__bf16)((v - redS[r][0]) * redS[r][1] * gv + bv);
        }
    __syncthreads();
    // ---- MLP: 4 phases of 128 hidden cols, 6 row-tiles ----
    f32x4 acc2[6][2];
    #pragma unroll
    for (int mt = 0; mt < 6; ++mt)
        #pragma unroll
        for (int j = 0; j < 2; ++j) acc2[mt][j] = (f32x4){0.f, 0.f, 0.f, 0.f};
    for (int ph = 0; ph < 4; ++ph) {
        if (ph) __syncthreads();
        #pragma unroll
        for (int mt = 0; mt < 6; ++mt) {
            bf16x8 af[4];
            #pragma unroll
            for (int ks = 0; ks < 4; ++ks)
                af[ks] = *(const bf16x8*)(X + (mt * 16 + l15) * 136 + ks * 32 + quad * 8);
            #pragma unroll
            for (int nt = 0; nt < 2; ++nt) {
                int colf = ph * 128 + w * 32 + nt * 16 + l15;
                f32x4 a = {0.f, 0.f, 0.f, 0.f};
                #pragma unroll
                for (int ks = 0; ks < 4; ++ks) {
                    bf16x8 bf = *(const bf16x8*)(W1T + (size_t)colf * 128 + ks * 32 + quad * 8);
                    a = __builtin_amdgcn_mfma_f32_16x16x32_bf16(af[ks], bf, a, 0, 0, 0);
                }
                float bj = b1[colf];
                #pragma unroll
                for (int rg = 0; rg < 4; ++rg) {
                    int row = mt * 16 + quad * 4 + rg;
                    H4[row * 136 + w * 32 + nt * 16 + l15] = (__bf16)gelu_f(a[rg] + bj);
                }
            }
        }
        __syncthreads();
        #pragma unroll
        for (int mt = 0; mt < 6; ++mt)
            #pragma unroll
            for (int ks = 0; ks < 4; ++ks) {
                bf16x8 af = *(const bf16x8*)(H4 + (mt * 16 + l15) * 136 + ks * 32 + quad * 8);
                #pragma unroll
                for (int j = 0; j < 2; ++j) {
                    int col = w * 32 + j * 16 + l15;
                    bf16x8 bf = *(const bf16x8*)(W2T2 + (size_t)col * 512 + ph * 128 + ks * 32 + quad * 8);
                    acc2[mt][j] = __builtin_amdgcn_mfma_f32_16x16x32_bf16(af, bf, acc2[mt][j], 0, 0, 0);
                }
            }
    }
    // ---- residual h update (writes h_bf + X) ----
    #pragma unroll
    for (int mt = 0; mt < 6; ++mt) {
        float bj0 = b2[w * 32 + l15], bj1 = b2[w * 32 + 16 + l15];
        #pragma unroll
        for (int rg = 0; rg < 4; ++rg) {
            int row = mt * 16 + quad * 4 + rg;
            int node = n0 + row / 12, pp = row % 12;
            size_t hi = ((size_t)node * 12 + pp) * 128;
            {
                int col = w * 32 + l15;
                float hv = (float)h_bf[hi + col] + acc2[mt][0][rg] + bj0;
                h_bf[hi + col] = (__bf16)hv;
                X[row * 136 + col] = (__bf16)hv;
            }
            {
                int col = w * 32 + 16 + l15;
                float hv = (float)h_bf[hi + col] + acc2[mt][1][rg] + bj1;
                h_bf[hi + col] = (__bf16)hv;
                X[row * 136 + col] = (__bf16)hv;
            }
        }
    }
    __syncthreads();
    // ---- readout via MFMA: 6 row-tiles over 4 waves, B-frag from WroF ----
    for (int mt2 = w; mt2 < 6; mt2 += 4) {
        const __bf16* wp = WroFl + (size_t)lane * 32;
        f32x4 a = {0.f, 0.f, 0.f, 0.f};
        #pragma unroll
        for (int ks = 0; ks < 4; ++ks) {
            bf16x8 af = *(const bf16x8*)(X + (mt2 * 16 + l15) * 136 + ks * 32 + quad * 8);
            bf16x8 bf = *(const bf16x8*)(wp + ks * 8);
            a = __builtin_amdgcn_mfma_f32_16x16x32_bf16(af, bf, a, 0, 0, 0);
        }
        if (l15 < 9) {
            float bj = bro[l15];
            #pragma unroll
            for (int rg = 0; rg < 4; ++rg) {
                int row = mt2 * 16 + quad * 4 + rg;
                int node = n0 + row / 12, pp = row % 12;
                size_t ri = ((size_t)node * 12 + pp) * 9 + l15;
                readout[ri] += (a[rg] + bj) * (1.0f / 3.0f);
            }
        }
    }
}

// ---------------- final pooling ----------------
__global__ __launch_bounds__(128) void k_out(
    const float* __restrict__ readout, const float* __restrict__ node_grid,
    const int* __restrict__ batch, float* __restrict__ out) {
    int n = blockIdx.x * 128 + threadIdx.x;
    if (n >= N_NODES) return;
    int b = batch[n];
    const float* ro = readout + (size_t)n * 108;
    float ss[8] = {0, 0, 0, 0, 0, 0, 0, 0};
    float v0 = 0.f, v1 = 0.f, v2 = 0.f;
    for (int p = 0; p < 12; ++p) {
        #pragma unroll
        for (int j = 0; j < 8; ++j) ss[j] += ro[p * 9 + j];
        float rv = ro[p * 9 + 8];
        v0 += rv * node_grid[n * 36 + p * 3 + 0];
        v1 += rv * node_grid[n * 36 + p * 3 + 1];
        v2 += rv * node_grid[n * 36 + p * 3 + 2];
    }
    #pragma unroll
    for (int j = 0; j < 8; ++j) atomicAdd(&out[b * 8 + j], ss[j] * (1.0f / 12.0f));
    atomicAdd(&out[512 + b * 3 + 0], v0 * (1.0f / 12.0f));
    atomicAdd(&out[512 + b * 3 + 1], v1 * (1.0f / 12.0f));
    atomicAdd(&out[512 + b * 3 + 2], v2 * (1.0f / 12.0f));
}

extern "C" void kernel_launch(void* const* d_in, const int* in_sizes, int n_in,
                              void* d_out, int out_size, void* d_ws, size_t ws_size,
                              hipStream_t stream) {
    const float* x    = (const float*)d_in[0];
    const float* vec  = (const float*)d_in[1];
    const float* pos  = (const float*)d_in[2];
    const float* Q    = (const float*)d_in[3];
    const float* Wsp1 = (const float*)d_in[4];
    const float* bsp1 = (const float*)d_in[5];
    const float* Wsp2 = (const float*)d_in[6];
    const float* bsp2 = (const float*)d_in[7];
    const float* Wsh1 = (const float*)d_in[8];
    const float* bsh1 = (const float*)d_in[9];
    const float* Wsh2 = (const float*)d_in[10];
    const float* bsh2 = (const float*)d_in[11];
    const float* Wemb = (const float*)d_in[12];
    const float* Wk   = (const float*)d_in[13];
    const float* Wfk  = (const float*)d_in[14];
    const float* bconv= (const float*)d_in[15];
    const float* ln_g = (const float*)d_in[16];
    const float* ln_b = (const float*)d_in[17];
    const float* W1   = (const float*)d_in[18];
    const float* b1   = (const float*)d_in[19];
    const float* W2   = (const float*)d_in[20];
    const float* b2   = (const float*)d_in[21];
    const float* Wro  = (const float*)d_in[22];
    const float* bro  = (const float*)d_in[23];
    const int* ei     = (const int*)d_in[24];
    const int* batch  = (const int*)d_in[25];
    const int* send = ei;
    const int* recv = ei + N_EDGES;

    float* ws = (float*)d_ws;
    float* grid0  = ws;
    float* grid   = ws + 64;
    float* fk     = ws + 2368;
    float* ng     = ws + 57664;
    float* ro     = ws + 345664;
    float* attr_s = ws + 1209664;
    const size_t P_WT  = 2746048;            // bf16 WT: 458752 bf16
    const size_t P_WK8 = P_WT + 229376;      // int8 Wk: 49152 B
    const size_t P_SC  = P_WK8 + 12288;      // col scales
    const size_t P_WP  = P_SC + 384;         // WP1T: 4096 bf16
    const size_t P_WROF= P_WP + 2048;        // WroF: 6144 bf16 = 3072 f
    const size_t P_H   = P_WROF + 3072;      // h bf16
    const size_t P_AGG = P_H + 6144000;      // aggb
    const size_t P_KB8 = P_AGG + 6144000;    // kb int8 (98.3 MB)
    const size_t P_SR  = P_KB8 + 24576000;   // row scales
    const size_t T_INT = P_SR + 768000;
    const size_t NEED  = (T_INT + 216096) * 4ull;   // ~163 MB

    if (ws_size < NEED) return;

    __bf16* WT   = (__bf16*)(ws + P_WT);
    signed char* Wk8 = (signed char*)(ws + P_WK8);
    float* s_c   = ws + P_SC;
    __bf16* WP1T = (__bf16*)(ws + P_WP);
    __bf16* WroF = (__bf16*)(ws + P_WROF);
    __bf16* hA   = (__bf16*)(ws + P_H);
    __bf16* aggb = (__bf16*)(ws + P_AGG);
    signed char* kb8 = (signed char*)(ws + P_KB8);
    float* s_r   = ws + P_SR;
    int*   ibase = (int*)(ws + T_INT);
    int* deg    = ibase;
    int* cursor = ibase + 8000;
    int* rowptr = ibase + 16000;
    int* perm   = ibase + 24064;
    int* send_s = ibase + 88064;
    int* recv_s = ibase + 152080;

    const __bf16* Wsp2T = WT;
    const __bf16* W1T   = WT + 65536;
    const __bf16* W2T   = WT + 65536 + 3 * 65536;

    hipMemsetAsync(d_out, 0, sizeof(float) * (size_t)out_size, stream);
    hipMemsetAsync(ro, 0, sizeof(float) * 864000, stream);
    hipMemsetAsync(deg, 0, sizeof(int) * 8000, stream);

    k_grid<<<1, 256, 0, stream>>>(Q, grid0, grid);
    k_kbsh<<<144, 128, 0, stream>>>(grid0, Wsh1, bsh1, Wsh2, bsh2, Wfk, fk);
    k_embed<<<N_NODES, 128, 0, stream>>>(x, vec, batch, grid, Wemb, ng, hA);
    k_deg<<<250, 256, 0, stream>>>(recv, deg);
    k_scan<<<1, 1024, 0, stream>>>(deg, rowptr, cursor);
    k_fill<<<250, 256, 0, stream>>>(recv, cursor, perm);
    k_attr_sorted<<<((N_EDGES + 16) * 12 + 255) / 256, 256, 0, stream>>>(
        pos, ng, send, recv, perm, attr_s, send_s, recv_s);
    k_prepw2<<<(7 * 65536 + 255) / 256, 256, 0, stream>>>(Wsp2, Wk, W1, W2, WT);
    k_prepw_i8<<<3, 128, 0, stream>>>(Wk, Wk8, s_c);
    k_prepw_p<<<1, 128, 0, stream>>>(Wsp1, bsp1, WP1T);
    k_prepw_ro<<<1, 192, 0, stream>>>(Wro, WroF);

    k_kb_i8<<<N_EDGES * 12 / 64, 256, 0, stream>>>(attr_s, Wsp2T, WP1T, bsp2, kb8, s_r);

    for (int l = 0; l < 3; ++l) {
        k_gscat2<<<NBLK, 256, 0, stream>>>(kb8, s_r,
            Wk8 + (size_t)l * 16384, s_c + l * 128,
            send_s, recv_s, rowptr, hA, aggb);
        k_mlp<<<N_NODES / MNPB, 256, 0, stream>>>(aggb, fk + l * 18432,
            bconv + l * 128, ln_g + l * 128, ln_b + l * 128,
            W1T + l * 65536, b1 + l * 512, W2T + l * 65536, b2 + l * 128,
            WroF + l * 2048, bro + l * 9, hA, ro);
    }
    k_out<<<(N_NODES + 127) / 128, 128, 0, stream>>>(ro, ng, batch, (float*)d_out);
}

// Round 11
// 896.347 us; speedup vs baseline: 1.2796x; 1.1622x over previous
//
#include <hip/hip_runtime.h>
#include <hip/hip_bf16.h>

#define N_NODES 8000
#define N_EDGES 64000
#define NBATCH  64
#define NGRID   12
#define HIDC    128
#define MNPB    8
#define EB      64
#define SE      8
#define NBLK    (N_EDGES / EB)

typedef __bf16 bf16x8 __attribute__((ext_vector_type(8)));
typedef __bf16 bf16x4 __attribute__((ext_vector_type(4)));
typedef float  f32x4  __attribute__((ext_vector_type(4)));
typedef int    i32x4  __attribute__((ext_vector_type(4)));

// gelu = x * sigmoid(2u); fast v_rcp (err ~1e-6)
__device__ __forceinline__ float gelu_f(float x) {
    float u = 0.7978845608f * x * (1.0f + 0.044715f * x * x);
    float e = __expf(2.0f * u);
    float r = __builtin_amdgcn_rcpf(e + 1.0f);
    return x * (1.0f - r);
}

// ---------------- grid0 + per-batch rotated grids ----------------
__global__ void k_grid(const float* __restrict__ Q, float* __restrict__ grid0,
                       float* __restrict__ grid) {
    int t = threadIdx.x;
    __shared__ float g0[12][3];
    if (t < 12) {
        float fi = (float)t;
        float theta = 6.28318530717958647692f * fi / 1.61803398874989484820f;
        float z = 1.0f - (2.0f * fi + 1.0f) / 12.0f;
        float r = sqrtf(fmaxf(1.0f - z * z, 0.0f));
        g0[t][0] = r * cosf(theta);
        g0[t][1] = r * sinf(theta);
        g0[t][2] = z;
        grid0[t * 3 + 0] = g0[t][0];
        grid0[t * 3 + 1] = g0[t][1];
        grid0[t * 3 + 2] = g0[t][2];
    }
    __syncthreads();
    for (int idx = t; idx < NBATCH * 12 * 3; idx += blockDim.x) {
        int b = idx / 36, rmd = idx % 36, n = rmd / 3, i = rmd % 3;
        float acc = 0.f;
        #pragma unroll
        for (int j = 0; j < 3; ++j) acc += Q[b * 9 + i * 3 + j] * g0[n][j];
        grid[idx] = acc;
    }
}

// ---------------- kb_sh -> fk  (fk layout: [l][p][c][o]) ----------------
__global__ __launch_bounds__(128) void k_kbsh(
    const float* __restrict__ grid0,
    const float* __restrict__ Wsh1, const float* __restrict__ bsh1,
    const float* __restrict__ Wsh2, const float* __restrict__ bsh2,
    const float* __restrict__ Wfk, float* __restrict__ fk) {
    int row = blockIdx.x;
    int p = row / 12, o = row % 12, t = threadIdx.x;
    float tt = grid0[p*3]*grid0[o*3] + grid0[p*3+1]*grid0[o*3+1] + grid0[p*3+2]*grid0[o*3+2];
    float p1 = tt, p2 = tt * tt, p3 = p2 * tt;
    float h1 = gelu_f(p1 * Wsh1[t] + p2 * Wsh1[128 + t] + p3 * Wsh1[256 + t] + bsh1[t]);
    __shared__ float h1S[128];
    __shared__ float h2S[128];
    h1S[t] = h1;
    __syncthreads();
    float acc = bsh2[t];
    #pragma unroll 8
    for (int k = 0; k < 128; ++k) acc += h1S[k] * Wsh2[k * 128 + t];
    h2S[t] = gelu_f(acc);
    __syncthreads();
    for (int l = 0; l < 3; ++l) {
        float a = 0.f;
        #pragma unroll 8
        for (int k = 0; k < 128; ++k) a += h2S[k] * Wfk[l * 16384 + k * 128 + t];
        fk[l * 18432 + (p * 128 + t) * 12 + o] = a;
    }
}

// ---------------- embed (round-7 verified version) ----------------
__global__ __launch_bounds__(128) void k_embed(
    const float* __restrict__ x, const float* __restrict__ vec,
    const int* __restrict__ batch, const float* __restrict__ grid,
    const float* __restrict__ Wemb, float* __restrict__ node_grid,
    __bf16* __restrict__ h_bf) {
    __shared__ float WembS[18 * 128];
    __shared__ float ngS[36];
    __shared__ float xS[16];
    __shared__ float vS[6];
    int n = blockIdx.x, t = threadIdx.x;
    for (int i = t; i < 18 * 128; i += 128) WembS[i] = Wemb[i];
    int b = batch[n];
    if (t < 36) { float g = grid[b * 36 + t]; ngS[t] = g; node_grid[n * 36 + t] = g; }
    if (t < 16) xS[t] = x[n * 16 + t];
    if (t >= 16 && t < 22) vS[t - 16] = vec[n * 6 + (t - 16)];
    __syncthreads();
    for (int g = 0; g < NGRID; ++g) {
        float g0 = ngS[g*3], g1 = ngS[g*3+1], g2 = ngS[g*3+2];
        float xv0 = vS[0]*g0 + vS[1]*g1 + vS[2]*g2;
        float xv1 = vS[3]*g0 + vS[4]*g1 + vS[5]*g2;
        float acc = xv0 * WembS[16*128 + t] + xv1 * WembS[17*128 + t];
        #pragma unroll
        for (int j = 0; j < 16; ++j) acc += xS[j] * WembS[j*128 + t];
        h_bf[((size_t)n * NGRID + g) * HIDC + t] = (__bf16)acc;
    }
}

// ---------------- CSR build ----------------
__global__ __launch_bounds__(256) void k_deg(const int* __restrict__ recv,
                                             int* __restrict__ deg) {
    int e = blockIdx.x * 256 + threadIdx.x;
    if (e < N_EDGES) atomicAdd(&deg[recv[e]], 1);
}

__global__ __launch_bounds__(1024) void k_scan(const int* __restrict__ deg,
                                               int* __restrict__ rowptr,
                                               int* __restrict__ cursor) {
    __shared__ int part[1024];
    int t = threadIdx.x;
    int base = t * 8;
    int local[8];
    int s = 0;
    #pragma unroll
    for (int j = 0; j < 8; ++j) {
        int idx = base + j;
        int v = (idx < N_NODES) ? deg[idx] : 0;
        local[j] = s;
        s += v;
    }
    part[t] = s;
    __syncthreads();
    for (int off = 1; off < 1024; off <<= 1) {
        int v = (t >= off) ? part[t - off] : 0;
        __syncthreads();
        part[t] += v;
        __syncthreads();
    }
    int excl = (t == 0) ? 0 : part[t - 1];
    #pragma unroll
    for (int j = 0; j < 8; ++j) {
        int idx = base + j;
        if (idx < N_NODES) {
            int v = excl + local[j];
            rowptr[idx] = v;
            cursor[idx] = v;
        }
    }
    if (t == 1023) rowptr[N_NODES] = part[1023];
}

__global__ __launch_bounds__(256) void k_fill(const int* __restrict__ recv,
                                              int* __restrict__ cursor,
                                              int* __restrict__ perm) {
    int e = blockIdx.x * 256 + threadIdx.x;
    if (e < N_EDGES) {
        int r = recv[e];
        int p = atomicAdd(&cursor[r], 1);
        perm[p] = e;
    }
}

// ---------------- attrs (recv-sorted) ----------------
__global__ __launch_bounds__(256) void k_attr_sorted(
    const float* __restrict__ pos, const float* __restrict__ ng,
    const int* __restrict__ send, const int* __restrict__ recv,
    const int* __restrict__ perm,
    float* __restrict__ attr_s, int* __restrict__ send_s,
    int* __restrict__ recv_s) {
    int idx = blockIdx.x * 256 + threadIdx.x;
    if (idx >= (N_EDGES + 16) * 12) return;
    int i = idx / 12, g = idx % 12;
    if (i < N_EDGES) {
        int e = perm[i];
        int s = send[e], r = recv[e];
        float rx = pos[s*3+0] - pos[r*3+0];
        float ry = pos[s*3+1] - pos[r*3+1];
        float rz = pos[s*3+2] - pos[r*3+2];
        const float* gr = ng + ((size_t)r * 12 + g) * 3;
        float g0 = gr[0], g1 = gr[1], g2 = gr[2];
        float iv1 = rx*g0 + ry*g1 + rz*g2;
        float wx = rx - iv1*g0, wy = ry - iv1*g1, wz = rz - iv1*g2;
        attr_s[(size_t)idx * 2 + 0] = iv1;
        attr_s[(size_t)idx * 2 + 1] = sqrtf(wx*wx + wy*wy + wz*wz);
        if (g == 0) { send_s[i] = s; recv_s[i] = r; }
    } else {
        attr_s[(size_t)idx * 2 + 0] = 0.f;
        attr_s[(size_t)idx * 2 + 1] = 0.f;
        if (g == 0) { send_s[i] = 0; recv_s[i] = 0; }
    }
}

// ---- transposed bf16 weights [Wsp2T | WkT | W1T | W2T] ----
__global__ __launch_bounds__(256) void k_prepw2(
    const float* __restrict__ Wsp2, const float* __restrict__ Wk,
    const float* __restrict__ W1, const float* __restrict__ W2,
    __bf16* __restrict__ WT) {
    int i = blockIdx.x * 256 + threadIdx.x;
    if (i >= 7 * 65536) return;
    float v;
    if (i < 65536) {
        int buf = i >> 14, r = i & 16383;
        int n = r >> 7, k = r & 127;
        v = (buf == 0) ? Wsp2[k * 128 + n] : Wk[(buf - 1) * 16384 + k * 128 + n];
    } else {
        int i2 = i - 65536;
        int l = i2 >> 16, r = i2 & 65535;
        if (l < 3) {
            int n = r >> 7, k = r & 127;
            v = W1[l * 65536 + k * 512 + n];
        } else {
            int l2 = l - 3;
            int n = r >> 9, k = r & 511;
            v = W2[l2 * 65536 + k * 128 + n];
        }
    }
    WT[i] = (__bf16)v;
}

// ---- int8 Wk (transposed, per-column scales) ----
__global__ __launch_bounds__(128) void k_prepw_i8(
    const float* __restrict__ Wk, signed char* __restrict__ Wk8,
    float* __restrict__ s_c) {
    int i = blockIdx.x * 128 + threadIdx.x;
    if (i >= 384) return;
    int l = i / 128, col = i % 128;
    float mx = 0.f;
    for (int k = 0; k < 128; ++k)
        mx = fmaxf(mx, fabsf(Wk[l * 16384 + k * 128 + col]));
    float s = fmaxf(mx * (1.0f / 127.0f), 1e-20f);
    s_c[i] = s;
    float inv = 127.0f / fmaxf(mx, 1e-20f);
    for (int k = 0; k < 128; ++k) {
        int q = __float2int_rn(Wk[l * 16384 + k * 128 + col] * inv);
        q = q > 127 ? 127 : (q < -127 ? -127 : q);
        Wk8[(size_t)l * 16384 + col * 128 + k] = (signed char)q;
    }
}

// ---- combined poly weights WP1T [128 cols x 32 k] bf16 (bias at k=9) ----
__global__ __launch_bounds__(128) void k_prepw_p(
    const float* __restrict__ Wsp1, const float* __restrict__ bsp1,
    __bf16* __restrict__ WP1T) {
    int col = threadIdx.x;
    float w1[14];
    #pragma unroll
    for (int j = 0; j < 14; ++j) w1[j] = Wsp1[j * 128 + col];
    float vals[10];
    vals[0] = w1[0];                       // a
    vals[1] = w1[1];                       // b
    vals[2] = w1[2];                       // aa
    vals[3] = w1[3] + w1[4];               // ab
    vals[4] = w1[5];                       // bb
    vals[5] = w1[6];                       // aaa
    vals[6] = w1[7] + w1[8] + w1[10];      // aab
    vals[7] = w1[9] + w1[11] + w1[12];     // abb
    vals[8] = w1[13];                      // bbb
    vals[9] = bsp1[col];                   // bias (monomial 1)
    for (int k = 0; k < 32; ++k)
        WP1T[col * 32 + k] = (k < 10) ? (__bf16)vals[k] : (__bf16)0.f;
}

// ---- Wro packed per-layer into MFMA B-fragment per-lane layout ----
// WroF[l][lane][ks*8+j] = bf16( col<9 ? Wro[l][k*9+col] : 0 ),
//   col = lane&15, k = ks*32 + (lane>>4)*8 + j.  (verified rounds 6+8)
__global__ __launch_bounds__(192) void k_prepw_ro(
    const float* __restrict__ Wro, __bf16* __restrict__ WroF) {
    int t = threadIdx.x;
    int l = t / 64, lane = t % 64;
    int l15 = lane & 15, quad = lane >> 4;
    #pragma unroll
    for (int ks = 0; ks < 4; ++ks)
        #pragma unroll
        for (int j = 0; j < 8; ++j) {
            int k = ks * 32 + quad * 8 + j;
            float v = (l15 < 9) ? Wro[l * 1152 + k * 9 + l15] : 0.f;
            WroF[(size_t)(l * 64 + lane) * 32 + ks * 8 + j] = (__bf16)v;
        }
}

// ---------------- kb precompute (once): MFMA poly -> GEMM1 -> gelu -> kb int8 ----------------
__global__ __launch_bounds__(256, 4) void k_kb_i8(
    const float* __restrict__ attr_s,
    const __bf16* __restrict__ W2T, const __bf16* __restrict__ WP1T,
    const float* __restrict__ bsp2,
    signed char* __restrict__ kb8, float* __restrict__ s_r) {
    __shared__ __align__(16) __bf16 H1[64 * 136];
    __shared__ __align__(16) signed char K8[64 * 144];
    __shared__ float rowmaxS[64];
    int t = threadIdx.x;
    int lane = t & 63, w = t >> 6, l15 = lane & 15, quad = lane >> 4;
    size_t grow0 = (size_t)blockIdx.x * 64;
    // ---- poly via MFMA: wave w owns rows w*16 + l15 ----
    {
        float2 ab = ((const float2*)attr_s)[grow0 + w * 16 + l15];
        float a = ab.x, b = ab.y;
        float aa = a * a, abm = a * b, bb = b * b;
        float m0 = quad == 0 ? a        : (quad == 1 ? bb * b : 0.f);
        float m1 = quad == 0 ? b        : (quad == 1 ? 1.f    : 0.f);
        float m2 = quad == 0 ? aa       : 0.f;
        float m3 = quad == 0 ? abm      : 0.f;
        float m4 = quad == 0 ? bb       : 0.f;
        float m5 = quad == 0 ? aa * a   : 0.f;
        float m6 = quad == 0 ? aa * b   : 0.f;
        float m7 = quad == 0 ? abm * b  : 0.f;
        bf16x8 afrag = { (__bf16)m0, (__bf16)m1, (__bf16)m2, (__bf16)m3,
                         (__bf16)m4, (__bf16)m5, (__bf16)m6, (__bf16)m7 };
        #pragma unroll
        for (int n = 0; n < 8; ++n) {
            bf16x8 bp = *(const bf16x8*)(WP1T + (n * 16 + l15) * 32 + quad * 8);
            f32x4 cacc = {0.f, 0.f, 0.f, 0.f};
            cacc = __builtin_amdgcn_mfma_f32_16x16x32_bf16(afrag, bp, cacc, 0, 0, 0);
            #pragma unroll
            for (int rg = 0; rg < 4; ++rg) {
                int row = w * 16 + quad * 4 + rg;
                H1[row * 136 + n * 16 + l15] = (__bf16)gelu_f(cacc[rg]);
            }
        }
    }
    __syncthreads();
    bf16x8 Bf[2][4];
    #pragma unroll
    for (int j = 0; j < 2; ++j)
        #pragma unroll
        for (int ks = 0; ks < 4; ++ks)
            Bf[j][ks] = *(const bf16x8*)(W2T + (size_t)(w * 32 + j * 16 + l15) * 128 + ks * 32 + quad * 8);
    float b2v[2] = { bsp2[w * 32 + l15], bsp2[w * 32 + 16 + l15] };
    f32x4 acc[4][2];
    #pragma unroll
    for (int mt = 0; mt < 4; ++mt) {
        acc[mt][0] = (f32x4){0.f,0.f,0.f,0.f};
        acc[mt][1] = (f32x4){0.f,0.f,0.f,0.f};
        #pragma unroll
        for (int ks = 0; ks < 4; ++ks) {
            bf16x8 af = *(const bf16x8*)(H1 + (mt * 16 + l15) * 136 + ks * 32 + quad * 8);
            acc[mt][0] = __builtin_amdgcn_mfma_f32_16x16x32_bf16(af, Bf[0][ks], acc[mt][0], 0, 0, 0);
            acc[mt][1] = __builtin_amdgcn_mfma_f32_16x16x32_bf16(af, Bf[1][ks], acc[mt][1], 0, 0, 0);
        }
    }
    float g[4][2][4];
    #pragma unroll
    for (int mt = 0; mt < 4; ++mt)
        #pragma unroll
        for (int j = 0; j < 2; ++j)
            #pragma unroll
            for (int rg = 0; rg < 4; ++rg)
                g[mt][j][rg] = gelu_f(acc[mt][j][rg] + b2v[j]);
    __syncthreads();
    #pragma unroll
    for (int mt = 0; mt < 4; ++mt)
        #pragma unroll
        for (int j = 0; j < 2; ++j)
            #pragma unroll
            for (int rg = 0; rg < 4; ++rg) {
                int row = mt * 16 + quad * 4 + rg;
                H1[row * 136 + w * 32 + j * 16 + l15] = (__bf16)g[mt][j][rg];
            }
    __syncthreads();
    if (t < 64) {
        float mx = 0.f;
        #pragma unroll
        for (int ks = 0; ks < 16; ++ks) {
            bf16x8 xv = *(const bf16x8*)(H1 + t * 136 + ks * 8);
            #pragma unroll
            for (int m = 0; m < 8; ++m) mx = fmaxf(mx, fabsf((float)xv[m]));
        }
        float s = fmaxf(mx * (1.0f / 127.0f), 1e-20f);
        rowmaxS[t] = s;
        s_r[grow0 + t] = s;
    }
    __syncthreads();
    #pragma unroll
    for (int mt = 0; mt < 4; ++mt)
        #pragma unroll
        for (int j = 0; j < 2; ++j)
            #pragma unroll
            for (int rg = 0; rg < 4; ++rg) {
                int row = mt * 16 + quad * 4 + rg;
                float inv = __builtin_amdgcn_rcpf(rowmaxS[row]);
                int q = __float2int_rn(g[mt][j][rg] * inv);
                q = q > 127 ? 127 : (q < -127 ? -127 : q);
                K8[row * 144 + w * 32 + j * 16 + l15] = (signed char)q;
            }
    __syncthreads();
    #pragma unroll
    for (int it = 0; it < 2; ++it) {
        int idx = it * 256 + t;
        int row = idx >> 3, cv = idx & 7;
        *(uint4*)(kb8 + (grow0 + row) * 128 + cv * 16) =
            *(const uint4*)(K8 + row * 144 + cv * 16);
    }
}

// -------- fused per-layer GEMM2 + scatter (node-aligned, NO atomics) --------
// EB=64 (round-7 verified optimum).
__global__ __launch_bounds__(256, 4) void k_gscat2(
    const signed char* __restrict__ kb8, const float* __restrict__ s_r,
    const signed char* __restrict__ Wk8, const float* __restrict__ s_cL,
    const int* __restrict__ send_s, const int* __restrict__ recv_s,
    const int* __restrict__ rowptr, const __bf16* __restrict__ h_bf,
    __bf16* __restrict__ aggb) {
    __shared__ __align__(16) signed char T8[96 * 144];
    __shared__ __align__(16) __bf16 P[96 * 136];
    __shared__ float srS[96];
    int t = threadIdx.x;
    int lane = t & 63, w = t >> 6, l15 = lane & 15, quad = lane >> 4;
    int bid = blockIdx.x;
    int n0, n1;
    {
        if (bid == 0) n0 = 0;
        else {
            int tgt = bid * EB, lo = 0, hi = N_NODES;
            while (lo < hi) { int m = (lo + hi) >> 1; if (rowptr[m] < tgt) lo = m + 1; else hi = m; }
            n0 = lo;
        }
        if (bid == NBLK - 1) n1 = N_NODES;
        else {
            int tgt = (bid + 1) * EB, lo = 0, hi = N_NODES;
            while (lo < hi) { int m = (lo + hi) >> 1; if (rowptr[m] < tgt) lo = m + 1; else hi = m; }
            n1 = lo;
        }
    }
    if (n0 >= n1) return;                    // uniform: no barriers crossed
    int e0 = rowptr[n0], e1 = rowptr[n1];
    long long Bf[2][4];
    #pragma unroll
    for (int j = 0; j < 2; ++j)
        #pragma unroll
        for (int ks = 0; ks < 4; ++ks)
            Bf[j][ks] = *(const long long*)(Wk8 + (size_t)(w * 32 + j * 16 + l15) * 128 + ks * 32 + quad * 8);
    float sc0 = s_cL[w * 32 + l15], sc1 = s_cL[w * 32 + 16 + l15];
    int c = t & 127, half = t >> 7;
    float acc[6] = {0.f, 0.f, 0.f, 0.f, 0.f, 0.f};
    int cur = (e0 < e1) ? recv_s[e0] : -1;
    for (int et0 = e0; et0 < e1; et0 += SE) {
        int cnt = e1 - et0; if (cnt > SE) cnt = SE;
        int nrows = cnt * 12;
        __syncthreads();                     // previous scatter done reading P
        #pragma unroll
        for (int it = 0; it < 3; ++it) {
            int idx = it * 256 + t;
            if (idx < nrows * 8) {
                int row = idx >> 3, cv = idx & 7;
                *(uint4*)(T8 + row * 144 + cv * 16) =
                    *(const uint4*)(kb8 + ((size_t)et0 * 12 + row) * 128 + cv * 16);
            }
        }
        if (t < nrows) srS[t] = s_r[(size_t)et0 * 12 + t];
        __syncthreads();
        int nrt = (nrows + 15) >> 4;
        for (int rt = 0; rt < nrt; ++rt) {
            i32x4 a0 = (i32x4){0, 0, 0, 0};
            i32x4 a1 = (i32x4){0, 0, 0, 0};
            #pragma unroll
            for (int ks = 0; ks < 4; ++ks) {
                long long a = *(const long long*)(T8 + (rt * 16 + l15) * 144 + ks * 32 + quad * 8);
                a0 = __builtin_amdgcn_mfma_i32_16x16x32_i8(a, Bf[0][ks], a0, 0, 0, 0);
                a1 = __builtin_amdgcn_mfma_i32_16x16x32_i8(a, Bf[1][ks], a1, 0, 0, 0);
            }
            #pragma unroll
            for (int rg = 0; rg < 4; ++rg) {
                int row = rt * 16 + quad * 4 + rg;
                float sr = srS[row];
                P[row * 136 + w * 32 + l15]      = (__bf16)((float)a0[rg] * sr * sc0);
                P[row * 136 + w * 32 + 16 + l15] = (__bf16)((float)a1[rg] * sr * sc1);
            }
        }
        __syncthreads();
        for (int el = 0; el < cnt; ++el) {
            int e = et0 + el;
            int r = recv_s[e];
            if (r != cur) {
                __bf16* op = aggb + ((size_t)cur * 128 + c) * 12 + half * 6;
                #pragma unroll
                for (int j = 0; j < 6; ++j) { op[j] = (__bf16)acc[j]; acc[j] = 0.f; }
                cur = r;
            }
            int s = send_s[e];
            const __bf16* hp = h_bf + (size_t)s * 1536 + half * 6 * 128 + c;
            const __bf16* pp = P + (el * 12 + half * 6) * 136 + c;
            #pragma unroll
            for (int j = 0; j < 6; ++j)
                acc[j] += (float)hp[j * 128] * (float)pp[j * 136];
        }
    }
    if (e0 < e1) {
        __bf16* op = aggb + ((size_t)cur * 128 + c) * 12 + half * 6;
        #pragma unroll
        for (int j = 0; j < 6; ++j) op[j] = (__bf16)acc[j];
    }
    for (int n = n0; n < n1; ++n) {
        if (rowptr[n] == rowptr[n + 1]) {
            __bf16* op = aggb + ((size_t)n * 128 + c) * 12 + half * 6;
            #pragma unroll
            for (int j = 0; j < 6; ++j) op[j] = (__bf16)0.f;
        }
    }
}

// ---------------- node kernel: conv + LN + MFMA MLP + MFMA readout ----------------
// Round-24: MNPB=8 (verified 153 µs) + software-pipelined weight loads.
// All W1T/W2T fragment loads previously sat AFTER a barrier with immediate
// use (compiler can't hoist loads across __syncthreads) -> each phase-half
// opened with an unhidden L2-latency stall. Now: W2f for phase ph issues
// before the W1-compute; W1f for ph+1 issues before the mid-phase barrier.
// Static indexing throughout (rule #20). VGPR ~84 -> ~148 (<=170 for 3/CU).
__global__ __launch_bounds__(256, 3) void k_mlp(
    const __bf16* __restrict__ aggb, const float* __restrict__ fkl,
    const float* __restrict__ bconv, const float* __restrict__ ln_g,
    const float* __restrict__ ln_b,
    const __bf16* __restrict__ W1T, const float* __restrict__ b1,
    const __bf16* __restrict__ W2T2, const float* __restrict__ b2,
    const __bf16* __restrict__ WroFl, const float* __restrict__ bro,
    __bf16* __restrict__ h_bf, float* __restrict__ readout) {
    __shared__ __align__(16) __bf16 X[96 * 136];
    __shared__ __align__(16) __bf16 H4[96 * 136];
    __shared__ float redS[96][2];
    int t = threadIdx.x;
    int lane = t & 63, w = t >> 6, l15 = lane & 15, quad = lane >> 4;
    int c = t & 127, nh = t >> 7;
    int n0 = blockIdx.x * MNPB;
    float bcv = bconv[c];
    // ---- conv: thread owns channel c, nodes {nh, nh+2, nh+4, nh+6} ----
    {
        float a2[4][12];
        #pragma unroll
        for (int u = 0; u < 4; ++u) {
            const __bf16* ap = aggb + ((size_t)(n0 + nh + u * 2) * 128 + c) * 12;
            #pragma unroll
            for (int v = 0; v < 3; ++v) {
                bf16x4 pk = *(const bf16x4*)(ap + v * 4);
                #pragma unroll
                for (int j = 0; j < 4; ++j) a2[u][v * 4 + j] = (float)pk[j];
            }
        }
        #pragma unroll 4
        for (int p = 0; p < 12; ++p) {
            const float* fp = fkl + ((size_t)p * 128 + c) * 12;
            float fr[12];
            #pragma unroll
            for (int v = 0; v < 3; ++v) {
                float4 fv = *(const float4*)(fp + v * 4);
                fr[v*4+0] = fv.x; fr[v*4+1] = fv.y; fr[v*4+2] = fv.z; fr[v*4+3] = fv.w;
            }
            #pragma unroll
            for (int u = 0; u < 4; ++u) {
                float s = 0.f;
                #pragma unroll
                for (int o = 0; o < 12; ++o) s += a2[u][o] * fr[o];
                X[((nh + u * 2) * 12 + p) * 136 + c] = (__bf16)(s * (1.0f / 12.0f) + bcv);
            }
        }
    }
    __syncthreads();
    // ---- LN stats: wave w owns rows w*24 .. w*24+24 ----
    for (int r = w * 24; r < w * 24 + 24; ++r) {
        float v0 = (float)X[r * 136 + lane];
        float v1 = (float)X[r * 136 + 64 + lane];
        float s = v0 + v1, s2 = v0 * v0 + v1 * v1;
        for (int off = 32; off > 0; off >>= 1) {
            s += __shfl_down(s, off);
            s2 += __shfl_down(s2, off);
        }
        if (lane == 0) {
            float mu = s * (1.0f / 128.0f);
            float var = s2 * (1.0f / 128.0f) - mu * mu;
            redS[r][0] = mu;
            redS[r][1] = rsqrtf(var + 1e-5f);
        }
    }
    __syncthreads();
    float gv = ln_g[c], bv = ln_b[c];
    #pragma unroll
    for (int nn = nh; nn < 8; nn += 2)
        #pragma unroll
        for (int p = 0; p < 12; ++p) {
            int r = nn * 12 + p;
            float v = (float)X[r * 136 + c];
            X[r * 136 + c] = (__bf16)((v - redS[r][0]) * redS[r][1] * gv + bv);
        }
    __syncthreads();
    // ---- MLP: 4 phases of 128 hidden cols, 6 row-tiles; pipelined weights ----
    f32x4 acc2[6][2];
    #pragma unroll
    for (int mt = 0; mt < 6; ++mt)
        #pragma unroll
        for (int j = 0; j < 2; ++j) acc2[mt][j] = (f32x4){0.f, 0.f, 0.f, 0.f};
    // preload W1 fragments for phase 0 (8 x bf16x8)
    bf16x8 W1f[2][4];
    #pragma unroll
    for (int nt = 0; nt < 2; ++nt)
        #pragma unroll
        for (int ks = 0; ks < 4; ++ks)
            W1f[nt][ks] = *(const bf16x8*)(W1T + (size_t)(w * 32 + nt * 16 + l15) * 128 + ks * 32 + quad * 8);
    for (int ph = 0; ph < 4; ++ph) {
        if (ph) __syncthreads();
        // issue W2 fragment loads for THIS phase early (used after mid barrier)
        bf16x8 W2f[2][4];
        #pragma unroll
        for (int j = 0; j < 2; ++j)
            #pragma unroll
            for (int ks = 0; ks < 4; ++ks)
                W2f[j][ks] = *(const bf16x8*)(W2T2 + (size_t)(w * 32 + j * 16 + l15) * 512 + ph * 128 + ks * 32 + quad * 8);
        float bj0 = b1[ph * 128 + w * 32 + l15];
        float bj1 = b1[ph * 128 + w * 32 + 16 + l15];
        #pragma unroll
        for (int mt = 0; mt < 6; ++mt) {
            bf16x8 af[4];
            #pragma unroll
            for (int ks = 0; ks < 4; ++ks)
                af[ks] = *(const bf16x8*)(X + (mt * 16 + l15) * 136 + ks * 32 + quad * 8);
            f32x4 a0 = {0.f, 0.f, 0.f, 0.f};
            f32x4 a1 = {0.f, 0.f, 0.f, 0.f};
            #pragma unroll
            for (int ks = 0; ks < 4; ++ks) {
                a0 = __builtin_amdgcn_mfma_f32_16x16x32_bf16(af[ks], W1f[0][ks], a0, 0, 0, 0);
                a1 = __builtin_amdgcn_mfma_f32_16x16x32_bf16(af[ks], W1f[1][ks], a1, 0, 0, 0);
            }
            #pragma unroll
            for (int rg = 0; rg < 4; ++rg) {
                int row = mt * 16 + quad * 4 + rg;
                H4[row * 136 + w * 32 + l15]      = (__bf16)gelu_f(a0[rg] + bj0);
                H4[row * 136 + w * 32 + 16 + l15] = (__bf16)gelu_f(a1[rg] + bj1);
            }
        }
        // prefetch W1 fragments for NEXT phase (hidden under W2 compute)
        if (ph < 3) {
            #pragma unroll
            for (int nt = 0; nt < 2; ++nt)
                #pragma unroll
                for (int ks = 0; ks < 4; ++ks)
                    W1f[nt][ks] = *(const bf16x8*)(W1T + (size_t)((ph + 1) * 128 + w * 32 + nt * 16 + l15) * 128 + ks * 32 + quad * 8);
        }
        __syncthreads();
        #pragma unroll
        for (int mt = 0; mt < 6; ++mt)
            #pragma unroll
            for (int ks = 0; ks < 4; ++ks) {
                bf16x8 af = *(const bf16x8*)(H4 + (mt * 16 + l15) * 136 + ks * 32 + quad * 8);
                acc2[mt][0] = __builtin_amdgcn_mfma_f32_16x16x32_bf16(af, W2f[0][ks], acc2[mt][0], 0, 0, 0);
                acc2[mt][1] = __builtin_amdgcn_mfma_f32_16x16x32_bf16(af, W2f[1][ks], acc2[mt][1], 0, 0, 0);
            }
    }
    // ---- residual h update (writes h_bf + X) ----
    #pragma unroll
    for (int mt = 0; mt < 6; ++mt) {
        float bj0 = b2[w * 32 + l15], bj1 = b2[w * 32 + 16 + l15];
        #pragma unroll
        for (int rg = 0; rg < 4; ++rg) {
            int row = mt * 16 + quad * 4 + rg;
            int node = n0 + row / 12, pp = row % 12;
            size_t hi = ((size_t)node * 12 + pp) * 128;
            {
                int col = w * 32 + l15;
                float hv = (float)h_bf[hi + col] + acc2[mt][0][rg] + bj0;
                h_bf[hi + col] = (__bf16)hv;
                X[row * 136 + col] = (__bf16)hv;
            }
            {
                int col = w * 32 + 16 + l15;
                float hv = (float)h_bf[hi + col] + acc2[mt][1][rg] + bj1;
                h_bf[hi + col] = (__bf16)hv;
                X[row * 136 + col] = (__bf16)hv;
            }
        }
    }
    __syncthreads();
    // ---- readout via MFMA: 6 row-tiles over 4 waves, B-frag from WroF ----
    for (int mt2 = w; mt2 < 6; mt2 += 4) {
        const __bf16* wp = WroFl + (size_t)lane * 32;
        f32x4 a = {0.f, 0.f, 0.f, 0.f};
        #pragma unroll
        for (int ks = 0; ks < 4; ++ks) {
            bf16x8 af = *(const bf16x8*)(X + (mt2 * 16 + l15) * 136 + ks * 32 + quad * 8);
            bf16x8 bf = *(const bf16x8*)(wp + ks * 8);
            a = __builtin_amdgcn_mfma_f32_16x16x32_bf16(af, bf, a, 0, 0, 0);
        }
        if (l15 < 9) {
            float bj = bro[l15];
            #pragma unroll
            for (int rg = 0; rg < 4; ++rg) {
                int row = mt2 * 16 + quad * 4 + rg;
                int node = n0 + row / 12, pp = row % 12;
                size_t ri = ((size_t)node * 12 + pp) * 9 + l15;
                readout[ri] += (a[rg] + bj) * (1.0f / 3.0f);
            }
        }
    }
}

// ---------------- final pooling ----------------
__global__ __launch_bounds__(128) void k_out(
    const float* __restrict__ readout, const float* __restrict__ node_grid,
    const int* __restrict__ batch, float* __restrict__ out) {
    int n = blockIdx.x * 128 + threadIdx.x;
    if (n >= N_NODES) return;
    int b = batch[n];
    const float* ro = readout + (size_t)n * 108;
    float ss[8] = {0, 0, 0, 0, 0, 0, 0, 0};
    float v0 = 0.f, v1 = 0.f, v2 = 0.f;
    for (int p = 0; p < 12; ++p) {
        #pragma unroll
        for (int j = 0; j < 8; ++j) ss[j] += ro[p * 9 + j];
        float rv = ro[p * 9 + 8];
        v0 += rv * node_grid[n * 36 + p * 3 + 0];
        v1 += rv * node_grid[n * 36 + p * 3 + 1];
        v2 += rv * node_grid[n * 36 + p * 3 + 2];
    }
    #pragma unroll
    for (int j = 0; j < 8; ++j) atomicAdd(&out[b * 8 + j], ss[j] * (1.0f / 12.0f));
    atomicAdd(&out[512 + b * 3 + 0], v0 * (1.0f / 12.0f));
    atomicAdd(&out[512 + b * 3 + 1], v1 * (1.0f / 12.0f));
    atomicAdd(&out[512 + b * 3 + 2], v2 * (1.0f / 12.0f));
}

extern "C" void kernel_launch(void* const* d_in, const int* in_sizes, int n_in,
                              void* d_out, int out_size, void* d_ws, size_t ws_size,
                              hipStream_t stream) {
    const float* x    = (const float*)d_in[0];
    const float* vec  = (const float*)d_in[1];
    const float* pos  = (const float*)d_in[2];
    const float* Q    = (const float*)d_in[3];
    const float* Wsp1 = (const float*)d_in[4];
    const float* bsp1 = (const float*)d_in[5];
    const float* Wsp2 = (const float*)d_in[6];
    const float* bsp2 = (const float*)d_in[7];
    const float* Wsh1 = (const float*)d_in[8];
    const float* bsh1 = (const float*)d_in[9];
    const float* Wsh2 = (const float*)d_in[10];
    const float* bsh2 = (const float*)d_in[11];
    const float* Wemb = (const float*)d_in[12];
    const float* Wk   = (const float*)d_in[13];
    const float* Wfk  = (const float*)d_in[14];
    const float* bconv= (const float*)d_in[15];
    const float* ln_g = (const float*)d_in[16];
    const float* ln_b = (const float*)d_in[17];
    const float* W1   = (const float*)d_in[18];
    const float* b1   = (const float*)d_in[19];
    const float* W2   = (const float*)d_in[20];
    const float* b2   = (const float*)d_in[21];
    const float* Wro  = (const float*)d_in[22];
    const float* bro  = (const float*)d_in[23];
    const int* ei     = (const int*)d_in[24];
    const int* batch  = (const int*)d_in[25];
    const int* send = ei;
    const int* recv = ei + N_EDGES;

    float* ws = (float*)d_ws;
    float* grid0  = ws;
    float* grid   = ws + 64;
    float* fk     = ws + 2368;
    float* ng     = ws + 57664;
    float* ro     = ws + 345664;
    float* attr_s = ws + 1209664;
    const size_t P_WT  = 2746048;            // bf16 WT: 458752 bf16
    const size_t P_WK8 = P_WT + 229376;      // int8 Wk: 49152 B
    const size_t P_SC  = P_WK8 + 12288;      // col scales
    const size_t P_WP  = P_SC + 384;         // WP1T: 4096 bf16
    const size_t P_WROF= P_WP + 2048;        // WroF: 6144 bf16 = 3072 f
    const size_t P_H   = P_WROF + 3072;      // h bf16
    const size_t P_AGG = P_H + 6144000;      // aggb
    const size_t P_KB8 = P_AGG + 6144000;    // kb int8 (98.3 MB)
    const size_t P_SR  = P_KB8 + 24576000;   // row scales
    const size_t T_INT = P_SR + 768000;
    const size_t NEED  = (T_INT + 216096) * 4ull;   // ~163 MB

    if (ws_size < NEED) return;

    __bf16* WT   = (__bf16*)(ws + P_WT);
    signed char* Wk8 = (signed char*)(ws + P_WK8);
    float* s_c   = ws + P_SC;
    __bf16* WP1T = (__bf16*)(ws + P_WP);
    __bf16* WroF = (__bf16*)(ws + P_WROF);
    __bf16* hA   = (__bf16*)(ws + P_H);
    __bf16* aggb = (__bf16*)(ws + P_AGG);
    signed char* kb8 = (signed char*)(ws + P_KB8);
    float* s_r   = ws + P_SR;
    int*   ibase = (int*)(ws + T_INT);
    int* deg    = ibase;
    int* cursor = ibase + 8000;
    int* rowptr = ibase + 16000;
    int* perm   = ibase + 24064;
    int* send_s = ibase + 88064;
    int* recv_s = ibase + 152080;

    const __bf16* Wsp2T = WT;
    const __bf16* W1T   = WT + 65536;
    const __bf16* W2T   = WT + 65536 + 3 * 65536;

    hipMemsetAsync(d_out, 0, sizeof(float) * (size_t)out_size, stream);
    hipMemsetAsync(ro, 0, sizeof(float) * 864000, stream);
    hipMemsetAsync(deg, 0, sizeof(int) * 8000, stream);

    k_grid<<<1, 256, 0, stream>>>(Q, grid0, grid);
    k_kbsh<<<144, 128, 0, stream>>>(grid0, Wsh1, bsh1, Wsh2, bsh2, Wfk, fk);
    k_embed<<<N_NODES, 128, 0, stream>>>(x, vec, batch, grid, Wemb, ng, hA);
    k_deg<<<250, 256, 0, stream>>>(recv, deg);
    k_scan<<<1, 1024, 0, stream>>>(deg, rowptr, cursor);
    k_fill<<<250, 256, 0, stream>>>(recv, cursor, perm);
    k_attr_sorted<<<((N_EDGES + 16) * 12 + 255) / 256, 256, 0, stream>>>(
        pos, ng, send, recv, perm, attr_s, send_s, recv_s);
    k_prepw2<<<(7 * 65536 + 255) / 256, 256, 0, stream>>>(Wsp2, Wk, W1, W2, WT);
    k_prepw_i8<<<3, 128, 0, stream>>>(Wk, Wk8, s_c);
    k_prepw_p<<<1, 128, 0, stream>>>(Wsp1, bsp1, WP1T);
    k_prepw_ro<<<1, 192, 0, stream>>>(Wro, WroF);

    k_kb_i8<<<N_EDGES * 12 / 64, 256, 0, stream>>>(attr_s, Wsp2T, WP1T, bsp2, kb8, s_r);

    for (int l = 0; l < 3; ++l) {
        k_gscat2<<<NBLK, 256, 0, stream>>>(kb8, s_r,
            Wk8 + (size_t)l * 16384, s_c + l * 128,
            send_s, recv_s, rowptr, hA, aggb);
        k_mlp<<<N_NODES / MNPB, 256, 0, stream>>>(aggb, fk + l * 18432,
            bconv + l * 128, ln_g + l * 128, ln_b + l * 128,
            W1T + l * 65536, b1 + l * 512, W2T + l * 65536, b2 + l * 128,
            WroF + l * 2048, bro + l * 9, hA, ro);
    }
    k_out<<<(N_NODES + 127) / 128, 128, 0, stream>>>(ro, ng, batch, (float*)d_out);
}

// Round 12
// 880.214 us; speedup vs baseline: 1.3031x; 1.0183x over previous
//
#include <hip/hip_runtime.h>
#include <hip/hip_bf16.h>

#define N_NODES 8000
#define N_EDGES 64000
#define NBATCH  64
#define NGRID   12
#define HIDC    128
#define MNPB    8
#define EB      64
#define SE      8
#define NBLK    (N_EDGES / EB)

typedef __bf16 bf16x8 __attribute__((ext_vector_type(8)));
typedef __bf16 bf16x4 __attribute__((ext_vector_type(4)));
typedef float  f32x4  __attribute__((ext_vector_type(4)));
typedef int    i32x4  __attribute__((ext_vector_type(4)));

// gelu = x * sigmoid(2u); fast v_rcp (err ~1e-6)
__device__ __forceinline__ float gelu_f(float x) {
    float u = 0.7978845608f * x * (1.0f + 0.044715f * x * x);
    float e = __expf(2.0f * u);
    float r = __builtin_amdgcn_rcpf(e + 1.0f);
    return x * (1.0f - r);
}

// ---------------- grid0 + per-batch rotated grids ----------------
__global__ void k_grid(const float* __restrict__ Q, float* __restrict__ grid0,
                       float* __restrict__ grid) {
    int t = threadIdx.x;
    __shared__ float g0[12][3];
    if (t < 12) {
        float fi = (float)t;
        float theta = 6.28318530717958647692f * fi / 1.61803398874989484820f;
        float z = 1.0f - (2.0f * fi + 1.0f) / 12.0f;
        float r = sqrtf(fmaxf(1.0f - z * z, 0.0f));
        g0[t][0] = r * cosf(theta);
        g0[t][1] = r * sinf(theta);
        g0[t][2] = z;
        grid0[t * 3 + 0] = g0[t][0];
        grid0[t * 3 + 1] = g0[t][1];
        grid0[t * 3 + 2] = g0[t][2];
    }
    __syncthreads();
    for (int idx = t; idx < NBATCH * 12 * 3; idx += blockDim.x) {
        int b = idx / 36, rmd = idx % 36, n = rmd / 3, i = rmd % 3;
        float acc = 0.f;
        #pragma unroll
        for (int j = 0; j < 3; ++j) acc += Q[b * 9 + i * 3 + j] * g0[n][j];
        grid[idx] = acc;
    }
}

// ---------------- kb_sh -> fk  (fk layout: [l][p][c][o]) ----------------
__global__ __launch_bounds__(128) void k_kbsh(
    const float* __restrict__ grid0,
    const float* __restrict__ Wsh1, const float* __restrict__ bsh1,
    const float* __restrict__ Wsh2, const float* __restrict__ bsh2,
    const float* __restrict__ Wfk, float* __restrict__ fk) {
    int row = blockIdx.x;
    int p = row / 12, o = row % 12, t = threadIdx.x;
    float tt = grid0[p*3]*grid0[o*3] + grid0[p*3+1]*grid0[o*3+1] + grid0[p*3+2]*grid0[o*3+2];
    float p1 = tt, p2 = tt * tt, p3 = p2 * tt;
    float h1 = gelu_f(p1 * Wsh1[t] + p2 * Wsh1[128 + t] + p3 * Wsh1[256 + t] + bsh1[t]);
    __shared__ float h1S[128];
    __shared__ float h2S[128];
    h1S[t] = h1;
    __syncthreads();
    float acc = bsh2[t];
    #pragma unroll 8
    for (int k = 0; k < 128; ++k) acc += h1S[k] * Wsh2[k * 128 + t];
    h2S[t] = gelu_f(acc);
    __syncthreads();
    for (int l = 0; l < 3; ++l) {
        float a = 0.f;
        #pragma unroll 8
        for (int k = 0; k < 128; ++k) a += h2S[k] * Wfk[l * 16384 + k * 128 + t];
        fk[l * 18432 + (p * 128 + t) * 12 + o] = a;
    }
}

// ---------------- embed (round-7 verified version) ----------------
__global__ __launch_bounds__(128) void k_embed(
    const float* __restrict__ x, const float* __restrict__ vec,
    const int* __restrict__ batch, const float* __restrict__ grid,
    const float* __restrict__ Wemb, float* __restrict__ node_grid,
    __bf16* __restrict__ h_bf) {
    __shared__ float WembS[18 * 128];
    __shared__ float ngS[36];
    __shared__ float xS[16];
    __shared__ float vS[6];
    int n = blockIdx.x, t = threadIdx.x;
    for (int i = t; i < 18 * 128; i += 128) WembS[i] = Wemb[i];
    int b = batch[n];
    if (t < 36) { float g = grid[b * 36 + t]; ngS[t] = g; node_grid[n * 36 + t] = g; }
    if (t < 16) xS[t] = x[n * 16 + t];
    if (t >= 16 && t < 22) vS[t - 16] = vec[n * 6 + (t - 16)];
    __syncthreads();
    for (int g = 0; g < NGRID; ++g) {
        float g0 = ngS[g*3], g1 = ngS[g*3+1], g2 = ngS[g*3+2];
        float xv0 = vS[0]*g0 + vS[1]*g1 + vS[2]*g2;
        float xv1 = vS[3]*g0 + vS[4]*g1 + vS[5]*g2;
        float acc = xv0 * WembS[16*128 + t] + xv1 * WembS[17*128 + t];
        #pragma unroll
        for (int j = 0; j < 16; ++j) acc += xS[j] * WembS[j*128 + t];
        h_bf[((size_t)n * NGRID + g) * HIDC + t] = (__bf16)acc;
    }
}

// ---------------- CSR build ----------------
__global__ __launch_bounds__(256) void k_deg(const int* __restrict__ recv,
                                             int* __restrict__ deg) {
    int e = blockIdx.x * 256 + threadIdx.x;
    if (e < N_EDGES) atomicAdd(&deg[recv[e]], 1);
}

__global__ __launch_bounds__(1024) void k_scan(const int* __restrict__ deg,
                                               int* __restrict__ rowptr,
                                               int* __restrict__ cursor) {
    __shared__ int part[1024];
    int t = threadIdx.x;
    int base = t * 8;
    int local[8];
    int s = 0;
    #pragma unroll
    for (int j = 0; j < 8; ++j) {
        int idx = base + j;
        int v = (idx < N_NODES) ? deg[idx] : 0;
        local[j] = s;
        s += v;
    }
    part[t] = s;
    __syncthreads();
    for (int off = 1; off < 1024; off <<= 1) {
        int v = (t >= off) ? part[t - off] : 0;
        __syncthreads();
        part[t] += v;
        __syncthreads();
    }
    int excl = (t == 0) ? 0 : part[t - 1];
    #pragma unroll
    for (int j = 0; j < 8; ++j) {
        int idx = base + j;
        if (idx < N_NODES) {
            int v = excl + local[j];
            rowptr[idx] = v;
            cursor[idx] = v;
        }
    }
    if (t == 1023) rowptr[N_NODES] = part[1023];
}

__global__ __launch_bounds__(256) void k_fill(const int* __restrict__ recv,
                                              int* __restrict__ cursor,
                                              int* __restrict__ perm) {
    int e = blockIdx.x * 256 + threadIdx.x;
    if (e < N_EDGES) {
        int r = recv[e];
        int p = atomicAdd(&cursor[r], 1);
        perm[p] = e;
    }
}

// ---------------- attrs (recv-sorted) ----------------
__global__ __launch_bounds__(256) void k_attr_sorted(
    const float* __restrict__ pos, const float* __restrict__ ng,
    const int* __restrict__ send, const int* __restrict__ recv,
    const int* __restrict__ perm,
    float* __restrict__ attr_s, int* __restrict__ send_s,
    int* __restrict__ recv_s) {
    int idx = blockIdx.x * 256 + threadIdx.x;
    if (idx >= (N_EDGES + 16) * 12) return;
    int i = idx / 12, g = idx % 12;
    if (i < N_EDGES) {
        int e = perm[i];
        int s = send[e], r = recv[e];
        float rx = pos[s*3+0] - pos[r*3+0];
        float ry = pos[s*3+1] - pos[r*3+1];
        float rz = pos[s*3+2] - pos[r*3+2];
        const float* gr = ng + ((size_t)r * 12 + g) * 3;
        float g0 = gr[0], g1 = gr[1], g2 = gr[2];
        float iv1 = rx*g0 + ry*g1 + rz*g2;
        float wx = rx - iv1*g0, wy = ry - iv1*g1, wz = rz - iv1*g2;
        attr_s[(size_t)idx * 2 + 0] = iv1;
        attr_s[(size_t)idx * 2 + 1] = sqrtf(wx*wx + wy*wy + wz*wz);
        if (g == 0) { send_s[i] = s; recv_s[i] = r; }
    } else {
        attr_s[(size_t)idx * 2 + 0] = 0.f;
        attr_s[(size_t)idx * 2 + 1] = 0.f;
        if (g == 0) { send_s[i] = 0; recv_s[i] = 0; }
    }
}

// ---- transposed bf16 weights [Wsp2T | WkT | W1T | W2T] ----
__global__ __launch_bounds__(256) void k_prepw2(
    const float* __restrict__ Wsp2, const float* __restrict__ Wk,
    const float* __restrict__ W1, const float* __restrict__ W2,
    __bf16* __restrict__ WT) {
    int i = blockIdx.x * 256 + threadIdx.x;
    if (i >= 7 * 65536) return;
    float v;
    if (i < 65536) {
        int buf = i >> 14, r = i & 16383;
        int n = r >> 7, k = r & 127;
        v = (buf == 0) ? Wsp2[k * 128 + n] : Wk[(buf - 1) * 16384 + k * 128 + n];
    } else {
        int i2 = i - 65536;
        int l = i2 >> 16, r = i2 & 65535;
        if (l < 3) {
            int n = r >> 7, k = r & 127;
            v = W1[l * 65536 + k * 512 + n];
        } else {
            int l2 = l - 3;
            int n = r >> 9, k = r & 511;
            v = W2[l2 * 65536 + k * 128 + n];
        }
    }
    WT[i] = (__bf16)v;
}

// ---- int8 Wk (transposed, per-column scales) ----
__global__ __launch_bounds__(128) void k_prepw_i8(
    const float* __restrict__ Wk, signed char* __restrict__ Wk8,
    float* __restrict__ s_c) {
    int i = blockIdx.x * 128 + threadIdx.x;
    if (i >= 384) return;
    int l = i / 128, col = i % 128;
    float mx = 0.f;
    for (int k = 0; k < 128; ++k)
        mx = fmaxf(mx, fabsf(Wk[l * 16384 + k * 128 + col]));
    float s = fmaxf(mx * (1.0f / 127.0f), 1e-20f);
    s_c[i] = s;
    float inv = 127.0f / fmaxf(mx, 1e-20f);
    for (int k = 0; k < 128; ++k) {
        int q = __float2int_rn(Wk[l * 16384 + k * 128 + col] * inv);
        q = q > 127 ? 127 : (q < -127 ? -127 : q);
        Wk8[(size_t)l * 16384 + col * 128 + k] = (signed char)q;
    }
}

// ---- combined poly weights WP1T [128 cols x 32 k] bf16 (bias at k=9) ----
__global__ __launch_bounds__(128) void k_prepw_p(
    const float* __restrict__ Wsp1, const float* __restrict__ bsp1,
    __bf16* __restrict__ WP1T) {
    int col = threadIdx.x;
    float w1[14];
    #pragma unroll
    for (int j = 0; j < 14; ++j) w1[j] = Wsp1[j * 128 + col];
    float vals[10];
    vals[0] = w1[0];                       // a
    vals[1] = w1[1];                       // b
    vals[2] = w1[2];                       // aa
    vals[3] = w1[3] + w1[4];               // ab
    vals[4] = w1[5];                       // bb
    vals[5] = w1[6];                       // aaa
    vals[6] = w1[7] + w1[8] + w1[10];      // aab
    vals[7] = w1[9] + w1[11] + w1[12];     // abb
    vals[8] = w1[13];                      // bbb
    vals[9] = bsp1[col];                   // bias (monomial 1)
    for (int k = 0; k < 32; ++k)
        WP1T[col * 32 + k] = (k < 10) ? (__bf16)vals[k] : (__bf16)0.f;
}

// ---- Wro packed per-layer into MFMA B-fragment per-lane layout ----
__global__ __launch_bounds__(192) void k_prepw_ro(
    const float* __restrict__ Wro, __bf16* __restrict__ WroF) {
    int t = threadIdx.x;
    int l = t / 64, lane = t % 64;
    int l15 = lane & 15, quad = lane >> 4;
    #pragma unroll
    for (int ks = 0; ks < 4; ++ks)
        #pragma unroll
        for (int j = 0; j < 8; ++j) {
            int k = ks * 32 + quad * 8 + j;
            float v = (l15 < 9) ? Wro[l * 1152 + k * 9 + l15] : 0.f;
            WroF[(size_t)(l * 64 + lane) * 32 + ks * 8 + j] = (__bf16)v;
        }
}

// ---------------- kb precompute (once): MFMA poly -> GEMM1 -> gelu -> kb int8 ----------------
// Round-25: rowmax scan parallelized over all 256 threads (was t<64 serial
// over 128 cols; now 4 threads/row + LDS combine).
__global__ __launch_bounds__(256, 4) void k_kb_i8(
    const float* __restrict__ attr_s,
    const __bf16* __restrict__ W2T, const __bf16* __restrict__ WP1T,
    const float* __restrict__ bsp2,
    signed char* __restrict__ kb8, float* __restrict__ s_r) {
    __shared__ __align__(16) __bf16 H1[64 * 136];
    __shared__ __align__(16) signed char K8[64 * 144];
    __shared__ float rowmaxS[64];
    __shared__ float rm4[64][4];
    int t = threadIdx.x;
    int lane = t & 63, w = t >> 6, l15 = lane & 15, quad = lane >> 4;
    size_t grow0 = (size_t)blockIdx.x * 64;
    // ---- poly via MFMA: wave w owns rows w*16 + l15 ----
    {
        float2 ab = ((const float2*)attr_s)[grow0 + w * 16 + l15];
        float a = ab.x, b = ab.y;
        float aa = a * a, abm = a * b, bb = b * b;
        float m0 = quad == 0 ? a        : (quad == 1 ? bb * b : 0.f);
        float m1 = quad == 0 ? b        : (quad == 1 ? 1.f    : 0.f);
        float m2 = quad == 0 ? aa       : 0.f;
        float m3 = quad == 0 ? abm      : 0.f;
        float m4 = quad == 0 ? bb       : 0.f;
        float m5 = quad == 0 ? aa * a   : 0.f;
        float m6 = quad == 0 ? aa * b   : 0.f;
        float m7 = quad == 0 ? abm * b  : 0.f;
        bf16x8 afrag = { (__bf16)m0, (__bf16)m1, (__bf16)m2, (__bf16)m3,
                         (__bf16)m4, (__bf16)m5, (__bf16)m6, (__bf16)m7 };
        #pragma unroll
        for (int n = 0; n < 8; ++n) {
            bf16x8 bp = *(const bf16x8*)(WP1T + (n * 16 + l15) * 32 + quad * 8);
            f32x4 cacc = {0.f, 0.f, 0.f, 0.f};
            cacc = __builtin_amdgcn_mfma_f32_16x16x32_bf16(afrag, bp, cacc, 0, 0, 0);
            #pragma unroll
            for (int rg = 0; rg < 4; ++rg) {
                int row = w * 16 + quad * 4 + rg;
                H1[row * 136 + n * 16 + l15] = (__bf16)gelu_f(cacc[rg]);
            }
        }
    }
    __syncthreads();
    bf16x8 Bf[2][4];
    #pragma unroll
    for (int j = 0; j < 2; ++j)
        #pragma unroll
        for (int ks = 0; ks < 4; ++ks)
            Bf[j][ks] = *(const bf16x8*)(W2T + (size_t)(w * 32 + j * 16 + l15) * 128 + ks * 32 + quad * 8);
    float b2v[2] = { bsp2[w * 32 + l15], bsp2[w * 32 + 16 + l15] };
    f32x4 acc[4][2];
    #pragma unroll
    for (int mt = 0; mt < 4; ++mt) {
        acc[mt][0] = (f32x4){0.f,0.f,0.f,0.f};
        acc[mt][1] = (f32x4){0.f,0.f,0.f,0.f};
        #pragma unroll
        for (int ks = 0; ks < 4; ++ks) {
            bf16x8 af = *(const bf16x8*)(H1 + (mt * 16 + l15) * 136 + ks * 32 + quad * 8);
            acc[mt][0] = __builtin_amdgcn_mfma_f32_16x16x32_bf16(af, Bf[0][ks], acc[mt][0], 0, 0, 0);
            acc[mt][1] = __builtin_amdgcn_mfma_f32_16x16x32_bf16(af, Bf[1][ks], acc[mt][1], 0, 0, 0);
        }
    }
    float g[4][2][4];
    #pragma unroll
    for (int mt = 0; mt < 4; ++mt)
        #pragma unroll
        for (int j = 0; j < 2; ++j)
            #pragma unroll
            for (int rg = 0; rg < 4; ++rg)
                g[mt][j][rg] = gelu_f(acc[mt][j][rg] + b2v[j]);
    __syncthreads();
    #pragma unroll
    for (int mt = 0; mt < 4; ++mt)
        #pragma unroll
        for (int j = 0; j < 2; ++j)
            #pragma unroll
            for (int rg = 0; rg < 4; ++rg) {
                int row = mt * 16 + quad * 4 + rg;
                H1[row * 136 + w * 32 + j * 16 + l15] = (__bf16)g[mt][j][rg];
            }
    __syncthreads();
    // ---- parallel rowmax: 4 threads per row ----
    {
        int row = t & 63, qt = t >> 6;
        float mx = 0.f;
        #pragma unroll
        for (int ks = 0; ks < 4; ++ks) {
            bf16x8 xv = *(const bf16x8*)(H1 + row * 136 + qt * 32 + ks * 8);
            #pragma unroll
            for (int m = 0; m < 8; ++m) mx = fmaxf(mx, fabsf((float)xv[m]));
        }
        rm4[row][qt] = mx;
    }
    __syncthreads();
    if (t < 64) {
        float mx = fmaxf(fmaxf(rm4[t][0], rm4[t][1]), fmaxf(rm4[t][2], rm4[t][3]));
        float s = fmaxf(mx * (1.0f / 127.0f), 1e-20f);
        rowmaxS[t] = s;
        s_r[grow0 + t] = s;
    }
    __syncthreads();
    #pragma unroll
    for (int mt = 0; mt < 4; ++mt)
        #pragma unroll
        for (int j = 0; j < 2; ++j)
            #pragma unroll
            for (int rg = 0; rg < 4; ++rg) {
                int row = mt * 16 + quad * 4 + rg;
                float inv = __builtin_amdgcn_rcpf(rowmaxS[row]);
                int q = __float2int_rn(g[mt][j][rg] * inv);
                q = q > 127 ? 127 : (q < -127 ? -127 : q);
                K8[row * 144 + w * 32 + j * 16 + l15] = (signed char)q;
            }
    __syncthreads();
    #pragma unroll
    for (int it = 0; it < 2; ++it) {
        int idx = it * 256 + t;
        int row = idx >> 3, cv = idx & 7;
        *(uint4*)(kb8 + (grow0 + row) * 128 + cv * 16) =
            *(const uint4*)(K8 + row * 144 + cv * 16);
    }
}

// -------- fused per-layer GEMM2 + scatter (node-aligned, NO atomics) --------
// Round-25: register-prefetched kb8 staging (T14 async-STAGE split, the
// mechanism verified on k_mlp in round 11). Sub-tile i+1's kb8 loads issue
// BEFORE sub-tile i's MFMA+scatter, so their L2 latency hides under ~500
// cycles of compute instead of stalling the stage phase behind a barrier.
__global__ __launch_bounds__(256, 4) void k_gscat2(
    const signed char* __restrict__ kb8, const float* __restrict__ s_r,
    const signed char* __restrict__ Wk8, const float* __restrict__ s_cL,
    const int* __restrict__ send_s, const int* __restrict__ recv_s,
    const int* __restrict__ rowptr, const __bf16* __restrict__ h_bf,
    __bf16* __restrict__ aggb) {
    __shared__ __align__(16) signed char T8[96 * 144];
    __shared__ __align__(16) __bf16 P[96 * 136];
    __shared__ float srS[96];
    int t = threadIdx.x;
    int lane = t & 63, w = t >> 6, l15 = lane & 15, quad = lane >> 4;
    int bid = blockIdx.x;
    int n0, n1;
    {
        if (bid == 0) n0 = 0;
        else {
            int tgt = bid * EB, lo = 0, hi = N_NODES;
            while (lo < hi) { int m = (lo + hi) >> 1; if (rowptr[m] < tgt) lo = m + 1; else hi = m; }
            n0 = lo;
        }
        if (bid == NBLK - 1) n1 = N_NODES;
        else {
            int tgt = (bid + 1) * EB, lo = 0, hi = N_NODES;
            while (lo < hi) { int m = (lo + hi) >> 1; if (rowptr[m] < tgt) lo = m + 1; else hi = m; }
            n1 = lo;
        }
    }
    if (n0 >= n1) return;                    // uniform: no barriers crossed
    int e0 = rowptr[n0], e1 = rowptr[n1];
    long long Bf[2][4];
    #pragma unroll
    for (int j = 0; j < 2; ++j)
        #pragma unroll
        for (int ks = 0; ks < 4; ++ks)
            Bf[j][ks] = *(const long long*)(Wk8 + (size_t)(w * 32 + j * 16 + l15) * 128 + ks * 32 + quad * 8);
    float sc0 = s_cL[w * 32 + l15], sc1 = s_cL[w * 32 + 16 + l15];
    int c = t & 127, half = t >> 7;
    float acc[6] = {0.f, 0.f, 0.f, 0.f, 0.f, 0.f};
    int cur = (e0 < e1) ? recv_s[e0] : -1;
    // ---- prefetch sub-tile 0 into registers ----
    uint4 R0, R1, R2;
    float Rs = 0.f;
    bool v0, v1, v2, vs;
    {
        int cnt = e1 - e0; if (cnt > SE) cnt = SE;
        int nr8 = cnt * 96;                  // nrows*8
        v0 = t < nr8;
        v1 = 256 + t < nr8;
        v2 = 512 + t < nr8;
        vs = t < cnt * 12;
        if (v0) { int idx = t;       R0 = *(const uint4*)(kb8 + ((size_t)e0 * 12 + (idx >> 3)) * 128 + (idx & 7) * 16); }
        if (v1) { int idx = 256 + t; R1 = *(const uint4*)(kb8 + ((size_t)e0 * 12 + (idx >> 3)) * 128 + (idx & 7) * 16); }
        if (v2) { int idx = 512 + t; R2 = *(const uint4*)(kb8 + ((size_t)e0 * 12 + (idx >> 3)) * 128 + (idx & 7) * 16); }
        if (vs) Rs = s_r[(size_t)e0 * 12 + t];
    }
    for (int et0 = e0; et0 < e1; et0 += SE) {
        int cnt = e1 - et0; if (cnt > SE) cnt = SE;
        int nrows = cnt * 12;
        __syncthreads();                     // previous scatter done reading P; T8 free
        // commit prefetched registers to LDS
        if (v0) { int idx = t;       *(uint4*)(T8 + (idx >> 3) * 144 + (idx & 7) * 16) = R0; }
        if (v1) { int idx = 256 + t; *(uint4*)(T8 + (idx >> 3) * 144 + (idx & 7) * 16) = R1; }
        if (v2) { int idx = 512 + t; *(uint4*)(T8 + (idx >> 3) * 144 + (idx & 7) * 16) = R2; }
        if (vs) srS[t] = Rs;
        __syncthreads();
        // issue next sub-tile's loads (latency hides under MFMA + scatter)
        int net0 = et0 + SE;
        if (net0 < e1) {
            int ncnt = e1 - net0; if (ncnt > SE) ncnt = SE;
            int nr8 = ncnt * 96;
            v0 = t < nr8;
            v1 = 256 + t < nr8;
            v2 = 512 + t < nr8;
            vs = t < ncnt * 12;
            if (v0) { int idx = t;       R0 = *(const uint4*)(kb8 + ((size_t)net0 * 12 + (idx >> 3)) * 128 + (idx & 7) * 16); }
            if (v1) { int idx = 256 + t; R1 = *(const uint4*)(kb8 + ((size_t)net0 * 12 + (idx >> 3)) * 128 + (idx & 7) * 16); }
            if (v2) { int idx = 512 + t; R2 = *(const uint4*)(kb8 + ((size_t)net0 * 12 + (idx >> 3)) * 128 + (idx & 7) * 16); }
            if (vs) Rs = s_r[(size_t)net0 * 12 + t];
        }
        int nrt = (nrows + 15) >> 4;
        for (int rt = 0; rt < nrt; ++rt) {
            i32x4 a0 = (i32x4){0, 0, 0, 0};
            i32x4 a1 = (i32x4){0, 0, 0, 0};
            #pragma unroll
            for (int ks = 0; ks < 4; ++ks) {
                long long a = *(const long long*)(T8 + (rt * 16 + l15) * 144 + ks * 32 + quad * 8);
                a0 = __builtin_amdgcn_mfma_i32_16x16x32_i8(a, Bf[0][ks], a0, 0, 0, 0);
                a1 = __builtin_amdgcn_mfma_i32_16x16x32_i8(a, Bf[1][ks], a1, 0, 0, 0);
            }
            #pragma unroll
            for (int rg = 0; rg < 4; ++rg) {
                int row = rt * 16 + quad * 4 + rg;
                float sr = srS[row];
                P[row * 136 + w * 32 + l15]      = (__bf16)((float)a0[rg] * sr * sc0);
                P[row * 136 + w * 32 + 16 + l15] = (__bf16)((float)a1[rg] * sr * sc1);
            }
        }
        __syncthreads();
        for (int el = 0; el < cnt; ++el) {
            int e = et0 + el;
            int r = recv_s[e];
            if (r != cur) {
                __bf16* op = aggb + ((size_t)cur * 128 + c) * 12 + half * 6;
                #pragma unroll
                for (int j = 0; j < 6; ++j) { op[j] = (__bf16)acc[j]; acc[j] = 0.f; }
                cur = r;
            }
            int s = send_s[e];
            const __bf16* hp = h_bf + (size_t)s * 1536 + half * 6 * 128 + c;
            const __bf16* pp = P + (el * 12 + half * 6) * 136 + c;
            #pragma unroll
            for (int j = 0; j < 6; ++j)
                acc[j] += (float)hp[j * 128] * (float)pp[j * 136];
        }
    }
    if (e0 < e1) {
        __bf16* op = aggb + ((size_t)cur * 128 + c) * 12 + half * 6;
        #pragma unroll
        for (int j = 0; j < 6; ++j) op[j] = (__bf16)acc[j];
    }
    for (int n = n0; n < n1; ++n) {
        if (rowptr[n] == rowptr[n + 1]) {
            __bf16* op = aggb + ((size_t)n * 128 + c) * 12 + half * 6;
            #pragma unroll
            for (int j = 0; j < 6; ++j) op[j] = (__bf16)0.f;
        }
    }
}

// ---------------- node kernel: conv + LN + MFMA MLP + MFMA readout ----------------
// Round-11 verified version (software-pipelined weights, -45 µs/dispatch).
__global__ __launch_bounds__(256, 3) void k_mlp(
    const __bf16* __restrict__ aggb, const float* __restrict__ fkl,
    const float* __restrict__ bconv, const float* __restrict__ ln_g,
    const float* __restrict__ ln_b,
    const __bf16* __restrict__ W1T, const float* __restrict__ b1,
    const __bf16* __restrict__ W2T2, const float* __restrict__ b2,
    const __bf16* __restrict__ WroFl, const float* __restrict__ bro,
    __bf16* __restrict__ h_bf, float* __restrict__ readout) {
    __shared__ __align__(16) __bf16 X[96 * 136];
    __shared__ __align__(16) __bf16 H4[96 * 136];
    __shared__ float redS[96][2];
    int t = threadIdx.x;
    int lane = t & 63, w = t >> 6, l15 = lane & 15, quad = lane >> 4;
    int c = t & 127, nh = t >> 7;
    int n0 = blockIdx.x * MNPB;
    float bcv = bconv[c];
    // ---- conv: thread owns channel c, nodes {nh, nh+2, nh+4, nh+6} ----
    {
        float a2[4][12];
        #pragma unroll
        for (int u = 0; u < 4; ++u) {
            const __bf16* ap = aggb + ((size_t)(n0 + nh + u * 2) * 128 + c) * 12;
            #pragma unroll
            for (int v = 0; v < 3; ++v) {
                bf16x4 pk = *(const bf16x4*)(ap + v * 4);
                #pragma unroll
                for (int j = 0; j < 4; ++j) a2[u][v * 4 + j] = (float)pk[j];
            }
        }
        #pragma unroll 4
        for (int p = 0; p < 12; ++p) {
            const float* fp = fkl + ((size_t)p * 128 + c) * 12;
            float fr[12];
            #pragma unroll
            for (int v = 0; v < 3; ++v) {
                float4 fv = *(const float4*)(fp + v * 4);
                fr[v*4+0] = fv.x; fr[v*4+1] = fv.y; fr[v*4+2] = fv.z; fr[v*4+3] = fv.w;
            }
            #pragma unroll
            for (int u = 0; u < 4; ++u) {
                float s = 0.f;
                #pragma unroll
                for (int o = 0; o < 12; ++o) s += a2[u][o] * fr[o];
                X[((nh + u * 2) * 12 + p) * 136 + c] = (__bf16)(s * (1.0f / 12.0f) + bcv);
            }
        }
    }
    __syncthreads();
    // ---- LN stats: wave w owns rows w*24 .. w*24+24 ----
    for (int r = w * 24; r < w * 24 + 24; ++r) {
        float v0 = (float)X[r * 136 + lane];
        float v1 = (float)X[r * 136 + 64 + lane];
        float s = v0 + v1, s2 = v0 * v0 + v1 * v1;
        for (int off = 32; off > 0; off >>= 1) {
            s += __shfl_down(s, off);
            s2 += __shfl_down(s2, off);
        }
        if (lane == 0) {
            float mu = s * (1.0f / 128.0f);
            float var = s2 * (1.0f / 128.0f) - mu * mu;
            redS[r][0] = mu;
            redS[r][1] = rsqrtf(var + 1e-5f);
        }
    }
    __syncthreads();
    float gv = ln_g[c], bv = ln_b[c];
    #pragma unroll
    for (int nn = nh; nn < 8; nn += 2)
        #pragma unroll
        for (int p = 0; p < 12; ++p) {
            int r = nn * 12 + p;
            float v = (float)X[r * 136 + c];
            X[r * 136 + c] = (__bf16)((v - redS[r][0]) * redS[r][1] * gv + bv);
        }
    __syncthreads();
    // ---- MLP: 4 phases of 128 hidden cols, 6 row-tiles; pipelined weights ----
    f32x4 acc2[6][2];
    #pragma unroll
    for (int mt = 0; mt < 6; ++mt)
        #pragma unroll
        for (int j = 0; j < 2; ++j) acc2[mt][j] = (f32x4){0.f, 0.f, 0.f, 0.f};
    bf16x8 W1f[2][4];
    #pragma unroll
    for (int nt = 0; nt < 2; ++nt)
        #pragma unroll
        for (int ks = 0; ks < 4; ++ks)
            W1f[nt][ks] = *(const bf16x8*)(W1T + (size_t)(w * 32 + nt * 16 + l15) * 128 + ks * 32 + quad * 8);
    for (int ph = 0; ph < 4; ++ph) {
        if (ph) __syncthreads();
        bf16x8 W2f[2][4];
        #pragma unroll
        for (int j = 0; j < 2; ++j)
            #pragma unroll
            for (int ks = 0; ks < 4; ++ks)
                W2f[j][ks] = *(const bf16x8*)(W2T2 + (size_t)(w * 32 + j * 16 + l15) * 512 + ph * 128 + ks * 32 + quad * 8);
        float bj0 = b1[ph * 128 + w * 32 + l15];
        float bj1 = b1[ph * 128 + w * 32 + 16 + l15];
        #pragma unroll
        for (int mt = 0; mt < 6; ++mt) {
            bf16x8 af[4];
            #pragma unroll
            for (int ks = 0; ks < 4; ++ks)
                af[ks] = *(const bf16x8*)(X + (mt * 16 + l15) * 136 + ks * 32 + quad * 8);
            f32x4 a0 = {0.f, 0.f, 0.f, 0.f};
            f32x4 a1 = {0.f, 0.f, 0.f, 0.f};
            #pragma unroll
            for (int ks = 0; ks < 4; ++ks) {
                a0 = __builtin_amdgcn_mfma_f32_16x16x32_bf16(af[ks], W1f[0][ks], a0, 0, 0, 0);
                a1 = __builtin_amdgcn_mfma_f32_16x16x32_bf16(af[ks], W1f[1][ks], a1, 0, 0, 0);
            }
            #pragma unroll
            for (int rg = 0; rg < 4; ++rg) {
                int row = mt * 16 + quad * 4 + rg;
                H4[row * 136 + w * 32 + l15]      = (__bf16)gelu_f(a0[rg] + bj0);
                H4[row * 136 + w * 32 + 16 + l15] = (__bf16)gelu_f(a1[rg] + bj1);
            }
        }
        if (ph < 3) {
            #pragma unroll
            for (int nt = 0; nt < 2; ++nt)
                #pragma unroll
                for (int ks = 0; ks < 4; ++ks)
                    W1f[nt][ks] = *(const bf16x8*)(W1T + (size_t)((ph + 1) * 128 + w * 32 + nt * 16 + l15) * 128 + ks * 32 + quad * 8);
        }
        __syncthreads();
        #pragma unroll
        for (int mt = 0; mt < 6; ++mt)
            #pragma unroll
            for (int ks = 0; ks < 4; ++ks) {
                bf16x8 af = *(const bf16x8*)(H4 + (mt * 16 + l15) * 136 + ks * 32 + quad * 8);
                acc2[mt][0] = __builtin_amdgcn_mfma_f32_16x16x32_bf16(af, W2f[0][ks], acc2[mt][0], 0, 0, 0);
                acc2[mt][1] = __builtin_amdgcn_mfma_f32_16x16x32_bf16(af, W2f[1][ks], acc2[mt][1], 0, 0, 0);
            }
    }
    // ---- residual h update (writes h_bf + X) ----
    #pragma unroll
    for (int mt = 0; mt < 6; ++mt) {
        float bj0 = b2[w * 32 + l15], bj1 = b2[w * 32 + 16 + l15];
        #pragma unroll
        for (int rg = 0; rg < 4; ++rg) {
            int row = mt * 16 + quad * 4 + rg;
            int node = n0 + row / 12, pp = row % 12;
            size_t hi = ((size_t)node * 12 + pp) * 128;
            {
                int col = w * 32 + l15;
                float hv = (float)h_bf[hi + col] + acc2[mt][0][rg] + bj0;
                h_bf[hi + col] = (__bf16)hv;
                X[row * 136 + col] = (__bf16)hv;
            }
            {
                int col = w * 32 + 16 + l15;
                float hv = (float)h_bf[hi + col] + acc2[mt][1][rg] + bj1;
                h_bf[hi + col] = (__bf16)hv;
                X[row * 136 + col] = (__bf16)hv;
            }
        }
    }
    __syncthreads();
    // ---- readout via MFMA: 6 row-tiles over 4 waves, B-frag from WroF ----
    for (int mt2 = w; mt2 < 6; mt2 += 4) {
        const __bf16* wp = WroFl + (size_t)lane * 32;
        f32x4 a = {0.f, 0.f, 0.f, 0.f};
        #pragma unroll
        for (int ks = 0; ks < 4; ++ks) {
            bf16x8 af = *(const bf16x8*)(X + (mt2 * 16 + l15) * 136 + ks * 32 + quad * 8);
            bf16x8 bf = *(const bf16x8*)(wp + ks * 8);
            a = __builtin_amdgcn_mfma_f32_16x16x32_bf16(af, bf, a, 0, 0, 0);
        }
        if (l15 < 9) {
            float bj = bro[l15];
            #pragma unroll
            for (int rg = 0; rg < 4; ++rg) {
                int row = mt2 * 16 + quad * 4 + rg;
                int node = n0 + row / 12, pp = row % 12;
                size_t ri = ((size_t)node * 12 + pp) * 9 + l15;
                readout[ri] += (a[rg] + bj) * (1.0f / 3.0f);
            }
        }
    }
}

// ---------------- final pooling ----------------
__global__ __launch_bounds__(128) void k_out(
    const float* __restrict__ readout, const float* __restrict__ node_grid,
    const int* __restrict__ batch, float* __restrict__ out) {
    int n = blockIdx.x * 128 + threadIdx.x;
    if (n >= N_NODES) return;
    int b = batch[n];
    const float* ro = readout + (size_t)n * 108;
    float ss[8] = {0, 0, 0, 0, 0, 0, 0, 0};
    float v0 = 0.f, v1 = 0.f, v2 = 0.f;
    for (int p = 0; p < 12; ++p) {
        #pragma unroll
        for (int j = 0; j < 8; ++j) ss[j] += ro[p * 9 + j];
        float rv = ro[p * 9 + 8];
        v0 += rv * node_grid[n * 36 + p * 3 + 0];
        v1 += rv * node_grid[n * 36 + p * 3 + 1];
        v2 += rv * node_grid[n * 36 + p * 3 + 2];
    }
    #pragma unroll
    for (int j = 0; j < 8; ++j) atomicAdd(&out[b * 8 + j], ss[j] * (1.0f / 12.0f));
    atomicAdd(&out[512 + b * 3 + 0], v0 * (1.0f / 12.0f));
    atomicAdd(&out[512 + b * 3 + 1], v1 * (1.0f / 12.0f));
    atomicAdd(&out[512 + b * 3 + 2], v2 * (1.0f / 12.0f));
}

extern "C" void kernel_launch(void* const* d_in, const int* in_sizes, int n_in,
                              void* d_out, int out_size, void* d_ws, size_t ws_size,
                              hipStream_t stream) {
    const float* x    = (const float*)d_in[0];
    const float* vec  = (const float*)d_in[1];
    const float* pos  = (const float*)d_in[2];
    const float* Q    = (const float*)d_in[3];
    const float* Wsp1 = (const float*)d_in[4];
    const float* bsp1 = (const float*)d_in[5];
    const float* Wsp2 = (const float*)d_in[6];
    const float* bsp2 = (const float*)d_in[7];
    const float* Wsh1 = (const float*)d_in[8];
    const float* bsh1 = (const float*)d_in[9];
    const float* Wsh2 = (const float*)d_in[10];
    const float* bsh2 = (const float*)d_in[11];
    const float* Wemb = (const float*)d_in[12];
    const float* Wk   = (const float*)d_in[13];
    const float* Wfk  = (const float*)d_in[14];
    const float* bconv= (const float*)d_in[15];
    const float* ln_g = (const float*)d_in[16];
    const float* ln_b = (const float*)d_in[17];
    const float* W1   = (const float*)d_in[18];
    const float* b1   = (const float*)d_in[19];
    const float* W2   = (const float*)d_in[20];
    const float* b2   = (const float*)d_in[21];
    const float* Wro  = (const float*)d_in[22];
    const float* bro  = (const float*)d_in[23];
    const int* ei     = (const int*)d_in[24];
    const int* batch  = (const int*)d_in[25];
    const int* send = ei;
    const int* recv = ei + N_EDGES;

    float* ws = (float*)d_ws;
    float* grid0  = ws;
    float* grid   = ws + 64;
    float* fk     = ws + 2368;
    float* ng     = ws + 57664;
    float* ro     = ws + 345664;
    float* attr_s = ws + 1209664;
    const size_t P_WT  = 2746048;            // bf16 WT: 458752 bf16
    const size_t P_WK8 = P_WT + 229376;      // int8 Wk: 49152 B
    const size_t P_SC  = P_WK8 + 12288;      // col scales
    const size_t P_WP  = P_SC + 384;         // WP1T: 4096 bf16
    const size_t P_WROF= P_WP + 2048;        // WroF: 6144 bf16 = 3072 f
    const size_t P_H   = P_WROF + 3072;      // h bf16
    const size_t P_AGG = P_H + 6144000;      // aggb
    const size_t P_KB8 = P_AGG + 6144000;    // kb int8 (98.3 MB)
    const size_t P_SR  = P_KB8 + 24576000;   // row scales
    const size_t T_INT = P_SR + 768000;
    const size_t NEED  = (T_INT + 216096) * 4ull;   // ~163 MB

    if (ws_size < NEED) return;

    __bf16* WT   = (__bf16*)(ws + P_WT);
    signed char* Wk8 = (signed char*)(ws + P_WK8);
    float* s_c   = ws + P_SC;
    __bf16* WP1T = (__bf16*)(ws + P_WP);
    __bf16* WroF = (__bf16*)(ws + P_WROF);
    __bf16* hA   = (__bf16*)(ws + P_H);
    __bf16* aggb = (__bf16*)(ws + P_AGG);
    signed char* kb8 = (signed char*)(ws + P_KB8);
    float* s_r   = ws + P_SR;
    int*   ibase = (int*)(ws + T_INT);
    int* deg    = ibase;
    int* cursor = ibase + 8000;
    int* rowptr = ibase + 16000;
    int* perm   = ibase + 24064;
    int* send_s = ibase + 88064;
    int* recv_s = ibase + 152080;

    const __bf16* Wsp2T = WT;
    const __bf16* W1T   = WT + 65536;
    const __bf16* W2T   = WT + 65536 + 3 * 65536;

    hipMemsetAsync(d_out, 0, sizeof(float) * (size_t)out_size, stream);
    hipMemsetAsync(ro, 0, sizeof(float) * 864000, stream);
    hipMemsetAsync(deg, 0, sizeof(int) * 8000, stream);

    k_grid<<<1, 256, 0, stream>>>(Q, grid0, grid);
    k_kbsh<<<144, 128, 0, stream>>>(grid0, Wsh1, bsh1, Wsh2, bsh2, Wfk, fk);
    k_embed<<<N_NODES, 128, 0, stream>>>(x, vec, batch, grid, Wemb, ng, hA);
    k_deg<<<250, 256, 0, stream>>>(recv, deg);
    k_scan<<<1, 1024, 0, stream>>>(deg, rowptr, cursor);
    k_fill<<<250, 256, 0, stream>>>(recv, cursor, perm);
    k_attr_sorted<<<((N_EDGES + 16) * 12 + 255) / 256, 256, 0, stream>>>(
        pos, ng, send, recv, perm, attr_s, send_s, recv_s);
    k_prepw2<<<(7 * 65536 + 255) / 256, 256, 0, stream>>>(Wsp2, Wk, W1, W2, WT);
    k_prepw_i8<<<3, 128, 0, stream>>>(Wk, Wk8, s_c);
    k_prepw_p<<<1, 128, 0, stream>>>(Wsp1, bsp1, WP1T);
    k_prepw_ro<<<1, 192, 0, stream>>>(Wro, WroF);

    k_kb_i8<<<N_EDGES * 12 / 64, 256, 0, stream>>>(attr_s, Wsp2T, WP1T, bsp2, kb8, s_r);

    for (int l = 0; l < 3; ++l) {
        k_gscat2<<<NBLK, 256, 0, stream>>>(kb8, s_r,
            Wk8 + (size_t)l * 16384, s_c + l * 128,
            send_s, recv_s, rowptr, hA, aggb);
        k_mlp<<<N_NODES / MNPB, 256, 0, stream>>>(aggb, fk + l * 18432,
            bconv + l * 128, ln_g + l * 128, ln_b + l * 128,
            W1T + l * 65536, b1 + l * 512, W2T + l * 65536, b2 + l * 128,
            WroF + l * 2048, bro + l * 9, hA, ro);
    }
    k_out<<<(N_NODES + 127) / 128, 128, 0, stream>>>(ro, ng, batch, (float*)d_out);
}

// Round 13
// 878.457 us; speedup vs baseline: 1.3057x; 1.0020x over previous
//
#include <hip/hip_runtime.h>
#include <hip/hip_bf16.h>

#define N_NODES 8000
#define N_EDGES 64000
#define NBATCH  64
#define NGRID   12
#define HIDC    128
#define MNPB    8
#define EB      64
#define SE      8
#define NBLK    (N_EDGES / EB)

typedef __bf16 bf16x8 __attribute__((ext_vector_type(8)));
typedef __bf16 bf16x4 __attribute__((ext_vector_type(4)));
typedef float  f32x4  __attribute__((ext_vector_type(4)));
typedef int    i32x4  __attribute__((ext_vector_type(4)));

// gelu = x * sigmoid(2u); fast v_rcp (err ~1e-6)
__device__ __forceinline__ float gelu_f(float x) {
    float u = 0.7978845608f * x * (1.0f + 0.044715f * x * x);
    float e = __expf(2.0f * u);
    float r = __builtin_amdgcn_rcpf(e + 1.0f);
    return x * (1.0f - r);
}

// ---------------- grid0 + per-batch rotated grids ----------------
__global__ void k_grid(const float* __restrict__ Q, float* __restrict__ grid0,
                       float* __restrict__ grid) {
    int t = threadIdx.x;
    __shared__ float g0[12][3];
    if (t < 12) {
        float fi = (float)t;
        float theta = 6.28318530717958647692f * fi / 1.61803398874989484820f;
        float z = 1.0f - (2.0f * fi + 1.0f) / 12.0f;
        float r = sqrtf(fmaxf(1.0f - z * z, 0.0f));
        g0[t][0] = r * cosf(theta);
        g0[t][1] = r * sinf(theta);
        g0[t][2] = z;
        grid0[t * 3 + 0] = g0[t][0];
        grid0[t * 3 + 1] = g0[t][1];
        grid0[t * 3 + 2] = g0[t][2];
    }
    __syncthreads();
    for (int idx = t; idx < NBATCH * 12 * 3; idx += blockDim.x) {
        int b = idx / 36, rmd = idx % 36, n = rmd / 3, i = rmd % 3;
        float acc = 0.f;
        #pragma unroll
        for (int j = 0; j < 3; ++j) acc += Q[b * 9 + i * 3 + j] * g0[n][j];
        grid[idx] = acc;
    }
}

// ---------------- kb_sh -> fk  (fk layout: [l][p][c][o]) ----------------
__global__ __launch_bounds__(128) void k_kbsh(
    const float* __restrict__ grid0,
    const float* __restrict__ Wsh1, const float* __restrict__ bsh1,
    const float* __restrict__ Wsh2, const float* __restrict__ bsh2,
    const float* __restrict__ Wfk, float* __restrict__ fk) {
    int row = blockIdx.x;
    int p = row / 12, o = row % 12, t = threadIdx.x;
    float tt = grid0[p*3]*grid0[o*3] + grid0[p*3+1]*grid0[o*3+1] + grid0[p*3+2]*grid0[o*3+2];
    float p1 = tt, p2 = tt * tt, p3 = p2 * tt;
    float h1 = gelu_f(p1 * Wsh1[t] + p2 * Wsh1[128 + t] + p3 * Wsh1[256 + t] + bsh1[t]);
    __shared__ float h1S[128];
    __shared__ float h2S[128];
    h1S[t] = h1;
    __syncthreads();
    float acc = bsh2[t];
    #pragma unroll 8
    for (int k = 0; k < 128; ++k) acc += h1S[k] * Wsh2[k * 128 + t];
    h2S[t] = gelu_f(acc);
    __syncthreads();
    for (int l = 0; l < 3; ++l) {
        float a = 0.f;
        #pragma unroll 8
        for (int k = 0; k < 128; ++k) a += h2S[k] * Wfk[l * 16384 + k * 128 + t];
        fk[l * 18432 + (p * 128 + t) * 12 + o] = a;
    }
}

// ---------------- embed (round-7 verified version) ----------------
__global__ __launch_bounds__(128) void k_embed(
    const float* __restrict__ x, const float* __restrict__ vec,
    const int* __restrict__ batch, const float* __restrict__ grid,
    const float* __restrict__ Wemb, float* __restrict__ node_grid,
    __bf16* __restrict__ h_bf) {
    __shared__ float WembS[18 * 128];
    __shared__ float ngS[36];
    __shared__ float xS[16];
    __shared__ float vS[6];
    int n = blockIdx.x, t = threadIdx.x;
    for (int i = t; i < 18 * 128; i += 128) WembS[i] = Wemb[i];
    int b = batch[n];
    if (t < 36) { float g = grid[b * 36 + t]; ngS[t] = g; node_grid[n * 36 + t] = g; }
    if (t < 16) xS[t] = x[n * 16 + t];
    if (t >= 16 && t < 22) vS[t - 16] = vec[n * 6 + (t - 16)];
    __syncthreads();
    for (int g = 0; g < NGRID; ++g) {
        float g0 = ngS[g*3], g1 = ngS[g*3+1], g2 = ngS[g*3+2];
        float xv0 = vS[0]*g0 + vS[1]*g1 + vS[2]*g2;
        float xv1 = vS[3]*g0 + vS[4]*g1 + vS[5]*g2;
        float acc = xv0 * WembS[16*128 + t] + xv1 * WembS[17*128 + t];
        #pragma unroll
        for (int j = 0; j < 16; ++j) acc += xS[j] * WembS[j*128 + t];
        h_bf[((size_t)n * NGRID + g) * HIDC + t] = (__bf16)acc;
    }
}

// ---------------- CSR build ----------------
__global__ __launch_bounds__(256) void k_deg(const int* __restrict__ recv,
                                             int* __restrict__ deg) {
    int e = blockIdx.x * 256 + threadIdx.x;
    if (e < N_EDGES) atomicAdd(&deg[recv[e]], 1);
}

__global__ __launch_bounds__(1024) void k_scan(const int* __restrict__ deg,
                                               int* __restrict__ rowptr,
                                               int* __restrict__ cursor) {
    __shared__ int part[1024];
    int t = threadIdx.x;
    int base = t * 8;
    int local[8];
    int s = 0;
    #pragma unroll
    for (int j = 0; j < 8; ++j) {
        int idx = base + j;
        int v = (idx < N_NODES) ? deg[idx] : 0;
        local[j] = s;
        s += v;
    }
    part[t] = s;
    __syncthreads();
    for (int off = 1; off < 1024; off <<= 1) {
        int v = (t >= off) ? part[t - off] : 0;
        __syncthreads();
        part[t] += v;
        __syncthreads();
    }
    int excl = (t == 0) ? 0 : part[t - 1];
    #pragma unroll
    for (int j = 0; j < 8; ++j) {
        int idx = base + j;
        if (idx < N_NODES) {
            int v = excl + local[j];
            rowptr[idx] = v;
            cursor[idx] = v;
        }
    }
    if (t == 1023) rowptr[N_NODES] = part[1023];
}

__global__ __launch_bounds__(256) void k_fill(const int* __restrict__ recv,
                                              int* __restrict__ cursor,
                                              int* __restrict__ perm) {
    int e = blockIdx.x * 256 + threadIdx.x;
    if (e < N_EDGES) {
        int r = recv[e];
        int p = atomicAdd(&cursor[r], 1);
        perm[p] = e;
    }
}

// ---------------- attrs (recv-sorted) ----------------
__global__ __launch_bounds__(256) void k_attr_sorted(
    const float* __restrict__ pos, const float* __restrict__ ng,
    const int* __restrict__ send, const int* __restrict__ recv,
    const int* __restrict__ perm,
    float* __restrict__ attr_s, int* __restrict__ send_s,
    int* __restrict__ recv_s) {
    int idx = blockIdx.x * 256 + threadIdx.x;
    if (idx >= (N_EDGES + 16) * 12) return;
    int i = idx / 12, g = idx % 12;
    if (i < N_EDGES) {
        int e = perm[i];
        int s = send[e], r = recv[e];
        float rx = pos[s*3+0] - pos[r*3+0];
        float ry = pos[s*3+1] - pos[r*3+1];
        float rz = pos[s*3+2] - pos[r*3+2];
        const float* gr = ng + ((size_t)r * 12 + g) * 3;
        float g0 = gr[0], g1 = gr[1], g2 = gr[2];
        float iv1 = rx*g0 + ry*g1 + rz*g2;
        float wx = rx - iv1*g0, wy = ry - iv1*g1, wz = rz - iv1*g2;
        attr_s[(size_t)idx * 2 + 0] = iv1;
        attr_s[(size_t)idx * 2 + 1] = sqrtf(wx*wx + wy*wy + wz*wz);
        if (g == 0) { send_s[i] = s; recv_s[i] = r; }
    } else {
        attr_s[(size_t)idx * 2 + 0] = 0.f;
        attr_s[(size_t)idx * 2 + 1] = 0.f;
        if (g == 0) { send_s[i] = 0; recv_s[i] = 0; }
    }
}

// ---- transposed bf16 weights [Wsp2T | WkT | W1T | W2T] ----
__global__ __launch_bounds__(256) void k_prepw2(
    const float* __restrict__ Wsp2, const float* __restrict__ Wk,
    const float* __restrict__ W1, const float* __restrict__ W2,
    __bf16* __restrict__ WT) {
    int i = blockIdx.x * 256 + threadIdx.x;
    if (i >= 7 * 65536) return;
    float v;
    if (i < 65536) {
        int buf = i >> 14, r = i & 16383;
        int n = r >> 7, k = r & 127;
        v = (buf == 0) ? Wsp2[k * 128 + n] : Wk[(buf - 1) * 16384 + k * 128 + n];
    } else {
        int i2 = i - 65536;
        int l = i2 >> 16, r = i2 & 65535;
        if (l < 3) {
            int n = r >> 7, k = r & 127;
            v = W1[l * 65536 + k * 512 + n];
        } else {
            int l2 = l - 3;
            int n = r >> 9, k = r & 511;
            v = W2[l2 * 65536 + k * 128 + n];
        }
    }
    WT[i] = (__bf16)v;
}

// ---- int8 Wk (transposed, per-column scales) ----
__global__ __launch_bounds__(128) void k_prepw_i8(
    const float* __restrict__ Wk, signed char* __restrict__ Wk8,
    float* __restrict__ s_c) {
    int i = blockIdx.x * 128 + threadIdx.x;
    if (i >= 384) return;
    int l = i / 128, col = i % 128;
    float mx = 0.f;
    for (int k = 0; k < 128; ++k)
        mx = fmaxf(mx, fabsf(Wk[l * 16384 + k * 128 + col]));
    float s = fmaxf(mx * (1.0f / 127.0f), 1e-20f);
    s_c[i] = s;
    float inv = 127.0f / fmaxf(mx, 1e-20f);
    for (int k = 0; k < 128; ++k) {
        int q = __float2int_rn(Wk[l * 16384 + k * 128 + col] * inv);
        q = q > 127 ? 127 : (q < -127 ? -127 : q);
        Wk8[(size_t)l * 16384 + col * 128 + k] = (signed char)q;
    }
}

// ---- combined poly weights WP1T [128 cols x 32 k] bf16 (bias at k=9) ----
__global__ __launch_bounds__(128) void k_prepw_p(
    const float* __restrict__ Wsp1, const float* __restrict__ bsp1,
    __bf16* __restrict__ WP1T) {
    int col = threadIdx.x;
    float w1[14];
    #pragma unroll
    for (int j = 0; j < 14; ++j) w1[j] = Wsp1[j * 128 + col];
    float vals[10];
    vals[0] = w1[0];                       // a
    vals[1] = w1[1];                       // b
    vals[2] = w1[2];                       // aa
    vals[3] = w1[3] + w1[4];               // ab
    vals[4] = w1[5];                       // bb
    vals[5] = w1[6];                       // aaa
    vals[6] = w1[7] + w1[8] + w1[10];      // aab
    vals[7] = w1[9] + w1[11] + w1[12];     // abb
    vals[8] = w1[13];                      // bbb
    vals[9] = bsp1[col];                   // bias (monomial 1)
    for (int k = 0; k < 32; ++k)
        WP1T[col * 32 + k] = (k < 10) ? (__bf16)vals[k] : (__bf16)0.f;
}

// ---- Wro packed per-layer into MFMA B-fragment per-lane layout ----
__global__ __launch_bounds__(192) void k_prepw_ro(
    const float* __restrict__ Wro, __bf16* __restrict__ WroF) {
    int t = threadIdx.x;
    int l = t / 64, lane = t % 64;
    int l15 = lane & 15, quad = lane >> 4;
    #pragma unroll
    for (int ks = 0; ks < 4; ++ks)
        #pragma unroll
        for (int j = 0; j < 8; ++j) {
            int k = ks * 32 + quad * 8 + j;
            float v = (l15 < 9) ? Wro[l * 1152 + k * 9 + l15] : 0.f;
            WroF[(size_t)(l * 64 + lane) * 32 + ks * 8 + j] = (__bf16)v;
        }
}

// ---------------- kb precompute (once): MFMA poly -> GEMM1 -> gelu -> kb int8 ----------------
// Round-26: (a) launch_bounds 4 -> 5 blocks/CU (LDS 28KB admits 5; kernel is
// VALU-bound at 80% with coalesced streaming writes — no RMW L2-reuse to
// thrash, unlike k_mlp); (b) rowmaxS now stores the RECIPROCAL (s_r keeps
// the scale), removing 32 redundant v_rcp per thread from the quant loop.
__global__ __launch_bounds__(256, 5) void k_kb_i8(
    const float* __restrict__ attr_s,
    const __bf16* __restrict__ W2T, const __bf16* __restrict__ WP1T,
    const float* __restrict__ bsp2,
    signed char* __restrict__ kb8, float* __restrict__ s_r) {
    __shared__ __align__(16) __bf16 H1[64 * 136];
    __shared__ __align__(16) signed char K8[64 * 144];
    __shared__ float rowmaxS[64];
    __shared__ float rm4[64][4];
    int t = threadIdx.x;
    int lane = t & 63, w = t >> 6, l15 = lane & 15, quad = lane >> 4;
    size_t grow0 = (size_t)blockIdx.x * 64;
    // ---- poly via MFMA: wave w owns rows w*16 + l15 ----
    {
        float2 ab = ((const float2*)attr_s)[grow0 + w * 16 + l15];
        float a = ab.x, b = ab.y;
        float aa = a * a, abm = a * b, bb = b * b;
        float m0 = quad == 0 ? a        : (quad == 1 ? bb * b : 0.f);
        float m1 = quad == 0 ? b        : (quad == 1 ? 1.f    : 0.f);
        float m2 = quad == 0 ? aa       : 0.f;
        float m3 = quad == 0 ? abm      : 0.f;
        float m4 = quad == 0 ? bb       : 0.f;
        float m5 = quad == 0 ? aa * a   : 0.f;
        float m6 = quad == 0 ? aa * b   : 0.f;
        float m7 = quad == 0 ? abm * b  : 0.f;
        bf16x8 afrag = { (__bf16)m0, (__bf16)m1, (__bf16)m2, (__bf16)m3,
                         (__bf16)m4, (__bf16)m5, (__bf16)m6, (__bf16)m7 };
        #pragma unroll
        for (int n = 0; n < 8; ++n) {
            bf16x8 bp = *(const bf16x8*)(WP1T + (n * 16 + l15) * 32 + quad * 8);
            f32x4 cacc = {0.f, 0.f, 0.f, 0.f};
            cacc = __builtin_amdgcn_mfma_f32_16x16x32_bf16(afrag, bp, cacc, 0, 0, 0);
            #pragma unroll
            for (int rg = 0; rg < 4; ++rg) {
                int row = w * 16 + quad * 4 + rg;
                H1[row * 136 + n * 16 + l15] = (__bf16)gelu_f(cacc[rg]);
            }
        }
    }
    __syncthreads();
    bf16x8 Bf[2][4];
    #pragma unroll
    for (int j = 0; j < 2; ++j)
        #pragma unroll
        for (int ks = 0; ks < 4; ++ks)
            Bf[j][ks] = *(const bf16x8*)(W2T + (size_t)(w * 32 + j * 16 + l15) * 128 + ks * 32 + quad * 8);
    float b2v[2] = { bsp2[w * 32 + l15], bsp2[w * 32 + 16 + l15] };
    f32x4 acc[4][2];
    #pragma unroll
    for (int mt = 0; mt < 4; ++mt) {
        acc[mt][0] = (f32x4){0.f,0.f,0.f,0.f};
        acc[mt][1] = (f32x4){0.f,0.f,0.f,0.f};
        #pragma unroll
        for (int ks = 0; ks < 4; ++ks) {
            bf16x8 af = *(const bf16x8*)(H1 + (mt * 16 + l15) * 136 + ks * 32 + quad * 8);
            acc[mt][0] = __builtin_amdgcn_mfma_f32_16x16x32_bf16(af, Bf[0][ks], acc[mt][0], 0, 0, 0);
            acc[mt][1] = __builtin_amdgcn_mfma_f32_16x16x32_bf16(af, Bf[1][ks], acc[mt][1], 0, 0, 0);
        }
    }
    float g[4][2][4];
    #pragma unroll
    for (int mt = 0; mt < 4; ++mt)
        #pragma unroll
        for (int j = 0; j < 2; ++j)
            #pragma unroll
            for (int rg = 0; rg < 4; ++rg)
                g[mt][j][rg] = gelu_f(acc[mt][j][rg] + b2v[j]);
    __syncthreads();
    #pragma unroll
    for (int mt = 0; mt < 4; ++mt)
        #pragma unroll
        for (int j = 0; j < 2; ++j)
            #pragma unroll
            for (int rg = 0; rg < 4; ++rg) {
                int row = mt * 16 + quad * 4 + rg;
                H1[row * 136 + w * 32 + j * 16 + l15] = (__bf16)g[mt][j][rg];
            }
    __syncthreads();
    // ---- parallel rowmax: 4 threads per row ----
    {
        int row = t & 63, qt = t >> 6;
        float mx = 0.f;
        #pragma unroll
        for (int ks = 0; ks < 4; ++ks) {
            bf16x8 xv = *(const bf16x8*)(H1 + row * 136 + qt * 32 + ks * 8);
            #pragma unroll
            for (int m = 0; m < 8; ++m) mx = fmaxf(mx, fabsf((float)xv[m]));
        }
        rm4[row][qt] = mx;
    }
    __syncthreads();
    if (t < 64) {
        float mx = fmaxf(fmaxf(rm4[t][0], rm4[t][1]), fmaxf(rm4[t][2], rm4[t][3]));
        float s = fmaxf(mx * (1.0f / 127.0f), 1e-20f);
        rowmaxS[t] = __builtin_amdgcn_rcpf(s);   // store reciprocal
        s_r[grow0 + t] = s;                       // scale for dequant
    }
    __syncthreads();
    #pragma unroll
    for (int mt = 0; mt < 4; ++mt)
        #pragma unroll
        for (int j = 0; j < 2; ++j)
            #pragma unroll
            for (int rg = 0; rg < 4; ++rg) {
                int row = mt * 16 + quad * 4 + rg;
                float inv = rowmaxS[row];
                int q = __float2int_rn(g[mt][j][rg] * inv);
                q = q > 127 ? 127 : (q < -127 ? -127 : q);
                K8[row * 144 + w * 32 + j * 16 + l15] = (signed char)q;
            }
    __syncthreads();
    #pragma unroll
    for (int it = 0; it < 2; ++it) {
        int idx = it * 256 + t;
        int row = idx >> 3, cv = idx & 7;
        *(uint4*)(kb8 + (grow0 + row) * 128 + cv * 16) =
            *(const uint4*)(K8 + row * 144 + cv * 16);
    }
}

// -------- fused per-layer GEMM2 + scatter (node-aligned, NO atomics) --------
// Round-12 verified version (register-prefetched kb8 staging, T14).
__global__ __launch_bounds__(256, 4) void k_gscat2(
    const signed char* __restrict__ kb8, const float* __restrict__ s_r,
    const signed char* __restrict__ Wk8, const float* __restrict__ s_cL,
    const int* __restrict__ send_s, const int* __restrict__ recv_s,
    const int* __restrict__ rowptr, const __bf16* __restrict__ h_bf,
    __bf16* __restrict__ aggb) {
    __shared__ __align__(16) signed char T8[96 * 144];
    __shared__ __align__(16) __bf16 P[96 * 136];
    __shared__ float srS[96];
    int t = threadIdx.x;
    int lane = t & 63, w = t >> 6, l15 = lane & 15, quad = lane >> 4;
    int bid = blockIdx.x;
    int n0, n1;
    {
        if (bid == 0) n0 = 0;
        else {
            int tgt = bid * EB, lo = 0, hi = N_NODES;
            while (lo < hi) { int m = (lo + hi) >> 1; if (rowptr[m] < tgt) lo = m + 1; else hi = m; }
            n0 = lo;
        }
        if (bid == NBLK - 1) n1 = N_NODES;
        else {
            int tgt = (bid + 1) * EB, lo = 0, hi = N_NODES;
            while (lo < hi) { int m = (lo + hi) >> 1; if (rowptr[m] < tgt) lo = m + 1; else hi = m; }
            n1 = lo;
        }
    }
    if (n0 >= n1) return;                    // uniform: no barriers crossed
    int e0 = rowptr[n0], e1 = rowptr[n1];
    long long Bf[2][4];
    #pragma unroll
    for (int j = 0; j < 2; ++j)
        #pragma unroll
        for (int ks = 0; ks < 4; ++ks)
            Bf[j][ks] = *(const long long*)(Wk8 + (size_t)(w * 32 + j * 16 + l15) * 128 + ks * 32 + quad * 8);
    float sc0 = s_cL[w * 32 + l15], sc1 = s_cL[w * 32 + 16 + l15];
    int c = t & 127, half = t >> 7;
    float acc[6] = {0.f, 0.f, 0.f, 0.f, 0.f, 0.f};
    int cur = (e0 < e1) ? recv_s[e0] : -1;
    // ---- prefetch sub-tile 0 into registers ----
    uint4 R0, R1, R2;
    float Rs = 0.f;
    bool v0, v1, v2, vs;
    {
        int cnt = e1 - e0; if (cnt > SE) cnt = SE;
        int nr8 = cnt * 96;                  // nrows*8
        v0 = t < nr8;
        v1 = 256 + t < nr8;
        v2 = 512 + t < nr8;
        vs = t < cnt * 12;
        if (v0) { int idx = t;       R0 = *(const uint4*)(kb8 + ((size_t)e0 * 12 + (idx >> 3)) * 128 + (idx & 7) * 16); }
        if (v1) { int idx = 256 + t; R1 = *(const uint4*)(kb8 + ((size_t)e0 * 12 + (idx >> 3)) * 128 + (idx & 7) * 16); }
        if (v2) { int idx = 512 + t; R2 = *(const uint4*)(kb8 + ((size_t)e0 * 12 + (idx >> 3)) * 128 + (idx & 7) * 16); }
        if (vs) Rs = s_r[(size_t)e0 * 12 + t];
    }
    for (int et0 = e0; et0 < e1; et0 += SE) {
        int cnt = e1 - et0; if (cnt > SE) cnt = SE;
        int nrows = cnt * 12;
        __syncthreads();                     // previous scatter done reading P; T8 free
        // commit prefetched registers to LDS
        if (v0) { int idx = t;       *(uint4*)(T8 + (idx >> 3) * 144 + (idx & 7) * 16) = R0; }
        if (v1) { int idx = 256 + t; *(uint4*)(T8 + (idx >> 3) * 144 + (idx & 7) * 16) = R1; }
        if (v2) { int idx = 512 + t; *(uint4*)(T8 + (idx >> 3) * 144 + (idx & 7) * 16) = R2; }
        if (vs) srS[t] = Rs;
        __syncthreads();
        // issue next sub-tile's loads (latency hides under MFMA + scatter)
        int net0 = et0 + SE;
        if (net0 < e1) {
            int ncnt = e1 - net0; if (ncnt > SE) ncnt = SE;
            int nr8 = ncnt * 96;
            v0 = t < nr8;
            v1 = 256 + t < nr8;
            v2 = 512 + t < nr8;
            vs = t < ncnt * 12;
            if (v0) { int idx = t;       R0 = *(const uint4*)(kb8 + ((size_t)net0 * 12 + (idx >> 3)) * 128 + (idx & 7) * 16); }
            if (v1) { int idx = 256 + t; R1 = *(const uint4*)(kb8 + ((size_t)net0 * 12 + (idx >> 3)) * 128 + (idx & 7) * 16); }
            if (v2) { int idx = 512 + t; R2 = *(const uint4*)(kb8 + ((size_t)net0 * 12 + (idx >> 3)) * 128 + (idx & 7) * 16); }
            if (vs) Rs = s_r[(size_t)net0 * 12 + t];
        }
        int nrt = (nrows + 15) >> 4;
        for (int rt = 0; rt < nrt; ++rt) {
            i32x4 a0 = (i32x4){0, 0, 0, 0};
            i32x4 a1 = (i32x4){0, 0, 0, 0};
            #pragma unroll
            for (int ks = 0; ks < 4; ++ks) {
                long long a = *(const long long*)(T8 + (rt * 16 + l15) * 144 + ks * 32 + quad * 8);
                a0 = __builtin_amdgcn_mfma_i32_16x16x32_i8(a, Bf[0][ks], a0, 0, 0, 0);
                a1 = __builtin_amdgcn_mfma_i32_16x16x32_i8(a, Bf[1][ks], a1, 0, 0, 0);
            }
            #pragma unroll
            for (int rg = 0; rg < 4; ++rg) {
                int row = rt * 16 + quad * 4 + rg;
                float sr = srS[row];
                P[row * 136 + w * 32 + l15]      = (__bf16)((float)a0[rg] * sr * sc0);
                P[row * 136 + w * 32 + 16 + l15] = (__bf16)((float)a1[rg] * sr * sc1);
            }
        }
        __syncthreads();
        for (int el = 0; el < cnt; ++el) {
            int e = et0 + el;
            int r = recv_s[e];
            if (r != cur) {
                __bf16* op = aggb + ((size_t)cur * 128 + c) * 12 + half * 6;
                #pragma unroll
                for (int j = 0; j < 6; ++j) { op[j] = (__bf16)acc[j]; acc[j] = 0.f; }
                cur = r;
            }
            int s = send_s[e];
            const __bf16* hp = h_bf + (size_t)s * 1536 + half * 6 * 128 + c;
            const __bf16* pp = P + (el * 12 + half * 6) * 136 + c;
            #pragma unroll
            for (int j = 0; j < 6; ++j)
                acc[j] += (float)hp[j * 128] * (float)pp[j * 136];
        }
    }
    if (e0 < e1) {
        __bf16* op = aggb + ((size_t)cur * 128 + c) * 12 + half * 6;
        #pragma unroll
        for (int j = 0; j < 6; ++j) op[j] = (__bf16)acc[j];
    }
    for (int n = n0; n < n1; ++n) {
        if (rowptr[n] == rowptr[n + 1]) {
            __bf16* op = aggb + ((size_t)n * 128 + c) * 12 + half * 6;
            #pragma unroll
            for (int j = 0; j < 6; ++j) op[j] = (__bf16)0.f;
        }
    }
}

// ---------------- node kernel: conv + LN + MFMA MLP + MFMA readout ----------------
// Round-11 verified version (software-pipelined weights, -45 µs/dispatch).
__global__ __launch_bounds__(256, 3) void k_mlp(
    const __bf16* __restrict__ aggb, const float* __restrict__ fkl,
    const float* __restrict__ bconv, const float* __restrict__ ln_g,
    const float* __restrict__ ln_b,
    const __bf16* __restrict__ W1T, const float* __restrict__ b1,
    const __bf16* __restrict__ W2T2, const float* __restrict__ b2,
    const __bf16* __restrict__ WroFl, const float* __restrict__ bro,
    __bf16* __restrict__ h_bf, float* __restrict__ readout) {
    __shared__ __align__(16) __bf16 X[96 * 136];
    __shared__ __align__(16) __bf16 H4[96 * 136];
    __shared__ float redS[96][2];
    int t = threadIdx.x;
    int lane = t & 63, w = t >> 6, l15 = lane & 15, quad = lane >> 4;
    int c = t & 127, nh = t >> 7;
    int n0 = blockIdx.x * MNPB;
    float bcv = bconv[c];
    // ---- conv: thread owns channel c, nodes {nh, nh+2, nh+4, nh+6} ----
    {
        float a2[4][12];
        #pragma unroll
        for (int u = 0; u < 4; ++u) {
            const __bf16* ap = aggb + ((size_t)(n0 + nh + u * 2) * 128 + c) * 12;
            #pragma unroll
            for (int v = 0; v < 3; ++v) {
                bf16x4 pk = *(const bf16x4*)(ap + v * 4);
                #pragma unroll
                for (int j = 0; j < 4; ++j) a2[u][v * 4 + j] = (float)pk[j];
            }
        }
        #pragma unroll 4
        for (int p = 0; p < 12; ++p) {
            const float* fp = fkl + ((size_t)p * 128 + c) * 12;
            float fr[12];
            #pragma unroll
            for (int v = 0; v < 3; ++v) {
                float4 fv = *(const float4*)(fp + v * 4);
                fr[v*4+0] = fv.x; fr[v*4+1] = fv.y; fr[v*4+2] = fv.z; fr[v*4+3] = fv.w;
            }
            #pragma unroll
            for (int u = 0; u < 4; ++u) {
                float s = 0.f;
                #pragma unroll
                for (int o = 0; o < 12; ++o) s += a2[u][o] * fr[o];
                X[((nh + u * 2) * 12 + p) * 136 + c] = (__bf16)(s * (1.0f / 12.0f) + bcv);
            }
        }
    }
    __syncthreads();
    // ---- LN stats: wave w owns rows w*24 .. w*24+24 ----
    for (int r = w * 24; r < w * 24 + 24; ++r) {
        float v0 = (float)X[r * 136 + lane];
        float v1 = (float)X[r * 136 + 64 + lane];
        float s = v0 + v1, s2 = v0 * v0 + v1 * v1;
        for (int off = 32; off > 0; off >>= 1) {
            s += __shfl_down(s, off);
            s2 += __shfl_down(s2, off);
        }
        if (lane == 0) {
            float mu = s * (1.0f / 128.0f);
            float var = s2 * (1.0f / 128.0f) - mu * mu;
            redS[r][0] = mu;
            redS[r][1] = rsqrtf(var + 1e-5f);
        }
    }
    __syncthreads();
    float gv = ln_g[c], bv = ln_b[c];
    #pragma unroll
    for (int nn = nh; nn < 8; nn += 2)
        #pragma unroll
        for (int p = 0; p < 12; ++p) {
            int r = nn * 12 + p;
            float v = (float)X[r * 136 + c];
            X[r * 136 + c] = (__bf16)((v - redS[r][0]) * redS[r][1] * gv + bv);
        }
    __syncthreads();
    // ---- MLP: 4 phases of 128 hidden cols, 6 row-tiles; pipelined weights ----
    f32x4 acc2[6][2];
    #pragma unroll
    for (int mt = 0; mt < 6; ++mt)
        #pragma unroll
        for (int j = 0; j < 2; ++j) acc2[mt][j] = (f32x4){0.f, 0.f, 0.f, 0.f};
    bf16x8 W1f[2][4];
    #pragma unroll
    for (int nt = 0; nt < 2; ++nt)
        #pragma unroll
        for (int ks = 0; ks < 4; ++ks)
            W1f[nt][ks] = *(const bf16x8*)(W1T + (size_t)(w * 32 + nt * 16 + l15) * 128 + ks * 32 + quad * 8);
    for (int ph = 0; ph < 4; ++ph) {
        if (ph) __syncthreads();
        bf16x8 W2f[2][4];
        #pragma unroll
        for (int j = 0; j < 2; ++j)
            #pragma unroll
            for (int ks = 0; ks < 4; ++ks)
                W2f[j][ks] = *(const bf16x8*)(W2T2 + (size_t)(w * 32 + j * 16 + l15) * 512 + ph * 128 + ks * 32 + quad * 8);
        float bj0 = b1[ph * 128 + w * 32 + l15];
        float bj1 = b1[ph * 128 + w * 32 + 16 + l15];
        #pragma unroll
        for (int mt = 0; mt < 6; ++mt) {
            bf16x8 af[4];
            #pragma unroll
            for (int ks = 0; ks < 4; ++ks)
                af[ks] = *(const bf16x8*)(X + (mt * 16 + l15) * 136 + ks * 32 + quad * 8);
            f32x4 a0 = {0.f, 0.f, 0.f, 0.f};
            f32x4 a1 = {0.f, 0.f, 0.f, 0.f};
            #pragma unroll
            for (int ks = 0; ks < 4; ++ks) {
                a0 = __builtin_amdgcn_mfma_f32_16x16x32_bf16(af[ks], W1f[0][ks], a0, 0, 0, 0);
                a1 = __builtin_amdgcn_mfma_f32_16x16x32_bf16(af[ks], W1f[1][ks], a1, 0, 0, 0);
            }
            #pragma unroll
            for (int rg = 0; rg < 4; ++rg) {
                int row = mt * 16 + quad * 4 + rg;
                H4[row * 136 + w * 32 + l15]      = (__bf16)gelu_f(a0[rg] + bj0);
                H4[row * 136 + w * 32 + 16 + l15] = (__bf16)gelu_f(a1[rg] + bj1);
            }
        }
        if (ph < 3) {
            #pragma unroll
            for (int nt = 0; nt < 2; ++nt)
                #pragma unroll
                for (int ks = 0; ks < 4; ++ks)
                    W1f[nt][ks] = *(const bf16x8*)(W1T + (size_t)((ph + 1) * 128 + w * 32 + nt * 16 + l15) * 128 + ks * 32 + quad * 8);
        }
        __syncthreads();
        #pragma unroll
        for (int mt = 0; mt < 6; ++mt)
            #pragma unroll
            for (int ks = 0; ks < 4; ++ks) {
                bf16x8 af = *(const bf16x8*)(H4 + (mt * 16 + l15) * 136 + ks * 32 + quad * 8);
                acc2[mt][0] = __builtin_amdgcn_mfma_f32_16x16x32_bf16(af, W2f[0][ks], acc2[mt][0], 0, 0, 0);
                acc2[mt][1] = __builtin_amdgcn_mfma_f32_16x16x32_bf16(af, W2f[1][ks], acc2[mt][1], 0, 0, 0);
            }
    }
    // ---- residual h update (writes h_bf + X) ----
    #pragma unroll
    for (int mt = 0; mt < 6; ++mt) {
        float bj0 = b2[w * 32 + l15], bj1 = b2[w * 32 + 16 + l15];
        #pragma unroll
        for (int rg = 0; rg < 4; ++rg) {
            int row = mt * 16 + quad * 4 + rg;
            int node = n0 + row / 12, pp = row % 12;
            size_t hi = ((size_t)node * 12 + pp) * 128;
            {
                int col = w * 32 + l15;
                float hv = (float)h_bf[hi + col] + acc2[mt][0][rg] + bj0;
                h_bf[hi + col] = (__bf16)hv;
                X[row * 136 + col] = (__bf16)hv;
            }
            {
                int col = w * 32 + 16 + l15;
                float hv = (float)h_bf[hi + col] + acc2[mt][1][rg] + bj1;
                h_bf[hi + col] = (__bf16)hv;
                X[row * 136 + col] = (__bf16)hv;
            }
        }
    }
    __syncthreads();
    // ---- readout via MFMA: 6 row-tiles over 4 waves, B-frag from WroF ----
    for (int mt2 = w; mt2 < 6; mt2 += 4) {
        const __bf16* wp = WroFl + (size_t)lane * 32;
        f32x4 a = {0.f, 0.f, 0.f, 0.f};
        #pragma unroll
        for (int ks = 0; ks < 4; ++ks) {
            bf16x8 af = *(const bf16x8*)(X + (mt2 * 16 + l15) * 136 + ks * 32 + quad * 8);
            bf16x8 bf = *(const bf16x8*)(wp + ks * 8);
            a = __builtin_amdgcn_mfma_f32_16x16x32_bf16(af, bf, a, 0, 0, 0);
        }
        if (l15 < 9) {
            float bj = bro[l15];
            #pragma unroll
            for (int rg = 0; rg < 4; ++rg) {
                int row = mt2 * 16 + quad * 4 + rg;
                int node = n0 + row / 12, pp = row % 12;
                size_t ri = ((size_t)node * 12 + pp) * 9 + l15;
                readout[ri] += (a[rg] + bj) * (1.0f / 3.0f);
            }
        }
    }
}

// ---------------- final pooling ----------------
__global__ __launch_bounds__(128) void k_out(
    const float* __restrict__ readout, const float* __restrict__ node_grid,
    const int* __restrict__ batch, float* __restrict__ out) {
    int n = blockIdx.x * 128 + threadIdx.x;
    if (n >= N_NODES) return;
    int b = batch[n];
    const float* ro = readout + (size_t)n * 108;
    float ss[8] = {0, 0, 0, 0, 0, 0, 0, 0};
    float v0 = 0.f, v1 = 0.f, v2 = 0.f;
    for (int p = 0; p < 12; ++p) {
        #pragma unroll
        for (int j = 0; j < 8; ++j) ss[j] += ro[p * 9 + j];
        float rv = ro[p * 9 + 8];
        v0 += rv * node_grid[n * 36 + p * 3 + 0];
        v1 += rv * node_grid[n * 36 + p * 3 + 1];
        v2 += rv * node_grid[n * 36 + p * 3 + 2];
    }
    #pragma unroll
    for (int j = 0; j < 8; ++j) atomicAdd(&out[b * 8 + j], ss[j] * (1.0f / 12.0f));
    atomicAdd(&out[512 + b * 3 + 0], v0 * (1.0f / 12.0f));
    atomicAdd(&out[512 + b * 3 + 1], v1 * (1.0f / 12.0f));
    atomicAdd(&out[512 + b * 3 + 2], v2 * (1.0f / 12.0f));
}

extern "C" void kernel_launch(void* const* d_in, const int* in_sizes, int n_in,
                              void* d_out, int out_size, void* d_ws, size_t ws_size,
                              hipStream_t stream) {
    const float* x    = (const float*)d_in[0];
    const float* vec  = (const float*)d_in[1];
    const float* pos  = (const float*)d_in[2];
    const float* Q    = (const float*)d_in[3];
    const float* Wsp1 = (const float*)d_in[4];
    const float* bsp1 = (const float*)d_in[5];
    const float* Wsp2 = (const float*)d_in[6];
    const float* bsp2 = (const float*)d_in[7];
    const float* Wsh1 = (const float*)d_in[8];
    const float* bsh1 = (const float*)d_in[9];
    const float* Wsh2 = (const float*)d_in[10];
    const float* bsh2 = (const float*)d_in[11];
    const float* Wemb = (const float*)d_in[12];
    const float* Wk   = (const float*)d_in[13];
    const float* Wfk  = (const float*)d_in[14];
    const float* bconv= (const float*)d_in[15];
    const float* ln_g = (const float*)d_in[16];
    const float* ln_b = (const float*)d_in[17];
    const float* W1   = (const float*)d_in[18];
    const float* b1   = (const float*)d_in[19];
    const float* W2   = (const float*)d_in[20];
    const float* b2   = (const float*)d_in[21];
    const float* Wro  = (const float*)d_in[22];
    const float* bro  = (const float*)d_in[23];
    const int* ei     = (const int*)d_in[24];
    const int* batch  = (const int*)d_in[25];
    const int* send = ei;
    const int* recv = ei + N_EDGES;

    float* ws = (float*)d_ws;
    float* grid0  = ws;
    float* grid   = ws + 64;
    float* fk     = ws + 2368;
    float* ng     = ws + 57664;
    float* ro     = ws + 345664;
    float* attr_s = ws + 1209664;
    const size_t P_WT  = 2746048;            // bf16 WT: 458752 bf16
    const size_t P_WK8 = P_WT + 229376;      // int8 Wk: 49152 B
    const size_t P_SC  = P_WK8 + 12288;      // col scales
    const size_t P_WP  = P_SC + 384;         // WP1T: 4096 bf16
    const size_t P_WROF= P_WP + 2048;        // WroF: 6144 bf16 = 3072 f
    const size_t P_H   = P_WROF + 3072;      // h bf16
    const size_t P_AGG = P_H + 6144000;      // aggb
    const size_t P_KB8 = P_AGG + 6144000;    // kb int8 (98.3 MB)
    const size_t P_SR  = P_KB8 + 24576000;   // row scales
    const size_t T_INT = P_SR + 768000;
    const size_t NEED  = (T_INT + 216096) * 4ull;   // ~163 MB

    if (ws_size < NEED) return;

    __bf16* WT   = (__bf16*)(ws + P_WT);
    signed char* Wk8 = (signed char*)(ws + P_WK8);
    float* s_c   = ws + P_SC;
    __bf16* WP1T = (__bf16*)(ws + P_WP);
    __bf16* WroF = (__bf16*)(ws + P_WROF);
    __bf16* hA   = (__bf16*)(ws + P_H);
    __bf16* aggb = (__bf16*)(ws + P_AGG);
    signed char* kb8 = (signed char*)(ws + P_KB8);
    float* s_r   = ws + P_SR;
    int*   ibase = (int*)(ws + T_INT);
    int* deg    = ibase;
    int* cursor = ibase + 8000;
    int* rowptr = ibase + 16000;
    int* perm   = ibase + 24064;
    int* send_s = ibase + 88064;
    int* recv_s = ibase + 152080;

    const __bf16* Wsp2T = WT;
    const __bf16* W1T   = WT + 65536;
    const __bf16* W2T   = WT + 65536 + 3 * 65536;

    hipMemsetAsync(d_out, 0, sizeof(float) * (size_t)out_size, stream);
    hipMemsetAsync(ro, 0, sizeof(float) * 864000, stream);
    hipMemsetAsync(deg, 0, sizeof(int) * 8000, stream);

    k_grid<<<1, 256, 0, stream>>>(Q, grid0, grid);
    k_kbsh<<<144, 128, 0, stream>>>(grid0, Wsh1, bsh1, Wsh2, bsh2, Wfk, fk);
    k_embed<<<N_NODES, 128, 0, stream>>>(x, vec, batch, grid, Wemb, ng, hA);
    k_deg<<<250, 256, 0, stream>>>(recv, deg);
    k_scan<<<1, 1024, 0, stream>>>(deg, rowptr, cursor);
    k_fill<<<250, 256, 0, stream>>>(recv, cursor, perm);
    k_attr_sorted<<<((N_EDGES + 16) * 12 + 255) / 256, 256, 0, stream>>>(
        pos, ng, send, recv, perm, attr_s, send_s, recv_s);
    k_prepw2<<<(7 * 65536 + 255) / 256, 256, 0, stream>>>(Wsp2, Wk, W1, W2, WT);
    k_prepw_i8<<<3, 128, 0, stream>>>(Wk, Wk8, s_c);
    k_prepw_p<<<1, 128, 0, stream>>>(Wsp1, bsp1, WP1T);
    k_prepw_ro<<<1, 192, 0, stream>>>(Wro, WroF);

    k_kb_i8<<<N_EDGES * 12 / 64, 256, 0, stream>>>(attr_s, Wsp2T, WP1T, bsp2, kb8, s_r);

    for (int l = 0; l < 3; ++l) {
        k_gscat2<<<NBLK, 256, 0, stream>>>(kb8, s_r,
            Wk8 + (size_t)l * 16384, s_c + l * 128,
            send_s, recv_s, rowptr, hA, aggb);
        k_mlp<<<N_NODES / MNPB, 256, 0, stream>>>(aggb, fk + l * 18432,
            bconv + l * 128, ln_g + l * 128, ln_b + l * 128,
            W1T + l * 65536, b1 + l * 512, W2T + l * 65536, b2 + l * 128,
            WroF + l * 2048, bro + l * 9, hA, ro);
    }
    k_out<<<(N_NODES + 127) / 128, 128, 0, stream>>>(ro, ng, batch, (float*)d_out);
}